// Round 16
// baseline (614.380 us; speedup 1.0000x reference)
//
#include <hip/hip_runtime.h>
#include <hip/hip_bf16.h>
#include <stdint.h>
#include <math.h>

#define BB 16
#define CC 256
#define HH 64
#define WW 64
#define NN 4096   // HH*WW
#define SS 64
#define NHEAD 8
#define DH 32
#define HID 512
#define DC 64

typedef float    f32x4  __attribute__((ext_vector_type(4)));
typedef uint16_t u16x8  __attribute__((ext_vector_type(8)));
typedef uint16_t u16x4  __attribute__((ext_vector_type(4)));
typedef uint16_t u16x2  __attribute__((ext_vector_type(2)));

// tanh-approx gelu (|err| < ~1e-3 abs; budget absmax 0.108 >> this)
__device__ __forceinline__ float gelu_fast(float x){
  float u = 0.7978845608028654f * (x + 0.044715f * x * x * x);
  float e = __expf(2.0f * u);
  float th = 1.0f - 2.0f / (e + 1.0f);
  return 0.5f * x * (1.0f + th);
}
__device__ __forceinline__ uint16_t f2b(float f){
  union { float f; uint32_t u; } v; v.f = f;
  uint32_t r = v.u + 0x7fffu + ((v.u >> 16) & 1u);
  return (uint16_t)(r >> 16);
}
__device__ __forceinline__ float b2f(uint16_t h){
  union { uint32_t u; float f; } v; v.u = ((uint32_t)h) << 16;
  return v.f;
}

__device__ __forceinline__ float waveSum(float v){
#pragma unroll
  for (int m = 32; m >= 1; m >>= 1) v += __shfl_xor(v, m, 64);
  return v;
}
__device__ __forceinline__ float blockSum256(float v, float* s4){
  v = waveSum(v);
  __syncthreads();
  if ((threadIdx.x & 63) == 0) s4[threadIdx.x >> 6] = v;
  __syncthreads();
  return s4[0] + s4[1] + s4[2] + s4[3];
}

// ---- async global->LDS, 16B per lane (dest = wave-uniform base + lane*16) ----
__device__ __forceinline__ void g2l16(const void* g, void* l){
  __builtin_amdgcn_global_load_lds((const __attribute__((address_space(1))) uint32_t*)g,
                                   (__attribute__((address_space(3))) uint32_t*)l, 16, 0, 0);
}

// XOR swizzle for 64-elem (128B) rows: 16B-unit u' = u ^ (row&7).  [G4/T2/m173]
__device__ __forceinline__ int swz8(int row, int kp){ return (kp ^ (row & 7)) << 3; }

// ---- MFMA 16x16x32 bf16 via inline asm (D=C in-place) ----
// A/B frag: lane l holds row/col (l&15), k = (l>>4)*8 + e
// D: col = lane&15, row = (lane>>4)*4 + reg   [m89-verified]
__device__ __forceinline__ void mfma_bf16(f32x4& d, u16x8 a, u16x8 b){
  asm volatile("v_mfma_f32_16x16x32_bf16 %0, %1, %2, %0" : "+v"(d) : "v"(a), "v"(b));
}

// 4x4-fragment core over one BK=64 LDS tile; SWA/SWB: operand stored swizzled (lda/ldb==64 only)
template<int SWA, int SWB>
__device__ __forceinline__ void mma_core(const uint16_t* lA, int lda, const uint16_t* lB, int ldb,
                                         f32x4 (&acc)[4][4], int wrow, int wcol, int lane){
  const int rb = lane & 15, ub = lane >> 4;
#pragma unroll
  for (int ks = 0; ks < 2; ks++){
    const int u = ks * 4 + ub;
    u16x8 af[4], bf[4];
#pragma unroll
    for (int m = 0; m < 4; m++){
      int r = wrow + m * 16 + rb;
      int e = SWA ? ((u ^ (r & 7)) << 3) : (u << 3);
      af[m] = *(const u16x8*)&lA[r * lda + e];
    }
#pragma unroll
    for (int n = 0; n < 4; n++){
      int r = wcol + n * 16 + rb;
      int e = SWB ? ((u ^ (r & 7)) << 3) : (u << 3);
      bf[n] = *(const u16x8*)&lB[r * ldb + e];
    }
#pragma unroll
    for (int m = 0; m < 4; m++)
#pragma unroll
      for (int n = 0; n < 4; n++)
        mfma_bf16(acc[m][n], af[m], bf[n]);
  }
}

// ---------------- K0: x NCHW -> NHWC bf16 ----------------
__global__ __launch_bounds__(256) void k_t2b(const float* __restrict__ in, uint16_t* __restrict__ out){
  __shared__ float tile[64][33];   // [c][n]
  int b = blockIdx.z;
  int n0 = blockIdx.x * 32;
  int c0 = blockIdx.y * 64;
  int tx = threadIdx.x, ty = threadIdx.y;   // (32,8)
  const float* src = in + (size_t)b * CC * NN;
#pragma unroll
  for (int i = 0; i < 64; i += 8)
    tile[ty + i][tx] = src[(size_t)(c0 + ty + i) * NN + n0 + tx];
  __syncthreads();
  uint16_t* dst = out + (size_t)b * NN * CC;
#pragma unroll
  for (int i = 0; i < 32; i += 8){
    int r = ty + i;
    u16x2 o; o[0] = f2b(tile[tx * 2][r]); o[1] = f2b(tile[tx * 2 + 1][r]);
    *(u16x2*)&dst[(size_t)(n0 + r) * CC + c0 + tx * 2] = o;
  }
}

// ---------------- K1: 8x8 pooled slots + l2norm -> bf16 (vectorized) ----------------
__global__ __launch_bounds__(256) void k_pool(const uint16_t* __restrict__ xhwcb, uint16_t* __restrict__ slotsNb){
  int bs = blockIdx.x; int b = bs >> 6, s = bs & 63;
  int sy = (s >> 3) * 8, sx = (s & 7) * 8;
  int t = threadIdx.x;
  int c4 = t & 63, pg = t >> 6;      // channel-quad, pixel-group (16 px each)
  const uint16_t* base = xhwcb + (size_t)b * NN * CC;
  float a0 = 0.f, a1 = 0.f, a2 = 0.f, a3 = 0.f;
#pragma unroll
  for (int i = 0; i < 16; i++){
    int p = pg * 16 + i; int py = p >> 3, px = p & 7;
    u16x4 v = *(const u16x4*)&base[(size_t)((sy + py) * WW + sx + px) * CC + c4 * 4];
    a0 += b2f(v[0]); a1 += b2f(v[1]); a2 += b2f(v[2]); a3 += b2f(v[3]);
  }
  __shared__ float sm[4][64][4];
  sm[pg][c4][0] = a0; sm[pg][c4][1] = a1; sm[pg][c4][2] = a2; sm[pg][c4][3] = a3;
  __syncthreads();
  if (t < 64){
    float v0 = (sm[0][t][0] + sm[1][t][0] + sm[2][t][0] + sm[3][t][0]) * (1.0f / 64.0f);
    float v1 = (sm[0][t][1] + sm[1][t][1] + sm[2][t][1] + sm[3][t][1]) * (1.0f / 64.0f);
    float v2 = (sm[0][t][2] + sm[1][t][2] + sm[2][t][2] + sm[3][t][2]) * (1.0f / 64.0f);
    float v3 = (sm[0][t][3] + sm[1][t][3] + sm[2][t][3] + sm[3][t][3]) * (1.0f / 64.0f);
    float ss = waveSum(v0 * v0 + v1 * v1 + v2 * v2 + v3 * v3);
    float inv = 1.0f / fmaxf(sqrtf(ss), 1e-12f);
    u16x4 o; o[0] = f2b(v0 * inv); o[1] = f2b(v1 * inv); o[2] = f2b(v2 * inv); o[3] = f2b(v3 * inv);
    *(u16x4*)&slotsNb[(size_t)bs * CC + t * 4] = o;
  }
}

// ---- wave-per-row LayerNorm on bf16 (xa [+ xb]) -> bf16 (+ inv l2-norm | + padded-interior write) ----
__global__ __launch_bounds__(256) void k_ln_w(const uint16_t* __restrict__ xa, const uint16_t* __restrict__ xb,
                                              const float* __restrict__ w, const float* __restrict__ b,
                                              uint16_t* __restrict__ xoutb, float* __restrict__ rn,
                                              uint16_t* __restrict__ xn2p){
  int row = blockIdx.x * 4 + (threadIdx.x >> 6);
  int lane = threadIdx.x & 63;
  u16x4 va = *(const u16x4*)&xa[(size_t)row * CC + lane * 4];
  float v0 = b2f(va[0]), v1 = b2f(va[1]), v2 = b2f(va[2]), v3 = b2f(va[3]);
  if (xb){
    u16x4 vb = *(const u16x4*)&xb[(size_t)row * CC + lane * 4];
    v0 += b2f(vb[0]); v1 += b2f(vb[1]); v2 += b2f(vb[2]); v3 += b2f(vb[3]);
  }
  float mu = waveSum(v0 + v1 + v2 + v3) * (1.0f / CC);
  float d0 = v0 - mu, d1 = v1 - mu, d2 = v2 - mu, d3 = v3 - mu;
  float var = waveSum(d0 * d0 + d1 * d1 + d2 * d2 + d3 * d3) * (1.0f / CC);
  float inv = rsqrtf(var + 1e-5f);
  float4 wv = *(const float4*)&w[lane * 4];
  float4 bv = *(const float4*)&b[lane * 4];
  float x0 = d0 * inv * wv.x + bv.x;
  float x1 = d1 * inv * wv.y + bv.y;
  float x2 = d2 * inv * wv.z + bv.z;
  float x3 = d3 * inv * wv.w + bv.w;
  u16x4 o; o[0] = f2b(x0); o[1] = f2b(x1); o[2] = f2b(x2); o[3] = f2b(x3);
  *(u16x4*)&xoutb[(size_t)row * CC + lane * 4] = o;
  if (xn2p && lane < 16){
    int bb = row >> 12, n = row & 4095, y = n >> 6, x = n & 63;
    *(u16x4*)&xn2p[(((size_t)(bb * 66 + y + 1)) * 66 + x + 1) * 64 + lane * 4] = o;
  }
  if (rn){
    float ss = waveSum(x0 * x0 + x1 * x1 + x2 * x2 + x3 * x3);
    if (lane == 0) rn[row] = 1.0f / fmaxf(sqrtf(ss), 1e-12f);
  }
}

// ---------------- border zeros for padded image ----------------
__global__ __launch_bounds__(256) void k_zb(uint16_t* __restrict__ xn2p){
  int i = blockIdx.x * 256 + threadIdx.x;   // (b, j<260, c4<16)
  if (i >= 16 * 260 * 16) return;
  int c4 = i & 15; int rest = i >> 4;
  int j = rest % 260; int b = rest / 260;
  int py, px;
  if (j < 66){ py = 0; px = j; }
  else if (j < 132){ py = 65; px = j - 66; }
  else if (j < 196){ py = j - 132 + 1; px = 0; }
  else { py = j - 196 + 1; px = 65; }
  u16x4 z; z[0] = 0; z[1] = 0; z[2] = 0; z[3] = 0;
  *(u16x4*)&xn2p[(((size_t)(b * 66 + py)) * 66 + px) * 64 + c4 * 4] = z;
}

// ---------------- merged weight conversions (wi|wo|w1|w2|pconv|dwT) ----------------
__global__ __launch_bounds__(256) void k_cvtw(const float* __restrict__ wi, const float* __restrict__ wo,
                                              const float* __restrict__ w1, const float* __restrict__ w2,
                                              const float* __restrict__ pw, const float* __restrict__ dww,
                                              uint16_t* __restrict__ wib, uint16_t* __restrict__ wob,
                                              uint16_t* __restrict__ w1b, uint16_t* __restrict__ w2b,
                                              uint16_t* __restrict__ wp2, float* __restrict__ dwwT){
  int i = blockIdx.x * 256 + threadIdx.x;
  if (i < 163840){
    const float* src; uint16_t* dst; int off;
    if (i < 49152){ src = wi; dst = wib; off = i; }
    else if (i < 65536){ src = wo; dst = wob; off = i - 49152; }
    else if (i < 131072){ src = w1; dst = w1b; off = i - 65536; }
    else { src = w2; dst = w2b; off = i - 131072; }
    float4 v = ((const float4*)src)[off];
    u16x4 o;
    o[0] = f2b(v.x); o[1] = f2b(v.y); o[2] = f2b(v.z); o[3] = f2b(v.w);
    *(u16x4*)&dst[(size_t)off * 4] = o;
  } else if (i < 200704){
    int j = i - 163840;
    if (j < 64 * 576){
      int co = j / 576, r = j % 576, tap = r >> 6, ci = r & 63;
      wp2[j] = f2b(pw[(size_t)co * 576 + ci * 9 + tap]);
    }
  } else {
    int j = i - 200704;                         // dwwT[tap][ch] = dww[ch][tap]
    if (j < 9 * HID){
      int tap = j / HID, ch = j % HID;
      dwwT[j] = dww[(size_t)ch * 9 + tap];
    }
  }
}

// ---------------- logits GEMM + exp epilogue -> E bf16 [b][s][n] ----------------
__global__ __launch_bounds__(256) void k_logits_mfma(const uint16_t* __restrict__ slotsNb,
                                                     const uint16_t* __restrict__ xnb,
                                                     const float* __restrict__ rn,
                                                     const float* __restrict__ scale_p,
                                                     uint16_t* __restrict__ E){
  __shared__ uint16_t smem[20480];      // lA 64x64 | lB 256x64 ; reused as eT 64x264
  __shared__ float rnS[256];
  uint16_t* lA = smem;
  uint16_t* lB = smem + 64 * 64;
  int t = threadIdx.x, lane = t & 63, w = t >> 6;
  int b = blockIdx.y, n0 = blockIdx.x * 256;
  rnS[t] = rn[b * NN + n0 + t];
  f32x4 acc[4][4];
#pragma unroll
  for (int m = 0; m < 4; m++)
#pragma unroll
    for (int n = 0; n < 4; n++) acc[m][n] = (f32x4){0.f, 0.f, 0.f, 0.f};
  for (int kc = 0; kc < 4; kc++){
#pragma unroll
    for (int i = 0; i < 2; i++){
      int idx = i * 256 + t, row = idx >> 3, kp = idx & 7;
      *(u16x8*)&lA[row * 64 + swz8(row, kp)] = *(const u16x8*)&slotsNb[(size_t)(b * 64 + row) * 256 + kc * 64 + kp * 8];
    }
#pragma unroll
    for (int i = 0; i < 8; i++){
      int idx = i * 256 + t, row = idx >> 3, kp = idx & 7;
      *(u16x8*)&lB[row * 64 + swz8(row, kp)] = *(const u16x8*)&xnb[((size_t)b * NN + n0 + row) * 256 + kc * 64 + kp * 8];
    }
    __syncthreads();
    mma_core<1, 1>(lA, 64, lB, 64, acc, 0, w * 64, lane);
    __syncthreads();
  }
  float scale = scale_p[0];
  int rb4 = (lane >> 4) * 4, cb = lane & 15;
#pragma unroll
  for (int m = 0; m < 4; m++)
#pragma unroll
    for (int n = 0; n < 4; n++)
#pragma unroll
      for (int j = 0; j < 4; j++){
        int s = m * 16 + rb4 + j, nl = w * 64 + n * 16 + cb;
        smem[s * 264 + nl] = f2b(__expf(acc[m][n][j] * scale * rnS[nl]));
      }
  __syncthreads();
#pragma unroll
  for (int i = 0; i < 8; i++){
    int idx = i * 256 + t, row = idx >> 5, cseg = idx & 31;
    *(u16x8*)&E[((size_t)b * 64 + row) * NN + n0 + cseg * 8] = *(const u16x8*)&smem[row * 264 + cseg * 8];
  }
}

// ---------------- z1: invz1[b,s] = 1 / sum_n E (vectorized) ----------------
__global__ __launch_bounds__(256) void k_z1(const uint16_t* __restrict__ E, float* __restrict__ invz1){
  int bs = blockIdx.x, t = threadIdx.x;
  u16x8 v0 = *(const u16x8*)&E[(size_t)bs * NN + t * 16];
  u16x8 v1 = *(const u16x8*)&E[(size_t)bs * NN + t * 16 + 8];
  float s = 0.f;
#pragma unroll
  for (int i = 0; i < 8; i++) s += b2f(v0[i]) + b2f(v1[i]);
  __shared__ float s4[4];
  float z = blockSum256(s, s4);
  if (t == 0) invz1[bs] = 1.0f / z;
}

// ---------------- slots GEMM (4-way K-split partials) ----------------
__global__ __launch_bounds__(256) void k_slots_mfma(const uint16_t* __restrict__ E,
                                                    const uint16_t* __restrict__ xnb,
                                                    float* __restrict__ part){
  __shared__ uint16_t lA[64 * 64];
  __shared__ uint16_t lB[256 * 72];
  int t = threadIdx.x, lane = t & 63, w = t >> 6;
  int ks = blockIdx.x, b = blockIdx.y;
  f32x4 acc[4][4];
#pragma unroll
  for (int m = 0; m < 4; m++)
#pragma unroll
    for (int n = 0; n < 4; n++) acc[m][n] = (f32x4){0.f, 0.f, 0.f, 0.f};
  for (int kc = 0; kc < 16; kc++){
    int n0 = ks * 1024 + kc * 64;
#pragma unroll
    for (int i = 0; i < 2; i++){
      int idx = i * 256 + t, row = idx >> 3, kp = idx & 7;
      *(u16x8*)&lA[row * 64 + swz8(row, kp)] = *(const u16x8*)&E[((size_t)b * 64 + row) * NN + n0 + kp * 8];
    }
#pragma unroll
    for (int i = 0; i < 8; i++){
      int idx = i * 256 + t, nrow = idx >> 5, cseg = idx & 31;
      u16x8 v = *(const u16x8*)&xnb[((size_t)b * NN + n0 + nrow) * 256 + cseg * 8];
#pragma unroll
      for (int j = 0; j < 8; j++) lB[(cseg * 8 + j) * 72 + nrow] = v[j];
    }
    __syncthreads();
    mma_core<1, 0>(lA, 64, lB, 72, acc, 0, w * 64, lane);
    __syncthreads();
  }
  int rb4 = (lane >> 4) * 4, cb = lane & 15;
#pragma unroll
  for (int m = 0; m < 4; m++)
#pragma unroll
    for (int n = 0; n < 4; n++)
#pragma unroll
      for (int j = 0; j < 4; j++){
        int s = m * 16 + rb4 + j, c = w * 64 + n * 16 + cb;
        part[(((size_t)b * 4 + ks) * 64 + s) * 256 + c] = acc[m][n][j];
      }
}

// ---------------- fold partials -> slots bf16 ----------------
__global__ __launch_bounds__(256) void k_fold(const float* __restrict__ part, const float* __restrict__ invz1,
                                              uint16_t* __restrict__ slotsb){
  int i = blockIdx.x * 256 + threadIdx.x;
  int row = i >> 6, c4 = i & 63;
  int b = row >> 6, s = row & 63;
  float4 a = {0.f, 0.f, 0.f, 0.f};
#pragma unroll
  for (int p = 0; p < 4; p++){
    float4 v = *(const float4*)&part[(((size_t)b * 4 + p) * 64 + s) * 256 + c4 * 4];
    a.x += v.x; a.y += v.y; a.z += v.z; a.w += v.w;
  }
  float iz = invz1[row];
  u16x4 o; o[0] = f2b(a.x * iz); o[1] = f2b(a.y * iz); o[2] = f2b(a.z * iz); o[3] = f2b(a.w * iz);
  *(u16x4*)&slotsb[(size_t)row * 256 + c4 * 4] = o;
}

// ---------------- qkv GEMM: [1024 x 768] = slotsb @ wib^T + bi (fp32 out) ----------------
__global__ __launch_bounds__(256) void k_gemm_qkv(const uint16_t* __restrict__ slotsb,
                                                  const uint16_t* __restrict__ wib,
                                                  const float* __restrict__ bi,
                                                  float* __restrict__ qkv){
  __shared__ uint16_t lA[128 * 64];
  __shared__ uint16_t lB[128 * 64];
  int t = threadIdx.x, lane = t & 63, w = t >> 6;
  int wrow = (w >> 1) * 64, wcol = (w & 1) * 64;
  int BR = blockIdx.x * 128, BC = blockIdx.y * 128;
  f32x4 acc[4][4];
#pragma unroll
  for (int m = 0; m < 4; m++)
#pragma unroll
    for (int n = 0; n < 4; n++) acc[m][n] = (f32x4){0.f, 0.f, 0.f, 0.f};
  for (int kc = 0; kc < 4; kc++){
#pragma unroll
    for (int i = 0; i < 4; i++){
      int idx = i * 256 + t, row = idx >> 3, kp = idx & 7;
      *(u16x8*)&lA[row * 64 + swz8(row, kp)] = *(const u16x8*)&slotsb[(size_t)(BR + row) * 256 + kc * 64 + kp * 8];
      *(u16x8*)&lB[row * 64 + swz8(row, kp)] = *(const u16x8*)&wib[(size_t)(BC + row) * 256 + kc * 64 + kp * 8];
    }
    __syncthreads();
    mma_core<1, 1>(lA, 64, lB, 64, acc, wrow, wcol, lane);
    __syncthreads();
  }
  int rb4 = (lane >> 4) * 4, cb = lane & 15;
#pragma unroll
  for (int m = 0; m < 4; m++)
#pragma unroll
    for (int n = 0; n < 4; n++){
      int c = BC + wcol + n * 16 + cb;
      float bias = bi[c];
#pragma unroll
      for (int j = 0; j < 4; j++)
        qkv[(size_t)(BR + wrow + m * 16 + rb4 + j) * 768 + c] = acc[m][n][j] + bias;
    }
}

// ---------------- per (b,h) attention over S=64 -> aob bf16 ----------------
__global__ __launch_bounds__(256) void k_attn(const float* __restrict__ qkv, uint16_t* __restrict__ aob){
  int b = blockIdx.x >> 3, h = blockIdx.x & 7;
  __shared__ float lq[64][33], lk[64][33], lv[64][33];
  __shared__ float sc[64][65];
  int t = threadIdx.x;
  for (int idx = t; idx < 64 * 32; idx += 256){
    int s = idx >> 5, d = idx & 31;
    const float* base = qkv + ((size_t)b * SS + s) * 768 + h * DH + d;
    lq[s][d] = base[0];
    lk[s][d] = base[256];
    lv[s][d] = base[512];
  }
  __syncthreads();
  const float rs = 0.17677669529663687f;
  for (int idx = t; idx < 64 * 64; idx += 256){
    int qq = idx >> 6, kk = idx & 63;
    float a = 0.f;
#pragma unroll
    for (int d = 0; d < 32; d++) a += lq[qq][d] * lk[kk][d];
    sc[qq][kk] = a * rs;
  }
  __syncthreads();
  {
    int r = t >> 2, sub = t & 3;
    float m = -1e30f;
#pragma unroll
    for (int k = sub * 16; k < sub * 16 + 16; k++) m = fmaxf(m, sc[r][k]);
    m = fmaxf(m, __shfl_xor(m, 1, 64));
    m = fmaxf(m, __shfl_xor(m, 2, 64));
    float z = 0.f;
#pragma unroll
    for (int k = sub * 16; k < sub * 16 + 16; k++){
      float e = __expf(sc[r][k] - m); sc[r][k] = e; z += e;
    }
    z += __shfl_xor(z, 1, 64);
    z += __shfl_xor(z, 2, 64);
    float iv = 1.0f / z;
#pragma unroll
    for (int k = sub * 16; k < sub * 16 + 16; k++) sc[r][k] *= iv;
  }
  __syncthreads();
  for (int idx = t; idx < 64 * 32; idx += 256){
    int qq = idx >> 5, d = idx & 31;
    float a = 0.f;
#pragma unroll
    for (int k = 0; k < 64; k++) a += sc[qq][k] * lv[k][d];
    aob[((size_t)b * SS + qq) * CC + h * DH + d] = f2b(a);
  }
}

// ---------------- oproj GEMM: sl2T[b][c][s] = (aob @ wob^T + bo)^T bf16 ----------------
__global__ __launch_bounds__(256) void k_gemm_oproj(const uint16_t* __restrict__ aob,
                                                    const uint16_t* __restrict__ wob,
                                                    const float* __restrict__ bo,
                                                    uint16_t* __restrict__ sl2Tb){
  __shared__ uint16_t lA[128 * 64];
  __shared__ uint16_t lB[128 * 64];
  int t = threadIdx.x, lane = t & 63, w = t >> 6;
  int wrow = (w >> 1) * 64, wcol = (w & 1) * 64;
  int BR = blockIdx.x * 128, BC = blockIdx.y * 128;
  f32x4 acc[4][4];
#pragma unroll
  for (int m = 0; m < 4; m++)
#pragma unroll
    for (int n = 0; n < 4; n++) acc[m][n] = (f32x4){0.f, 0.f, 0.f, 0.f};
  for (int kc = 0; kc < 4; kc++){
#pragma unroll
    for (int i = 0; i < 4; i++){
      int idx = i * 256 + t, row = idx >> 3, kp = idx & 7;
      *(u16x8*)&lA[row * 64 + swz8(row, kp)] = *(const u16x8*)&aob[(size_t)(BR + row) * 256 + kc * 64 + kp * 8];
      *(u16x8*)&lB[row * 64 + swz8(row, kp)] = *(const u16x8*)&wob[(size_t)(BC + row) * 256 + kc * 64 + kp * 8];
    }
    __syncthreads();
    mma_core<1, 1>(lA, 64, lB, 64, acc, wrow, wcol, lane);
    __syncthreads();
  }
  int rb4 = (lane >> 4) * 4, cb = lane & 15;
#pragma unroll
  for (int m = 0; m < 4; m++)
#pragma unroll
    for (int n = 0; n < 4; n++){
      int c = BC + wcol + n * 16 + cb;
      float bias = bo[c];
#pragma unroll
      for (int j = 0; j < 4; j++){
        int r = BR + wrow + m * 16 + rb4 + j;
        int b = r >> 6, s = r & 63;
        sl2Tb[((size_t)b * 256 + c) * 64 + s] = f2b(acc[m][n][j] + bias);
      }
    }
}

// ---------------- mix GEMM (pt fused): mixb[n][c] = (E^T[n][s]/z2[n]) @ sl2T[c][s] ----------------
__global__ __launch_bounds__(256) void k_mix(const uint16_t* __restrict__ E, const uint16_t* __restrict__ sl2Tb,
                                             uint16_t* __restrict__ mixb){
  __shared__ uint16_t lA[128 * 72];    // E^T tile [n_local][s] (padded stride, no swizzle)
  __shared__ uint16_t lB[128 * 64];    // sl2T rows [c][s] (swizzled)
  __shared__ float z2S[128];
  int t = threadIdx.x, lane = t & 63, w = t >> 6;
  int wrow = (w >> 1) * 64, wcol = (w & 1) * 64;
  int BR = blockIdx.x * 128, BC = blockIdx.y * 128, b = blockIdx.z;
#pragma unroll
  for (int i = 0; i < 4; i++){
    int idx = i * 256 + t; int s = idx >> 4, n8 = (idx & 15) * 8;
    u16x8 v = *(const u16x8*)&E[((size_t)b * 64 + s) * NN + BR + n8];
#pragma unroll
    for (int j = 0; j < 8; j++) lA[(n8 + j) * 72 + s] = v[j];
  }
#pragma unroll
  for (int i = 0; i < 4; i++){
    int idx = i * 256 + t, row = idx >> 3, kp = idx & 7;
    *(u16x8*)&lB[row * 64 + swz8(row, kp)] = *(const u16x8*)&sl2Tb[((size_t)b * 256 + BC + row) * 64 + kp * 8];
  }
  __syncthreads();
  if (t < 128){
    float s = 0.f;
#pragma unroll
    for (int k2 = 0; k2 < 64; k2++) s += b2f(lA[t * 72 + k2]);
    z2S[t] = 1.0f / s;
  }
  __syncthreads();
  f32x4 acc[4][4];
#pragma unroll
  for (int m = 0; m < 4; m++)
#pragma unroll
    for (int n = 0; n < 4; n++) acc[m][n] = (f32x4){0.f, 0.f, 0.f, 0.f};
  mma_core<0, 1>(lA, 72, lB, 64, acc, wrow, wcol, lane);
  int rb4 = (lane >> 4) * 4, cb = lane & 15;
#pragma unroll
  for (int m = 0; m < 4; m++)
#pragma unroll
    for (int n = 0; n < 4; n++)
#pragma unroll
      for (int j = 0; j < 4; j++){
        int lrow = wrow + m * 16 + rb4 + j;
        size_t gi = ((size_t)b * NN + BR + lrow) * 256 + BC + wcol + n * 16 + cb;
        mixb[gi] = f2b(acc[m][n][j] * z2S[lrow]);
      }
}

// ---------------- pconv as 9-tap MFMA GEMM (g2l16 + pre-swizzled source) ----------------
__global__ __launch_bounds__(256) void k_pconv_mfma(const uint16_t* __restrict__ xn2p,
                                                    const uint16_t* __restrict__ wp2,
                                                    uint16_t* __restrict__ pcb){
  __shared__ uint16_t lA[256 * 64];
  __shared__ uint16_t lB[64 * 64];
  int t = threadIdx.x, lane = t & 63, w = t >> 6;
  int wrow = w * 64;
  int BR = blockIdx.x * 256;
  f32x4 acc[4][4];
#pragma unroll
  for (int m = 0; m < 4; m++)
#pragma unroll
    for (int n = 0; n < 4; n++) acc[m][n] = (f32x4){0.f, 0.f, 0.f, 0.f};
  for (int tap = 0; tap < 9; tap++){
    int dy = tap / 3 - 1, dx = tap % 3 - 1;
#pragma unroll
    for (int i = 0; i < 8; i++){
      int q = (w * 8 + i) * 64 + lane;
      int row = q >> 3, kpe = swz8(row, q & 7);
      int r = BR + row;
      int b = r >> 12, n = r & 4095, y = n >> 6, x = n & 63;
      size_t p = ((size_t)(b * 66 + (y + 1 + dy)) * 66 + (x + 1 + dx)) * 64 + kpe;
      g2l16(&xn2p[p], &lA[(w * 8 + i) * 512]);
    }
#pragma unroll
    for (int i = 0; i < 2; i++){
      int q = (w * 2 + i) * 64 + lane;
      int row = q >> 3, kpe = swz8(row, q & 7);
      g2l16(&wp2[(size_t)row * 576 + tap * 64 + kpe], &lB[(w * 2 + i) * 512]);
    }
    __syncthreads();
    mma_core<1, 1>(lA, 64, lB, 64, acc, wrow, 0, lane);
    __syncthreads();
  }
  int rb4 = (lane >> 4) * 4, cb = lane & 15;
#pragma unroll
  for (int m = 0; m < 4; m++)
#pragma unroll
    for (int n = 0; n < 4; n++)
#pragma unroll
      for (int j = 0; j < 4; j++)
        pcb[(size_t)(BR + wrow + m * 16 + rb4 + j) * 64 + (n * 16 + cb)] = f2b(acc[m][n][j]);
}

// ------- lin1 MFMA + gelu -> Y1b/Y2b (8-wave 256x128 tile; A via LDS, B direct from L2) -------
__global__ __launch_bounds__(512) void k_lin1_mfma(const uint16_t* __restrict__ pcb,
                                                   const uint16_t* __restrict__ xn2b,
                                                   const uint16_t* __restrict__ w1b,
                                                   const float* __restrict__ b1,
                                                   uint16_t* __restrict__ Y1b, uint16_t* __restrict__ Y2b){
  __shared__ uint16_t lA[256 * 64];   // 32 KB only -> 4 blocks/CU (wave-slot capped)
  int t = threadIdx.x, lane = t & 63, w = t >> 6;     // 8 waves
  int wrow = (w >> 1) * 64, wcol = (w & 1) * 64;      // 4M x 2N
  int bid = blockIdx.x;
  int xcd = bid & 7, i5 = bid >> 3;         // i5 in [0,256)
  int BR = (xcd * 32 + (i5 >> 3)) * 256;    // 32 row-panels per XCD
  int BC = (i5 & 7) * 128;
  const int rb = lane & 15, ub = lane >> 4;
  f32x4 acc[4][4];
#pragma unroll
  for (int m = 0; m < 4; m++)
#pragma unroll
    for (int n = 0; n < 4; n++) acc[m][n] = (f32x4){0.f, 0.f, 0.f, 0.f};
  for (int kc = 0; kc < 4; kc++){
#pragma unroll
    for (int i = 0; i < 4; i++){        // A: 256x64 = 32 units, 4/wave
      int q = (w * 4 + i) * 64 + lane;
      int row = q >> 3, kpe = swz8(row, q & 7);
      size_t gr = (size_t)(BR + row);
      const uint16_t* src = (kc == 0) ? &pcb[gr * 64 + kpe] : &xn2b[gr * 256 + kc * 64 + kpe];
      g2l16(src, &lA[(w * 4 + i) * 512]);
    }
    __syncthreads();
#pragma unroll
    for (int ks = 0; ks < 2; ks++){
      const int u = ks * 4 + ub;
      u16x8 af[4], bf[4];
#pragma unroll
      for (int m = 0; m < 4; m++){
        int r = wrow + m * 16 + rb;
        af[m] = *(const u16x8*)&lA[r * 64 + ((u ^ (r & 7)) << 3)];
      }
#pragma unroll
      for (int n = 0; n < 4; n++)       // B direct: L2-resident weights
        bf[n] = *(const u16x8*)&w1b[(size_t)(BC + wcol + n * 16 + rb) * 256 + kc * 64 + u * 8];
#pragma unroll
      for (int m = 0; m < 4; m++)
#pragma unroll
        for (int n = 0; n < 4; n++)
          mfma_bf16(acc[m][n], af[m], bf[n]);
    }
    __syncthreads();
  }
  int rb4 = (lane >> 4) * 4, cb = lane & 15;
#pragma unroll
  for (int m = 0; m < 4; m++){
#pragma unroll
    for (int n = 0; n < 4; n++){
      int c = BC + wcol + n * 16 + cb;
      float bias = b1[c];
#pragma unroll
      for (int j = 0; j < 4; j++){
        size_t r = (size_t)(BR + wrow + m * 16 + rb4 + j);
        uint16_t h = f2b(gelu_fast(acc[m][n][j] + bias));
        if (c < HID) Y1b[r * HID + c] = h;
        else         Y2b[r * HID + (c - HID)] = h;
      }
    }
  }
}

// ------- dwconv 3x3 + gelu, fused *Y2 — LDS-tiled: block = 16px (row seg) × 128ch -------
// grid (256 = 64rows × 4segs, 4 ch-chunks, BB). Halo tile 3×18×128 staged once; zero borders.
__global__ __launch_bounds__(256) void k_dwconv(const uint16_t* __restrict__ Y1b,
                                                const float* __restrict__ dwwT,   // [tap][512]
                                                const float* __restrict__ dwb,
                                                const uint16_t* __restrict__ Y2b,
                                                uint16_t* __restrict__ YPb){
  __shared__ uint16_t lds[3 * 18 * 136];   // px-stride 136 elems (272B) -> bank-shift 4/px
  int b = blockIdx.z, chunk = blockIdx.y;
  int y = blockIdx.x >> 2, seg = blockIdx.x & 3;
  int x0 = seg * 16;
  int t = threadIdx.x;
  const uint16_t* base = Y1b + (size_t)b * NN * HID + chunk * 128;
  const u16x8 z = {0, 0, 0, 0, 0, 0, 0, 0};
#pragma unroll
  for (int i = 0; i < 4; i++){
    int idx = i * 256 + t;
    if (idx < 864){                         // 3 rows × 18 px × 16 ch-groups
      int g8 = idx & 15, rest = idx >> 4;
      int c = rest % 18, r = rest / 18;
      int ry = y + r - 1, xx = x0 + c - 1;
      u16x8 v = z;
      if (ry >= 0 && ry < HH && xx >= 0 && xx < WW)
        v = *(const u16x8*)&base[(size_t)(ry * WW + xx) * HID + g8 * 8];
      *(u16x8*)&lds[(r * 18 + c) * 136 + g8 * 8] = v;
    }
  }
  __syncthreads();
  int px = t >> 4, g8 = t & 15;
  int cg = chunk * 128 + g8 * 8;
  int n = y * WW + x0 + px;
  u16x8 y2 = *(const u16x8*)&Y2b[((size_t)b * NN + n) * HID + cg];
  float acc[8];
  {
    float4 b0 = *(const float4*)&dwb[cg];
    float4 b1 = *(const float4*)&dwb[cg + 4];
    acc[0] = b0.x; acc[1] = b0.y; acc[2] = b0.z; acc[3] = b0.w;
    acc[4] = b1.x; acc[5] = b1.y; acc[6] = b1.z; acc[7] = b1.w;
  }
#pragma unroll
  for (int r = 0; r < 3; r++)
#pragma unroll
    for (int dx = 0; dx < 3; dx++){
      u16x8 v = *(const u16x8*)&lds[(r * 18 + px + dx) * 136 + g8 * 8];
      const float* wt = &dwwT[(r * 3 + dx) * HID + cg];
      float4 w0 = *(const float4*)wt;
      float4 w1 = *(const float4*)(wt + 4);
      acc[0] += b2f(v[0]) * w0.x; acc[1] += b2f(v[1]) * w0.y;
      acc[2] += b2f(v[2]) * w0.z; acc[3] += b2f(v[3]) * w0.w;
      acc[4] += b2f(v[4]) * w1.x; acc[5] += b2f(v[5]) * w1.y;
      acc[6] += b2f(v[6]) * w1.z; acc[7] += b2f(v[7]) * w1.w;
    }
  u16x8 o;
#pragma unroll
  for (int j = 0; j < 8; j++) o[j] = f2b(gelu_fast(acc[j]) * b2f(y2[j]));
  *(u16x8*)&YPb[((size_t)b * NN + n) * HID + cg] = o;
}

// ------- lin2 MFMA: deltab = YP @ w2^T + b2 (8-wave 256x128 tile; A via LDS, B direct) -------
__global__ __launch_bounds__(512) void k_lin2_mfma(const uint16_t* __restrict__ YPb,
                                                   const uint16_t* __restrict__ w2b,
                                                   const float* __restrict__ b2,
                                                   uint16_t* __restrict__ deltab){
  __shared__ uint16_t lA[256 * 64];
  int t = threadIdx.x, lane = t & 63, w = t >> 6;
  int wrow = (w >> 1) * 64, wcol = (w & 1) * 64;
  int bid = blockIdx.x;
  int xcd = bid & 7, i5 = bid >> 3;         // i5 in [0,64)
  int BR = (xcd * 32 + (i5 >> 1)) * 256;
  int BC = (i5 & 1) * 128;
  const int rb = lane & 15, ub = lane >> 4;
  f32x4 acc[4][4];
#pragma unroll
  for (int m = 0; m < 4; m++)
#pragma unroll
    for (int n = 0; n < 4; n++) acc[m][n] = (f32x4){0.f, 0.f, 0.f, 0.f};
  for (int kc = 0; kc < 8; kc++){
#pragma unroll
    for (int i = 0; i < 4; i++){
      int q = (w * 4 + i) * 64 + lane;
      int row = q >> 3, kpe = swz8(row, q & 7);
      g2l16(&YPb[(size_t)(BR + row) * HID + kc * 64 + kpe], &lA[(w * 4 + i) * 512]);
    }
    __syncthreads();
#pragma unroll
    for (int ks = 0; ks < 2; ks++){
      const int u = ks * 4 + ub;
      u16x8 af[4], bf[4];
#pragma unroll
      for (int m = 0; m < 4; m++){
        int r = wrow + m * 16 + rb;
        af[m] = *(const u16x8*)&lA[r * 64 + ((u ^ (r & 7)) << 3)];
      }
#pragma unroll
      for (int n = 0; n < 4; n++)
        bf[n] = *(const u16x8*)&w2b[(size_t)(BC + wcol + n * 16 + rb) * 512 + kc * 64 + u * 8];
#pragma unroll
      for (int m = 0; m < 4; m++)
#pragma unroll
        for (int n = 0; n < 4; n++)
          mfma_bf16(acc[m][n], af[m], bf[n]);
    }
    __syncthreads();
  }
  int rb4 = (lane >> 4) * 4, cb = lane & 15;
#pragma unroll
  for (int m = 0; m < 4; m++){
#pragma unroll
    for (int n = 0; n < 4; n++){
      int c = BC + wcol + n * 16 + cb;
      float bias = b2[c];
#pragma unroll
      for (int j = 0; j < 4; j++){
        size_t gr = (size_t)(BR + wrow + m * 16 + rb4 + j);
        deltab[gr * CC + c] = f2b(acc[m][n][j] + bias);
      }
    }
  }
}

// ---------------- final: v = mixb+deltab; out0 = xhwcb + v (NCHW), out1 = -v ----------------
__global__ __launch_bounds__(256) void k_final2(const uint16_t* __restrict__ mixb,
                                                const uint16_t* __restrict__ deltab,
                                                const uint16_t* __restrict__ xhwcb,
                                                float* __restrict__ out){
  __shared__ float t0[64 * 68];
  __shared__ float t1[64 * 68];
  int b = blockIdx.z;
  int n0 = blockIdx.x * 64, c0 = blockIdx.y * 64;
  int t = threadIdx.x;
#pragma unroll
  for (int i = 0; i < 4; i++){
    int idx = i * 256 + t, row = idx >> 4, c4 = idx & 15;
    size_t gp = ((size_t)b * NN + n0 + row) * CC + c0 + c4 * 4;
    u16x4 m = *(const u16x4*)&mixb[gp];
    u16x4 d = *(const u16x4*)&deltab[gp];
    u16x4 xh = *(const u16x4*)&xhwcb[gp];
    f32x4 v0, v1;
#pragma unroll
    for (int j = 0; j < 4; j++){
      float v = b2f(m[j]) + b2f(d[j]);
      v0[j] = b2f(xh[j]) + v;
      v1[j] = -v;
    }
    *(f32x4*)&t0[row * 68 + c4 * 4] = v0;
    *(f32x4*)&t1[row * 68 + c4 * 4] = v1;
  }
  __syncthreads();
  int cl = t >> 2, seg = t & 3;
  float* o1 = out + (size_t)BB * CC * NN;
  size_t gbase = ((size_t)(b * CC + c0 + cl)) * NN + n0 + seg * 16;
#pragma unroll
  for (int k = 0; k < 4; k++){
    float4 a, c;
    a.x = t0[(seg * 16 + k * 4 + 0) * 68 + cl];
    a.y = t0[(seg * 16 + k * 4 + 1) * 68 + cl];
    a.z = t0[(seg * 16 + k * 4 + 2) * 68 + cl];
    a.w = t0[(seg * 16 + k * 4 + 3) * 68 + cl];
    c.x = t1[(seg * 16 + k * 4 + 0) * 68 + cl];
    c.y = t1[(seg * 16 + k * 4 + 1) * 68 + cl];
    c.z = t1[(seg * 16 + k * 4 + 2) * 68 + cl];
    c.w = t1[(seg * 16 + k * 4 + 3) * 68 + cl];
    *(float4*)&out[gbase + k * 4] = a;
    *(float4*)&o1[gbase + k * 4] = c;
  }
}

extern "C" void kernel_launch(void* const* d_in, const int* in_sizes, int n_in,
                              void* d_out, int out_size, void* d_ws, size_t ws_size,
                              hipStream_t stream){
  const float* x       = (const float*)d_in[0];
  const float* scale_p = (const float*)d_in[1];
  const float* n1w     = (const float*)d_in[2];
  const float* n1b     = (const float*)d_in[3];
  const float* wi      = (const float*)d_in[4];
  const float* bi      = (const float*)d_in[5];
  const float* wo      = (const float*)d_in[6];
  const float* bo      = (const float*)d_in[7];
  const float* n2w     = (const float*)d_in[8];
  const float* n2b     = (const float*)d_in[9];
  const float* pw      = (const float*)d_in[10];
  const float* w1      = (const float*)d_in[11];
  const float* b1      = (const float*)d_in[12];
  const float* dww     = (const float*)d_in[13];
  const float* dwb     = (const float*)d_in[14];
  const float* w2      = (const float*)d_in[15];
  const float* b2      = (const float*)d_in[16];

  // ---- workspace layout (float units) — total ≈ 417 MB, ws = 512 MiB (fill evidence r4-r8) ----
  float* base = (float*)d_ws;
  size_t off = 0;
  float* part = base + off; off += (size_t)BB * 8 * SS * CC;            // (8-split capacity kept)
  float* QKV  = base + off; off += (size_t)BB * SS * 3 * CC;
  float* RN   = base + off; off += (size_t)BB * NN;
  float* IZ1  = base + off; off += (size_t)BB * SS;
  float* dwwT = base + off; off += (size_t)9 * HID;                     // transposed dw weights
  uint16_t* slotsNb = (uint16_t*)(base + off); off += (size_t)BB * SS * CC / 2;
  uint16_t* slotsb  = (uint16_t*)(base + off); off += (size_t)BB * SS * CC / 2;
  uint16_t* aob     = (uint16_t*)(base + off); off += (size_t)BB * SS * CC / 2;
  uint16_t* sl2Tb   = (uint16_t*)(base + off); off += (size_t)BB * CC * SS / 2;
  uint16_t* xhwcb   = (uint16_t*)(base + off); off += (size_t)BB * NN * CC / 2;    // 33.5 MB
  uint16_t* xnb     = (uint16_t*)(base + off); off += (size_t)BB * NN * CC / 2;    // 33.5 MB
  uint16_t* mixb    = (uint16_t*)(base + off); off += (size_t)BB * NN * CC / 2;    // 33.5 MB
  uint16_t* deltab  = (uint16_t*)(base + off); off += (size_t)BB * NN * CC / 2;    // 33.5 MB
  uint16_t* E       = (uint16_t*)(base + off); off += (size_t)BB * SS * NN / 2;    // 8.4 MB
  uint16_t* w1b     = (uint16_t*)(base + off); off += (size_t)(2 * HID) * CC / 2;
  uint16_t* w2b     = (uint16_t*)(base + off); off += (size_t)CC * HID / 2;
  uint16_t* wib     = (uint16_t*)(base + off); off += (size_t)(3 * CC) * CC / 2;
  uint16_t* wob     = (uint16_t*)(base + off); off += (size_t)CC * CC / 2;
  uint16_t* wp2     = (uint16_t*)(base + off); off += (size_t)64 * 576 / 2 + 16;
  uint16_t* Y1b     = (uint16_t*)(base + off); off += (size_t)BB * NN * HID / 2;   // 67.1 MB
  uint16_t* Y2b     = (uint16_t*)(base + off); off += (size_t)BB * NN * HID / 2;   // 67.1 MB
  uint16_t* YPb     = (uint16_t*)(base + off); off += (size_t)BB * NN * HID / 2;   // 67.1 MB
  uint16_t* xn2b    = (uint16_t*)(base + off); off += (size_t)BB * NN * CC / 2;    // 33.5 MB
  uint16_t* xn2p    = (uint16_t*)(base + off); off += (size_t)BB * 66 * 66 * 64 / 2; // 8.9 MB
  uint16_t* pcb     = (uint16_t*)(base + off); off += (size_t)BB * NN * 64 / 2;    // 8.4 MB
  if (ws_size < off * sizeof(float)) return;
  float* OUT = (float*)d_out;

  dim3 tb2(32, 8);
  // ---- slot-mixing phase ----
  k_t2b<<<dim3(NN / 32, CC / 64, BB), tb2, 0, stream>>>(x, xhwcb);
  k_pool<<<BB * SS, 256, 0, stream>>>(xhwcb, slotsNb);
  k_ln_w<<<BB * NN / 4, 256, 0, stream>>>(xhwcb, (const uint16_t*)nullptr, n1w, n1b, xnb, RN,
                                          (uint16_t*)nullptr);
  k_cvtw<<<803, 256, 0, stream>>>(wi, wo, w1, w2, pw, dww, wib, wob, w1b, w2b, wp2, dwwT);
  k_zb<<<(16 * 260 * 16 + 255) / 256, 256, 0, stream>>>(xn2p);
  k_logits_mfma<<<dim3(NN / 256, BB), 256, 0, stream>>>(slotsNb, xnb, RN, scale_p, E);
  k_z1<<<BB * SS, 256, 0, stream>>>(E, IZ1);
  k_slots_mfma<<<dim3(4, BB), 256, 0, stream>>>(E, xnb, part);
  k_fold<<<(BB * SS * CC / 4) / 256, 256, 0, stream>>>(part, IZ1, slotsb);
  k_gemm_qkv<<<dim3(8, 6), 256, 0, stream>>>(slotsb, wib, bi, QKV);
  k_attn<<<BB * NHEAD, 256, 0, stream>>>(QKV, aob);
  k_gemm_oproj<<<dim3(8, 2), 256, 0, stream>>>(aob, wob, bo, sl2Tb);
  k_mix<<<dim3(NN / 128, CC / 128, BB), 256, 0, stream>>>(E, sl2Tb, mixb);
  // ---- FRFN phase (de-chunked) ----
  k_ln_w<<<BB * NN / 4, 256, 0, stream>>>(xhwcb, mixb, n2w, n2b, xn2b, (float*)nullptr, xn2p);
  k_pconv_mfma<<<BB * NN / 256, 256, 0, stream>>>(xn2p, wp2, pcb);
  k_lin1_mfma<<<2048, 512, 0, stream>>>(pcb, xn2b, w1b, b1, Y1b, Y2b);
  k_dwconv<<<dim3(256, 4, BB), 256, 0, stream>>>(Y1b, dwwT, dwb, Y2b, YPb);
  k_lin2_mfma<<<512, 512, 0, stream>>>(YPb, w2b, b2, deltab);
  // ---- fused residual/transpose output ----
  k_final2<<<dim3(NN / 64, CC / 64, BB), 256, 0, stream>>>(mixb, deltab, xhwcb, OUT);
}

// Round 17
// 518.543 us; speedup vs baseline: 1.1848x; 1.1848x over previous
//
#include <hip/hip_runtime.h>
#include <hip/hip_bf16.h>
#include <stdint.h>
#include <math.h>

#define BB 16
#define CC 256
#define HH 64
#define WW 64
#define NN 4096   // HH*WW
#define SS 64
#define NHEAD 8
#define DH 32
#define HID 512
#define DC 64

typedef float    f32x4  __attribute__((ext_vector_type(4)));
typedef uint16_t u16x8  __attribute__((ext_vector_type(8)));
typedef uint16_t u16x4  __attribute__((ext_vector_type(4)));
typedef uint16_t u16x2  __attribute__((ext_vector_type(2)));

// tanh-approx gelu (|err| < ~1e-3 abs; budget absmax 0.108 >> this)
__device__ __forceinline__ float gelu_fast(float x){
  float u = 0.7978845608028654f * (x + 0.044715f * x * x * x);
  float e = __expf(2.0f * u);
  float th = 1.0f - 2.0f / (e + 1.0f);
  return 0.5f * x * (1.0f + th);
}
__device__ __forceinline__ uint16_t f2b(float f){
  union { float f; uint32_t u; } v; v.f = f;
  uint32_t r = v.u + 0x7fffu + ((v.u >> 16) & 1u);
  return (uint16_t)(r >> 16);
}
__device__ __forceinline__ float b2f(uint16_t h){
  union { uint32_t u; float f; } v; v.u = ((uint32_t)h) << 16;
  return v.f;
}

__device__ __forceinline__ float waveSum(float v){
#pragma unroll
  for (int m = 32; m >= 1; m >>= 1) v += __shfl_xor(v, m, 64);
  return v;
}
__device__ __forceinline__ float blockSum256(float v, float* s4){
  v = waveSum(v);
  __syncthreads();
  if ((threadIdx.x & 63) == 0) s4[threadIdx.x >> 6] = v;
  __syncthreads();
  return s4[0] + s4[1] + s4[2] + s4[3];
}

// ---- async global->LDS, 16B per lane (dest = wave-uniform base + lane*16) ----
__device__ __forceinline__ void g2l16(const void* g, void* l){
  __builtin_amdgcn_global_load_lds((const __attribute__((address_space(1))) uint32_t*)g,
                                   (__attribute__((address_space(3))) uint32_t*)l, 16, 0, 0);
}

// XOR swizzle for 64-elem (128B) rows: 16B-unit u' = u ^ (row&7).  [G4/T2/m173]
__device__ __forceinline__ int swz8(int row, int kp){ return (kp ^ (row & 7)) << 3; }

// ---- MFMA 16x16x32 bf16 via inline asm (D=C in-place) ----
// A/B frag: lane l holds row/col (l&15), k = (l>>4)*8 + e
// D: col = lane&15, row = (lane>>4)*4 + reg   [m89-verified]
__device__ __forceinline__ void mfma_bf16(f32x4& d, u16x8 a, u16x8 b){
  asm volatile("v_mfma_f32_16x16x32_bf16 %0, %1, %2, %0" : "+v"(d) : "v"(a), "v"(b));
}

// 4x4-fragment core over one BK=64 LDS tile; SWA/SWB: operand stored swizzled (lda/ldb==64 only)
template<int SWA, int SWB>
__device__ __forceinline__ void mma_core(const uint16_t* lA, int lda, const uint16_t* lB, int ldb,
                                         f32x4 (&acc)[4][4], int wrow, int wcol, int lane){
  const int rb = lane & 15, ub = lane >> 4;
#pragma unroll
  for (int ks = 0; ks < 2; ks++){
    const int u = ks * 4 + ub;
    u16x8 af[4], bf[4];
#pragma unroll
    for (int m = 0; m < 4; m++){
      int r = wrow + m * 16 + rb;
      int e = SWA ? ((u ^ (r & 7)) << 3) : (u << 3);
      af[m] = *(const u16x8*)&lA[r * lda + e];
    }
#pragma unroll
    for (int n = 0; n < 4; n++){
      int r = wcol + n * 16 + rb;
      int e = SWB ? ((u ^ (r & 7)) << 3) : (u << 3);
      bf[n] = *(const u16x8*)&lB[r * ldb + e];
    }
#pragma unroll
    for (int m = 0; m < 4; m++)
#pragma unroll
      for (int n = 0; n < 4; n++)
        mfma_bf16(acc[m][n], af[m], bf[n]);
  }
}

// ---------------- K0: x NCHW -> NHWC bf16 ----------------
__global__ __launch_bounds__(256) void k_t2b(const float* __restrict__ in, uint16_t* __restrict__ out){
  __shared__ float tile[64][33];   // [c][n]
  int b = blockIdx.z;
  int n0 = blockIdx.x * 32;
  int c0 = blockIdx.y * 64;
  int tx = threadIdx.x, ty = threadIdx.y;   // (32,8)
  const float* src = in + (size_t)b * CC * NN;
#pragma unroll
  for (int i = 0; i < 64; i += 8)
    tile[ty + i][tx] = src[(size_t)(c0 + ty + i) * NN + n0 + tx];
  __syncthreads();
  uint16_t* dst = out + (size_t)b * NN * CC;
#pragma unroll
  for (int i = 0; i < 32; i += 8){
    int r = ty + i;
    u16x2 o; o[0] = f2b(tile[tx * 2][r]); o[1] = f2b(tile[tx * 2 + 1][r]);
    *(u16x2*)&dst[(size_t)(n0 + r) * CC + c0 + tx * 2] = o;
  }
}

// ---------------- K1: 8x8 pooled slots + l2norm -> bf16 (vectorized) ----------------
__global__ __launch_bounds__(256) void k_pool(const uint16_t* __restrict__ xhwcb, uint16_t* __restrict__ slotsNb){
  int bs = blockIdx.x; int b = bs >> 6, s = bs & 63;
  int sy = (s >> 3) * 8, sx = (s & 7) * 8;
  int t = threadIdx.x;
  int c4 = t & 63, pg = t >> 6;      // channel-quad, pixel-group (16 px each)
  const uint16_t* base = xhwcb + (size_t)b * NN * CC;
  float a0 = 0.f, a1 = 0.f, a2 = 0.f, a3 = 0.f;
#pragma unroll
  for (int i = 0; i < 16; i++){
    int p = pg * 16 + i; int py = p >> 3, px = p & 7;
    u16x4 v = *(const u16x4*)&base[(size_t)((sy + py) * WW + sx + px) * CC + c4 * 4];
    a0 += b2f(v[0]); a1 += b2f(v[1]); a2 += b2f(v[2]); a3 += b2f(v[3]);
  }
  __shared__ float sm[4][64][4];
  sm[pg][c4][0] = a0; sm[pg][c4][1] = a1; sm[pg][c4][2] = a2; sm[pg][c4][3] = a3;
  __syncthreads();
  if (t < 64){
    float v0 = (sm[0][t][0] + sm[1][t][0] + sm[2][t][0] + sm[3][t][0]) * (1.0f / 64.0f);
    float v1 = (sm[0][t][1] + sm[1][t][1] + sm[2][t][1] + sm[3][t][1]) * (1.0f / 64.0f);
    float v2 = (sm[0][t][2] + sm[1][t][2] + sm[2][t][2] + sm[3][t][2]) * (1.0f / 64.0f);
    float v3 = (sm[0][t][3] + sm[1][t][3] + sm[2][t][3] + sm[3][t][3]) * (1.0f / 64.0f);
    float ss = waveSum(v0 * v0 + v1 * v1 + v2 * v2 + v3 * v3);
    float inv = 1.0f / fmaxf(sqrtf(ss), 1e-12f);
    u16x4 o; o[0] = f2b(v0 * inv); o[1] = f2b(v1 * inv); o[2] = f2b(v2 * inv); o[3] = f2b(v3 * inv);
    *(u16x4*)&slotsNb[(size_t)bs * CC + t * 4] = o;
  }
}

// ---- wave-per-row LayerNorm on bf16 (xa [+ xb]) -> bf16 (+ inv l2-norm | + padded-interior write) ----
__global__ __launch_bounds__(256) void k_ln_w(const uint16_t* __restrict__ xa, const uint16_t* __restrict__ xb,
                                              const float* __restrict__ w, const float* __restrict__ b,
                                              uint16_t* __restrict__ xoutb, float* __restrict__ rn,
                                              uint16_t* __restrict__ xn2p){
  int row = blockIdx.x * 4 + (threadIdx.x >> 6);
  int lane = threadIdx.x & 63;
  u16x4 va = *(const u16x4*)&xa[(size_t)row * CC + lane * 4];
  float v0 = b2f(va[0]), v1 = b2f(va[1]), v2 = b2f(va[2]), v3 = b2f(va[3]);
  if (xb){
    u16x4 vb = *(const u16x4*)&xb[(size_t)row * CC + lane * 4];
    v0 += b2f(vb[0]); v1 += b2f(vb[1]); v2 += b2f(vb[2]); v3 += b2f(vb[3]);
  }
  float mu = waveSum(v0 + v1 + v2 + v3) * (1.0f / CC);
  float d0 = v0 - mu, d1 = v1 - mu, d2 = v2 - mu, d3 = v3 - mu;
  float var = waveSum(d0 * d0 + d1 * d1 + d2 * d2 + d3 * d3) * (1.0f / CC);
  float inv = rsqrtf(var + 1e-5f);
  float4 wv = *(const float4*)&w[lane * 4];
  float4 bv = *(const float4*)&b[lane * 4];
  float x0 = d0 * inv * wv.x + bv.x;
  float x1 = d1 * inv * wv.y + bv.y;
  float x2 = d2 * inv * wv.z + bv.z;
  float x3 = d3 * inv * wv.w + bv.w;
  u16x4 o; o[0] = f2b(x0); o[1] = f2b(x1); o[2] = f2b(x2); o[3] = f2b(x3);
  *(u16x4*)&xoutb[(size_t)row * CC + lane * 4] = o;
  if (xn2p && lane < 16){
    int bb = row >> 12, n = row & 4095, y = n >> 6, x = n & 63;
    *(u16x4*)&xn2p[(((size_t)(bb * 66 + y + 1)) * 66 + x + 1) * 64 + lane * 4] = o;
  }
  if (rn){
    float ss = waveSum(x0 * x0 + x1 * x1 + x2 * x2 + x3 * x3);
    if (lane == 0) rn[row] = 1.0f / fmaxf(sqrtf(ss), 1e-12f);
  }
}

// ---------------- border zeros for padded image ----------------
__global__ __launch_bounds__(256) void k_zb(uint16_t* __restrict__ xn2p){
  int i = blockIdx.x * 256 + threadIdx.x;   // (b, j<260, c4<16)
  if (i >= 16 * 260 * 16) return;
  int c4 = i & 15; int rest = i >> 4;
  int j = rest % 260; int b = rest / 260;
  int py, px;
  if (j < 66){ py = 0; px = j; }
  else if (j < 132){ py = 65; px = j - 66; }
  else if (j < 196){ py = j - 132 + 1; px = 0; }
  else { py = j - 196 + 1; px = 65; }
  u16x4 z; z[0] = 0; z[1] = 0; z[2] = 0; z[3] = 0;
  *(u16x4*)&xn2p[(((size_t)(b * 66 + py)) * 66 + px) * 64 + c4 * 4] = z;
}

// ---------------- merged weight conversions (wi|wo|w1|w2|pconv|dwT) ----------------
__global__ __launch_bounds__(256) void k_cvtw(const float* __restrict__ wi, const float* __restrict__ wo,
                                              const float* __restrict__ w1, const float* __restrict__ w2,
                                              const float* __restrict__ pw, const float* __restrict__ dww,
                                              uint16_t* __restrict__ wib, uint16_t* __restrict__ wob,
                                              uint16_t* __restrict__ w1b, uint16_t* __restrict__ w2b,
                                              uint16_t* __restrict__ wp2, float* __restrict__ dwwT){
  int i = blockIdx.x * 256 + threadIdx.x;
  if (i < 163840){
    const float* src; uint16_t* dst; int off;
    if (i < 49152){ src = wi; dst = wib; off = i; }
    else if (i < 65536){ src = wo; dst = wob; off = i - 49152; }
    else if (i < 131072){ src = w1; dst = w1b; off = i - 65536; }
    else { src = w2; dst = w2b; off = i - 131072; }
    float4 v = ((const float4*)src)[off];
    u16x4 o;
    o[0] = f2b(v.x); o[1] = f2b(v.y); o[2] = f2b(v.z); o[3] = f2b(v.w);
    *(u16x4*)&dst[(size_t)off * 4] = o;
  } else if (i < 200704){
    int j = i - 163840;
    if (j < 64 * 576){
      int co = j / 576, r = j % 576, tap = r >> 6, ci = r & 63;
      wp2[j] = f2b(pw[(size_t)co * 576 + ci * 9 + tap]);
    }
  } else {
    int j = i - 200704;                         // dwwT[tap][ch] = dww[ch][tap]
    if (j < 9 * HID){
      int tap = j / HID, ch = j % HID;
      dwwT[j] = dww[(size_t)ch * 9 + tap];
    }
  }
}

// ---------------- logits GEMM + exp epilogue -> E bf16 [b][s][n] ----------------
__global__ __launch_bounds__(256) void k_logits_mfma(const uint16_t* __restrict__ slotsNb,
                                                     const uint16_t* __restrict__ xnb,
                                                     const float* __restrict__ rn,
                                                     const float* __restrict__ scale_p,
                                                     uint16_t* __restrict__ E){
  __shared__ uint16_t smem[20480];      // lA 64x64 | lB 256x64 ; reused as eT 64x264
  __shared__ float rnS[256];
  uint16_t* lA = smem;
  uint16_t* lB = smem + 64 * 64;
  int t = threadIdx.x, lane = t & 63, w = t >> 6;
  int b = blockIdx.y, n0 = blockIdx.x * 256;
  rnS[t] = rn[b * NN + n0 + t];
  f32x4 acc[4][4];
#pragma unroll
  for (int m = 0; m < 4; m++)
#pragma unroll
    for (int n = 0; n < 4; n++) acc[m][n] = (f32x4){0.f, 0.f, 0.f, 0.f};
  for (int kc = 0; kc < 4; kc++){
#pragma unroll
    for (int i = 0; i < 2; i++){
      int idx = i * 256 + t, row = idx >> 3, kp = idx & 7;
      *(u16x8*)&lA[row * 64 + swz8(row, kp)] = *(const u16x8*)&slotsNb[(size_t)(b * 64 + row) * 256 + kc * 64 + kp * 8];
    }
#pragma unroll
    for (int i = 0; i < 8; i++){
      int idx = i * 256 + t, row = idx >> 3, kp = idx & 7;
      *(u16x8*)&lB[row * 64 + swz8(row, kp)] = *(const u16x8*)&xnb[((size_t)b * NN + n0 + row) * 256 + kc * 64 + kp * 8];
    }
    __syncthreads();
    mma_core<1, 1>(lA, 64, lB, 64, acc, 0, w * 64, lane);
    __syncthreads();
  }
  float scale = scale_p[0];
  int rb4 = (lane >> 4) * 4, cb = lane & 15;
#pragma unroll
  for (int m = 0; m < 4; m++)
#pragma unroll
    for (int n = 0; n < 4; n++)
#pragma unroll
      for (int j = 0; j < 4; j++){
        int s = m * 16 + rb4 + j, nl = w * 64 + n * 16 + cb;
        smem[s * 264 + nl] = f2b(__expf(acc[m][n][j] * scale * rnS[nl]));
      }
  __syncthreads();
#pragma unroll
  for (int i = 0; i < 8; i++){
    int idx = i * 256 + t, row = idx >> 5, cseg = idx & 31;
    *(u16x8*)&E[((size_t)b * 64 + row) * NN + n0 + cseg * 8] = *(const u16x8*)&smem[row * 264 + cseg * 8];
  }
}

// ---------------- z1: invz1[b,s] = 1 / sum_n E (vectorized) ----------------
__global__ __launch_bounds__(256) void k_z1(const uint16_t* __restrict__ E, float* __restrict__ invz1){
  int bs = blockIdx.x, t = threadIdx.x;
  u16x8 v0 = *(const u16x8*)&E[(size_t)bs * NN + t * 16];
  u16x8 v1 = *(const u16x8*)&E[(size_t)bs * NN + t * 16 + 8];
  float s = 0.f;
#pragma unroll
  for (int i = 0; i < 8; i++) s += b2f(v0[i]) + b2f(v1[i]);
  __shared__ float s4[4];
  float z = blockSum256(s, s4);
  if (t == 0) invz1[bs] = 1.0f / z;
}

// ---------------- slots GEMM (4-way K-split partials) ----------------
__global__ __launch_bounds__(256) void k_slots_mfma(const uint16_t* __restrict__ E,
                                                    const uint16_t* __restrict__ xnb,
                                                    float* __restrict__ part){
  __shared__ uint16_t lA[64 * 64];
  __shared__ uint16_t lB[256 * 72];
  int t = threadIdx.x, lane = t & 63, w = t >> 6;
  int ks = blockIdx.x, b = blockIdx.y;
  f32x4 acc[4][4];
#pragma unroll
  for (int m = 0; m < 4; m++)
#pragma unroll
    for (int n = 0; n < 4; n++) acc[m][n] = (f32x4){0.f, 0.f, 0.f, 0.f};
  for (int kc = 0; kc < 16; kc++){
    int n0 = ks * 1024 + kc * 64;
#pragma unroll
    for (int i = 0; i < 2; i++){
      int idx = i * 256 + t, row = idx >> 3, kp = idx & 7;
      *(u16x8*)&lA[row * 64 + swz8(row, kp)] = *(const u16x8*)&E[((size_t)b * 64 + row) * NN + n0 + kp * 8];
    }
#pragma unroll
    for (int i = 0; i < 8; i++){
      int idx = i * 256 + t, nrow = idx >> 5, cseg = idx & 31;
      u16x8 v = *(const u16x8*)&xnb[((size_t)b * NN + n0 + nrow) * 256 + cseg * 8];
#pragma unroll
      for (int j = 0; j < 8; j++) lB[(cseg * 8 + j) * 72 + nrow] = v[j];
    }
    __syncthreads();
    mma_core<1, 0>(lA, 64, lB, 72, acc, 0, w * 64, lane);
    __syncthreads();
  }
  int rb4 = (lane >> 4) * 4, cb = lane & 15;
#pragma unroll
  for (int m = 0; m < 4; m++)
#pragma unroll
    for (int n = 0; n < 4; n++)
#pragma unroll
      for (int j = 0; j < 4; j++){
        int s = m * 16 + rb4 + j, c = w * 64 + n * 16 + cb;
        part[(((size_t)b * 4 + ks) * 64 + s) * 256 + c] = acc[m][n][j];
      }
}

// ---------------- fold partials -> slots bf16 ----------------
__global__ __launch_bounds__(256) void k_fold(const float* __restrict__ part, const float* __restrict__ invz1,
                                              uint16_t* __restrict__ slotsb){
  int i = blockIdx.x * 256 + threadIdx.x;
  int row = i >> 6, c4 = i & 63;
  int b = row >> 6, s = row & 63;
  float4 a = {0.f, 0.f, 0.f, 0.f};
#pragma unroll
  for (int p = 0; p < 4; p++){
    float4 v = *(const float4*)&part[(((size_t)b * 4 + p) * 64 + s) * 256 + c4 * 4];
    a.x += v.x; a.y += v.y; a.z += v.z; a.w += v.w;
  }
  float iz = invz1[row];
  u16x4 o; o[0] = f2b(a.x * iz); o[1] = f2b(a.y * iz); o[2] = f2b(a.z * iz); o[3] = f2b(a.w * iz);
  *(u16x4*)&slotsb[(size_t)row * 256 + c4 * 4] = o;
}

// ---------------- qkv GEMM: [1024 x 768] = slotsb @ wib^T + bi (fp32 out) ----------------
__global__ __launch_bounds__(256) void k_gemm_qkv(const uint16_t* __restrict__ slotsb,
                                                  const uint16_t* __restrict__ wib,
                                                  const float* __restrict__ bi,
                                                  float* __restrict__ qkv){
  __shared__ uint16_t lA[128 * 64];
  __shared__ uint16_t lB[128 * 64];
  int t = threadIdx.x, lane = t & 63, w = t >> 6;
  int wrow = (w >> 1) * 64, wcol = (w & 1) * 64;
  int BR = blockIdx.x * 128, BC = blockIdx.y * 128;
  f32x4 acc[4][4];
#pragma unroll
  for (int m = 0; m < 4; m++)
#pragma unroll
    for (int n = 0; n < 4; n++) acc[m][n] = (f32x4){0.f, 0.f, 0.f, 0.f};
  for (int kc = 0; kc < 4; kc++){
#pragma unroll
    for (int i = 0; i < 4; i++){
      int idx = i * 256 + t, row = idx >> 3, kp = idx & 7;
      *(u16x8*)&lA[row * 64 + swz8(row, kp)] = *(const u16x8*)&slotsb[(size_t)(BR + row) * 256 + kc * 64 + kp * 8];
      *(u16x8*)&lB[row * 64 + swz8(row, kp)] = *(const u16x8*)&wib[(size_t)(BC + row) * 256 + kc * 64 + kp * 8];
    }
    __syncthreads();
    mma_core<1, 1>(lA, 64, lB, 64, acc, wrow, wcol, lane);
    __syncthreads();
  }
  int rb4 = (lane >> 4) * 4, cb = lane & 15;
#pragma unroll
  for (int m = 0; m < 4; m++)
#pragma unroll
    for (int n = 0; n < 4; n++){
      int c = BC + wcol + n * 16 + cb;
      float bias = bi[c];
#pragma unroll
      for (int j = 0; j < 4; j++)
        qkv[(size_t)(BR + wrow + m * 16 + rb4 + j) * 768 + c] = acc[m][n][j] + bias;
    }
}

// ---------------- per (b,h) attention over S=64 -> aob bf16 ----------------
__global__ __launch_bounds__(256) void k_attn(const float* __restrict__ qkv, uint16_t* __restrict__ aob){
  int b = blockIdx.x >> 3, h = blockIdx.x & 7;
  __shared__ float lq[64][33], lk[64][33], lv[64][33];
  __shared__ float sc[64][65];
  int t = threadIdx.x;
  for (int idx = t; idx < 64 * 32; idx += 256){
    int s = idx >> 5, d = idx & 31;
    const float* base = qkv + ((size_t)b * SS + s) * 768 + h * DH + d;
    lq[s][d] = base[0];
    lk[s][d] = base[256];
    lv[s][d] = base[512];
  }
  __syncthreads();
  const float rs = 0.17677669529663687f;
  for (int idx = t; idx < 64 * 64; idx += 256){
    int qq = idx >> 6, kk = idx & 63;
    float a = 0.f;
#pragma unroll
    for (int d = 0; d < 32; d++) a += lq[qq][d] * lk[kk][d];
    sc[qq][kk] = a * rs;
  }
  __syncthreads();
  {
    int r = t >> 2, sub = t & 3;
    float m = -1e30f;
#pragma unroll
    for (int k = sub * 16; k < sub * 16 + 16; k++) m = fmaxf(m, sc[r][k]);
    m = fmaxf(m, __shfl_xor(m, 1, 64));
    m = fmaxf(m, __shfl_xor(m, 2, 64));
    float z = 0.f;
#pragma unroll
    for (int k = sub * 16; k < sub * 16 + 16; k++){
      float e = __expf(sc[r][k] - m); sc[r][k] = e; z += e;
    }
    z += __shfl_xor(z, 1, 64);
    z += __shfl_xor(z, 2, 64);
    float iv = 1.0f / z;
#pragma unroll
    for (int k = sub * 16; k < sub * 16 + 16; k++) sc[r][k] *= iv;
  }
  __syncthreads();
  for (int idx = t; idx < 64 * 32; idx += 256){
    int qq = idx >> 5, d = idx & 31;
    float a = 0.f;
#pragma unroll
    for (int k = 0; k < 64; k++) a += sc[qq][k] * lv[k][d];
    aob[((size_t)b * SS + qq) * CC + h * DH + d] = f2b(a);
  }
}

// ---------------- oproj GEMM: sl2T[b][c][s] = (aob @ wob^T + bo)^T bf16 ----------------
__global__ __launch_bounds__(256) void k_gemm_oproj(const uint16_t* __restrict__ aob,
                                                    const uint16_t* __restrict__ wob,
                                                    const float* __restrict__ bo,
                                                    uint16_t* __restrict__ sl2Tb){
  __shared__ uint16_t lA[128 * 64];
  __shared__ uint16_t lB[128 * 64];
  int t = threadIdx.x, lane = t & 63, w = t >> 6;
  int wrow = (w >> 1) * 64, wcol = (w & 1) * 64;
  int BR = blockIdx.x * 128, BC = blockIdx.y * 128;
  f32x4 acc[4][4];
#pragma unroll
  for (int m = 0; m < 4; m++)
#pragma unroll
    for (int n = 0; n < 4; n++) acc[m][n] = (f32x4){0.f, 0.f, 0.f, 0.f};
  for (int kc = 0; kc < 4; kc++){
#pragma unroll
    for (int i = 0; i < 4; i++){
      int idx = i * 256 + t, row = idx >> 3, kp = idx & 7;
      *(u16x8*)&lA[row * 64 + swz8(row, kp)] = *(const u16x8*)&aob[(size_t)(BR + row) * 256 + kc * 64 + kp * 8];
      *(u16x8*)&lB[row * 64 + swz8(row, kp)] = *(const u16x8*)&wob[(size_t)(BC + row) * 256 + kc * 64 + kp * 8];
    }
    __syncthreads();
    mma_core<1, 1>(lA, 64, lB, 64, acc, wrow, wcol, lane);
    __syncthreads();
  }
  int rb4 = (lane >> 4) * 4, cb = lane & 15;
#pragma unroll
  for (int m = 0; m < 4; m++)
#pragma unroll
    for (int n = 0; n < 4; n++){
      int c = BC + wcol + n * 16 + cb;
      float bias = bo[c];
#pragma unroll
      for (int j = 0; j < 4; j++){
        int r = BR + wrow + m * 16 + rb4 + j;
        int b = r >> 6, s = r & 63;
        sl2Tb[((size_t)b * 256 + c) * 64 + s] = f2b(acc[m][n][j] + bias);
      }
    }
}

// ---------------- mix GEMM (pt fused): mixb[n][c] = (E^T[n][s]/z2[n]) @ sl2T[c][s] ----------------
__global__ __launch_bounds__(256) void k_mix(const uint16_t* __restrict__ E, const uint16_t* __restrict__ sl2Tb,
                                             uint16_t* __restrict__ mixb){
  __shared__ uint16_t lA[128 * 72];    // E^T tile [n_local][s] (padded stride, no swizzle)
  __shared__ uint16_t lB[128 * 64];    // sl2T rows [c][s] (swizzled)
  __shared__ float z2S[128];
  int t = threadIdx.x, lane = t & 63, w = t >> 6;
  int wrow = (w >> 1) * 64, wcol = (w & 1) * 64;
  int BR = blockIdx.x * 128, BC = blockIdx.y * 128, b = blockIdx.z;
#pragma unroll
  for (int i = 0; i < 4; i++){
    int idx = i * 256 + t; int s = idx >> 4, n8 = (idx & 15) * 8;
    u16x8 v = *(const u16x8*)&E[((size_t)b * 64 + s) * NN + BR + n8];
#pragma unroll
    for (int j = 0; j < 8; j++) lA[(n8 + j) * 72 + s] = v[j];
  }
#pragma unroll
  for (int i = 0; i < 4; i++){
    int idx = i * 256 + t, row = idx >> 3, kp = idx & 7;
    *(u16x8*)&lB[row * 64 + swz8(row, kp)] = *(const u16x8*)&sl2Tb[((size_t)b * 256 + BC + row) * 64 + kp * 8];
  }
  __syncthreads();
  if (t < 128){
    float s = 0.f;
#pragma unroll
    for (int k2 = 0; k2 < 64; k2++) s += b2f(lA[t * 72 + k2]);
    z2S[t] = 1.0f / s;
  }
  __syncthreads();
  f32x4 acc[4][4];
#pragma unroll
  for (int m = 0; m < 4; m++)
#pragma unroll
    for (int n = 0; n < 4; n++) acc[m][n] = (f32x4){0.f, 0.f, 0.f, 0.f};
  mma_core<0, 1>(lA, 72, lB, 64, acc, wrow, wcol, lane);
  int rb4 = (lane >> 4) * 4, cb = lane & 15;
#pragma unroll
  for (int m = 0; m < 4; m++)
#pragma unroll
    for (int n = 0; n < 4; n++)
#pragma unroll
      for (int j = 0; j < 4; j++){
        int lrow = wrow + m * 16 + rb4 + j;
        size_t gi = ((size_t)b * NN + BR + lrow) * 256 + BC + wcol + n * 16 + cb;
        mixb[gi] = f2b(acc[m][n][j] * z2S[lrow]);
      }
}

// ---------------- pconv as 9-tap MFMA GEMM (g2l16 + pre-swizzled source) ----------------
__global__ __launch_bounds__(256) void k_pconv_mfma(const uint16_t* __restrict__ xn2p,
                                                    const uint16_t* __restrict__ wp2,
                                                    uint16_t* __restrict__ pcb){
  __shared__ uint16_t lA[256 * 64];
  __shared__ uint16_t lB[64 * 64];
  int t = threadIdx.x, lane = t & 63, w = t >> 6;
  int wrow = w * 64;
  int BR = blockIdx.x * 256;
  f32x4 acc[4][4];
#pragma unroll
  for (int m = 0; m < 4; m++)
#pragma unroll
    for (int n = 0; n < 4; n++) acc[m][n] = (f32x4){0.f, 0.f, 0.f, 0.f};
  for (int tap = 0; tap < 9; tap++){
    int dy = tap / 3 - 1, dx = tap % 3 - 1;
#pragma unroll
    for (int i = 0; i < 8; i++){
      int q = (w * 8 + i) * 64 + lane;
      int row = q >> 3, kpe = swz8(row, q & 7);
      int r = BR + row;
      int b = r >> 12, n = r & 4095, y = n >> 6, x = n & 63;
      size_t p = ((size_t)(b * 66 + (y + 1 + dy)) * 66 + (x + 1 + dx)) * 64 + kpe;
      g2l16(&xn2p[p], &lA[(w * 8 + i) * 512]);
    }
#pragma unroll
    for (int i = 0; i < 2; i++){
      int q = (w * 2 + i) * 64 + lane;
      int row = q >> 3, kpe = swz8(row, q & 7);
      g2l16(&wp2[(size_t)row * 576 + tap * 64 + kpe], &lB[(w * 2 + i) * 512]);
    }
    __syncthreads();
    mma_core<1, 1>(lA, 64, lB, 64, acc, wrow, 0, lane);
    __syncthreads();
  }
  int rb4 = (lane >> 4) * 4, cb = lane & 15;
#pragma unroll
  for (int m = 0; m < 4; m++)
#pragma unroll
    for (int n = 0; n < 4; n++)
#pragma unroll
      for (int j = 0; j < 4; j++)
        pcb[(size_t)(BR + wrow + m * 16 + rb4 + j) * 64 + (n * 16 + cb)] = f2b(acc[m][n][j]);
}

// ---------------- lin1 MFMA + gelu -> Y1b/Y2b (1-D grid 4096, XCD-remapped) ----------------
__global__ __launch_bounds__(256) void k_lin1_mfma(const uint16_t* __restrict__ pcb,
                                                   const uint16_t* __restrict__ xn2b,
                                                   const uint16_t* __restrict__ w1b,
                                                   const float* __restrict__ b1,
                                                   uint16_t* __restrict__ Y1b, uint16_t* __restrict__ Y2b){
  __shared__ uint16_t lA[128 * 64];
  __shared__ uint16_t lB[128 * 64];
  int t = threadIdx.x, lane = t & 63, w = t >> 6;
  int wrow = (w >> 1) * 64, wcol = (w & 1) * 64;
  int bid = blockIdx.x;
  int xcd = bid & 7, i5 = bid >> 3;         // i5 in [0,512)
  int BR = (xcd * 64 + (i5 >> 3)) * 128;
  int BC = (i5 & 7) * 128;
  f32x4 acc[4][4];
#pragma unroll
  for (int m = 0; m < 4; m++)
#pragma unroll
    for (int n = 0; n < 4; n++) acc[m][n] = (f32x4){0.f, 0.f, 0.f, 0.f};
  for (int kc = 0; kc < 4; kc++){
#pragma unroll
    for (int i = 0; i < 4; i++){
      int q = (w * 4 + i) * 64 + lane;
      int row = q >> 3, kpe = swz8(row, q & 7);
      size_t gr = (size_t)(BR + row);
      const uint16_t* src = (kc == 0) ? &pcb[gr * 64 + kpe] : &xn2b[gr * 256 + kc * 64 + kpe];
      g2l16(src, &lA[(w * 4 + i) * 512]);
      g2l16(&w1b[(size_t)(BC + row) * 256 + kc * 64 + kpe], &lB[(w * 4 + i) * 512]);
    }
    __syncthreads();
    mma_core<1, 1>(lA, 64, lB, 64, acc, wrow, wcol, lane);
    __syncthreads();
  }
  int rb4 = (lane >> 4) * 4, cb = lane & 15;
#pragma unroll
  for (int m = 0; m < 4; m++){
#pragma unroll
    for (int n = 0; n < 4; n++){
      int c = BC + wcol + n * 16 + cb;
      float bias = b1[c];
#pragma unroll
      for (int j = 0; j < 4; j++){
        size_t r = (size_t)(BR + wrow + m * 16 + rb4 + j);
        uint16_t h = f2b(gelu_fast(acc[m][n][j] + bias));
        if (c < HID) Y1b[r * HID + c] = h;
        else         Y2b[r * HID + (c - HID)] = h;
      }
    }
  }
}

// ------- dwconv 3x3 + gelu, fused *Y2 — LDS-tiled: block = 16px (row seg) × 128ch -------
// grid (256 = 64rows × 4segs, 4 ch-chunks, BB). Halo tile 3×18×128 staged once; zero borders.
__global__ __launch_bounds__(256) void k_dwconv(const uint16_t* __restrict__ Y1b,
                                                const float* __restrict__ dwwT,   // [tap][512]
                                                const float* __restrict__ dwb,
                                                const uint16_t* __restrict__ Y2b,
                                                uint16_t* __restrict__ YPb){
  __shared__ uint16_t lds[3 * 18 * 136];   // px-stride 136 elems (272B) -> bank-shift 4/px
  int b = blockIdx.z, chunk = blockIdx.y;
  int y = blockIdx.x >> 2, seg = blockIdx.x & 3;
  int x0 = seg * 16;
  int t = threadIdx.x;
  const uint16_t* base = Y1b + (size_t)b * NN * HID + chunk * 128;
  const u16x8 z = {0, 0, 0, 0, 0, 0, 0, 0};
#pragma unroll
  for (int i = 0; i < 4; i++){
    int idx = i * 256 + t;
    if (idx < 864){                         // 3 rows × 18 px × 16 ch-groups
      int g8 = idx & 15, rest = idx >> 4;
      int c = rest % 18, r = rest / 18;
      int ry = y + r - 1, xx = x0 + c - 1;
      u16x8 v = z;
      if (ry >= 0 && ry < HH && xx >= 0 && xx < WW)
        v = *(const u16x8*)&base[(size_t)(ry * WW + xx) * HID + g8 * 8];
      *(u16x8*)&lds[(r * 18 + c) * 136 + g8 * 8] = v;
    }
  }
  __syncthreads();
  int px = t >> 4, g8 = t & 15;
  int cg = chunk * 128 + g8 * 8;
  int n = y * WW + x0 + px;
  u16x8 y2 = *(const u16x8*)&Y2b[((size_t)b * NN + n) * HID + cg];
  float acc[8];
  {
    float4 b0 = *(const float4*)&dwb[cg];
    float4 b1 = *(const float4*)&dwb[cg + 4];
    acc[0] = b0.x; acc[1] = b0.y; acc[2] = b0.z; acc[3] = b0.w;
    acc[4] = b1.x; acc[5] = b1.y; acc[6] = b1.z; acc[7] = b1.w;
  }
#pragma unroll
  for (int r = 0; r < 3; r++)
#pragma unroll
    for (int dx = 0; dx < 3; dx++){
      u16x8 v = *(const u16x8*)&lds[(r * 18 + px + dx) * 136 + g8 * 8];
      const float* wt = &dwwT[(r * 3 + dx) * HID + cg];
      float4 w0 = *(const float4*)wt;
      float4 w1 = *(const float4*)(wt + 4);
      acc[0] += b2f(v[0]) * w0.x; acc[1] += b2f(v[1]) * w0.y;
      acc[2] += b2f(v[2]) * w0.z; acc[3] += b2f(v[3]) * w0.w;
      acc[4] += b2f(v[4]) * w1.x; acc[5] += b2f(v[5]) * w1.y;
      acc[6] += b2f(v[6]) * w1.z; acc[7] += b2f(v[7]) * w1.w;
    }
  u16x8 o;
#pragma unroll
  for (int j = 0; j < 8; j++) o[j] = f2b(gelu_fast(acc[j]) * b2f(y2[j]));
  *(u16x8*)&YPb[((size_t)b * NN + n) * HID + cg] = o;
}

// ---------------- lin2 MFMA: deltab = YP @ w2^T + b2 (1-D grid 1024, XCD-remapped) ----------------
__global__ __launch_bounds__(256) void k_lin2_mfma(const uint16_t* __restrict__ YPb,
                                                   const uint16_t* __restrict__ w2b,
                                                   const float* __restrict__ b2,
                                                   uint16_t* __restrict__ deltab){
  __shared__ uint16_t lA[128 * 64];
  __shared__ uint16_t lB[128 * 64];
  int t = threadIdx.x, lane = t & 63, w = t >> 6;
  int wrow = (w >> 1) * 64, wcol = (w & 1) * 64;
  int bid = blockIdx.x;
  int xcd = bid & 7, i5 = bid >> 3;         // i5 in [0,128)
  int BR = (xcd * 64 + (i5 >> 1)) * 128;
  int BC = (i5 & 1) * 128;
  f32x4 acc[4][4];
#pragma unroll
  for (int m = 0; m < 4; m++)
#pragma unroll
    for (int n = 0; n < 4; n++) acc[m][n] = (f32x4){0.f, 0.f, 0.f, 0.f};
  for (int kc = 0; kc < 8; kc++){
#pragma unroll
    for (int i = 0; i < 4; i++){
      int q = (w * 4 + i) * 64 + lane;
      int row = q >> 3, kpe = swz8(row, q & 7);
      g2l16(&YPb[(size_t)(BR + row) * HID + kc * 64 + kpe], &lA[(w * 4 + i) * 512]);
      g2l16(&w2b[(size_t)(BC + row) * HID + kc * 64 + kpe], &lB[(w * 4 + i) * 512]);
    }
    __syncthreads();
    mma_core<1, 1>(lA, 64, lB, 64, acc, wrow, wcol, lane);
    __syncthreads();
  }
  int rb4 = (lane >> 4) * 4, cb = lane & 15;
#pragma unroll
  for (int m = 0; m < 4; m++){
#pragma unroll
    for (int n = 0; n < 4; n++){
      int c = BC + wcol + n * 16 + cb;
      float bias = b2[c];
#pragma unroll
      for (int j = 0; j < 4; j++){
        size_t gr = (size_t)(BR + wrow + m * 16 + rb4 + j);
        deltab[gr * CC + c] = f2b(acc[m][n][j] + bias);
      }
    }
  }
}

// ---------------- final: v = mixb+deltab; out0 = xhwcb + v (NCHW), out1 = -v ----------------
__global__ __launch_bounds__(256) void k_final2(const uint16_t* __restrict__ mixb,
                                                const uint16_t* __restrict__ deltab,
                                                const uint16_t* __restrict__ xhwcb,
                                                float* __restrict__ out){
  __shared__ float t0[64 * 68];
  __shared__ float t1[64 * 68];
  int b = blockIdx.z;
  int n0 = blockIdx.x * 64, c0 = blockIdx.y * 64;
  int t = threadIdx.x;
#pragma unroll
  for (int i = 0; i < 4; i++){
    int idx = i * 256 + t, row = idx >> 4, c4 = idx & 15;
    size_t gp = ((size_t)b * NN + n0 + row) * CC + c0 + c4 * 4;
    u16x4 m = *(const u16x4*)&mixb[gp];
    u16x4 d = *(const u16x4*)&deltab[gp];
    u16x4 xh = *(const u16x4*)&xhwcb[gp];
    f32x4 v0, v1;
#pragma unroll
    for (int j = 0; j < 4; j++){
      float v = b2f(m[j]) + b2f(d[j]);
      v0[j] = b2f(xh[j]) + v;
      v1[j] = -v;
    }
    *(f32x4*)&t0[row * 68 + c4 * 4] = v0;
    *(f32x4*)&t1[row * 68 + c4 * 4] = v1;
  }
  __syncthreads();
  int cl = t >> 2, seg = t & 3;
  float* o1 = out + (size_t)BB * CC * NN;
  size_t gbase = ((size_t)(b * CC + c0 + cl)) * NN + n0 + seg * 16;
#pragma unroll
  for (int k = 0; k < 4; k++){
    float4 a, c;
    a.x = t0[(seg * 16 + k * 4 + 0) * 68 + cl];
    a.y = t0[(seg * 16 + k * 4 + 1) * 68 + cl];
    a.z = t0[(seg * 16 + k * 4 + 2) * 68 + cl];
    a.w = t0[(seg * 16 + k * 4 + 3) * 68 + cl];
    c.x = t1[(seg * 16 + k * 4 + 0) * 68 + cl];
    c.y = t1[(seg * 16 + k * 4 + 1) * 68 + cl];
    c.z = t1[(seg * 16 + k * 4 + 2) * 68 + cl];
    c.w = t1[(seg * 16 + k * 4 + 3) * 68 + cl];
    *(float4*)&out[gbase + k * 4] = a;
    *(float4*)&o1[gbase + k * 4] = c;
  }
}

extern "C" void kernel_launch(void* const* d_in, const int* in_sizes, int n_in,
                              void* d_out, int out_size, void* d_ws, size_t ws_size,
                              hipStream_t stream){
  const float* x       = (const float*)d_in[0];
  const float* scale_p = (const float*)d_in[1];
  const float* n1w     = (const float*)d_in[2];
  const float* n1b     = (const float*)d_in[3];
  const float* wi      = (const float*)d_in[4];
  const float* bi      = (const float*)d_in[5];
  const float* wo      = (const float*)d_in[6];
  const float* bo      = (const float*)d_in[7];
  const float* n2w     = (const float*)d_in[8];
  const float* n2b     = (const float*)d_in[9];
  const float* pw      = (const float*)d_in[10];
  const float* w1      = (const float*)d_in[11];
  const float* b1      = (const float*)d_in[12];
  const float* dww     = (const float*)d_in[13];
  const float* dwb     = (const float*)d_in[14];
  const float* w2      = (const float*)d_in[15];
  const float* b2      = (const float*)d_in[16];

  // ---- workspace layout (float units) — total ≈ 417 MB, ws = 512 MiB ----
  float* base = (float*)d_ws;
  size_t off = 0;
  float* part = base + off; off += (size_t)BB * 8 * SS * CC;
  float* QKV  = base + off; off += (size_t)BB * SS * 3 * CC;
  float* RN   = base + off; off += (size_t)BB * NN;
  float* IZ1  = base + off; off += (size_t)BB * SS;
  float* dwwT = base + off; off += (size_t)9 * HID;
  uint16_t* slotsNb = (uint16_t*)(base + off); off += (size_t)BB * SS * CC / 2;
  uint16_t* slotsb  = (uint16_t*)(base + off); off += (size_t)BB * SS * CC / 2;
  uint16_t* aob     = (uint16_t*)(base + off); off += (size_t)BB * SS * CC / 2;
  uint16_t* sl2Tb   = (uint16_t*)(base + off); off += (size_t)BB * CC * SS / 2;
  uint16_t* xhwcb   = (uint16_t*)(base + off); off += (size_t)BB * NN * CC / 2;
  uint16_t* xnb     = (uint16_t*)(base + off); off += (size_t)BB * NN * CC / 2;
  uint16_t* mixb    = (uint16_t*)(base + off); off += (size_t)BB * NN * CC / 2;
  uint16_t* deltab  = (uint16_t*)(base + off); off += (size_t)BB * NN * CC / 2;
  uint16_t* E       = (uint16_t*)(base + off); off += (size_t)BB * SS * NN / 2;
  uint16_t* w1b     = (uint16_t*)(base + off); off += (size_t)(2 * HID) * CC / 2;
  uint16_t* w2b     = (uint16_t*)(base + off); off += (size_t)CC * HID / 2;
  uint16_t* wib     = (uint16_t*)(base + off); off += (size_t)(3 * CC) * CC / 2;
  uint16_t* wob     = (uint16_t*)(base + off); off += (size_t)CC * CC / 2;
  uint16_t* wp2     = (uint16_t*)(base + off); off += (size_t)64 * 576 / 2 + 16;
  uint16_t* Y1b     = (uint16_t*)(base + off); off += (size_t)BB * NN * HID / 2;
  uint16_t* Y2b     = (uint16_t*)(base + off); off += (size_t)BB * NN * HID / 2;
  uint16_t* YPb     = (uint16_t*)(base + off); off += (size_t)BB * NN * HID / 2;
  uint16_t* xn2b    = (uint16_t*)(base + off); off += (size_t)BB * NN * CC / 2;
  uint16_t* xn2p    = (uint16_t*)(base + off); off += (size_t)BB * 66 * 66 * 64 / 2;
  uint16_t* pcb     = (uint16_t*)(base + off); off += (size_t)BB * NN * 64 / 2;
  if (ws_size < off * sizeof(float)) return;
  float* OUT = (float*)d_out;

  dim3 tb2(32, 8);
  // ---- slot-mixing phase ----
  k_t2b<<<dim3(NN / 32, CC / 64, BB), tb2, 0, stream>>>(x, xhwcb);
  k_pool<<<BB * SS, 256, 0, stream>>>(xhwcb, slotsNb);
  k_ln_w<<<BB * NN / 4, 256, 0, stream>>>(xhwcb, (const uint16_t*)nullptr, n1w, n1b, xnb, RN,
                                          (uint16_t*)nullptr);
  k_cvtw<<<803, 256, 0, stream>>>(wi, wo, w1, w2, pw, dww, wib, wob, w1b, w2b, wp2, dwwT);
  k_zb<<<(16 * 260 * 16 + 255) / 256, 256, 0, stream>>>(xn2p);
  k_logits_mfma<<<dim3(NN / 256, BB), 256, 0, stream>>>(slotsNb, xnb, RN, scale_p, E);
  k_z1<<<BB * SS, 256, 0, stream>>>(E, IZ1);
  k_slots_mfma<<<dim3(4, BB), 256, 0, stream>>>(E, xnb, part);
  k_fold<<<(BB * SS * CC / 4) / 256, 256, 0, stream>>>(part, IZ1, slotsb);
  k_gemm_qkv<<<dim3(8, 6), 256, 0, stream>>>(slotsb, wib, bi, QKV);
  k_attn<<<BB * NHEAD, 256, 0, stream>>>(QKV, aob);
  k_gemm_oproj<<<dim3(8, 2), 256, 0, stream>>>(aob, wob, bo, sl2Tb);
  k_mix<<<dim3(NN / 128, CC / 128, BB), 256, 0, stream>>>(E, sl2Tb, mixb);
  // ---- FRFN phase ----
  k_ln_w<<<BB * NN / 4, 256, 0, stream>>>(xhwcb, mixb, n2w, n2b, xn2b, (float*)nullptr, xn2p);
  k_pconv_mfma<<<BB * NN / 256, 256, 0, stream>>>(xn2p, wp2, pcb);
  k_lin1_mfma<<<4096, 256, 0, stream>>>(pcb, xn2b, w1b, b1, Y1b, Y2b);
  k_dwconv<<<dim3(256, 4, BB), 256, 0, stream>>>(Y1b, dwwT, dwb, Y2b, YPb);
  k_lin2_mfma<<<1024, 256, 0, stream>>>(YPb, w2b, b2, deltab);
  // ---- fused residual/transpose output ----
  k_final2<<<dim3(NN / 64, CC / 64, BB), 256, 0, stream>>>(mixb, deltab, xhwcb, OUT);
}

// Round 18
// 428.879 us; speedup vs baseline: 1.4325x; 1.2091x over previous
//
#include <hip/hip_runtime.h>
#include <hip/hip_bf16.h>
#include <stdint.h>
#include <math.h>

#define BB 16
#define CC 256
#define HH 64
#define WW 64
#define NN 4096   // HH*WW
#define SS 64
#define NHEAD 8
#define DH 32
#define HID 512
#define DC 64

typedef float    f32x4  __attribute__((ext_vector_type(4)));
typedef uint16_t u16x8  __attribute__((ext_vector_type(8)));
typedef uint16_t u16x4  __attribute__((ext_vector_type(4)));
typedef uint16_t u16x2  __attribute__((ext_vector_type(2)));

// tanh-approx gelu (|err| < ~1e-3 abs; budget absmax 0.108 >> this)
__device__ __forceinline__ float gelu_fast(float x){
  float u = 0.7978845608028654f * (x + 0.044715f * x * x * x);
  float e = __expf(2.0f * u);
  float th = 1.0f - 2.0f / (e + 1.0f);
  return 0.5f * x * (1.0f + th);
}
__device__ __forceinline__ uint16_t f2b(float f){
  union { float f; uint32_t u; } v; v.f = f;
  uint32_t r = v.u + 0x7fffu + ((v.u >> 16) & 1u);
  return (uint16_t)(r >> 16);
}
__device__ __forceinline__ float b2f(uint16_t h){
  union { uint32_t u; float f; } v; v.u = ((uint32_t)h) << 16;
  return v.f;
}

__device__ __forceinline__ float waveSum(float v){
#pragma unroll
  for (int m = 32; m >= 1; m >>= 1) v += __shfl_xor(v, m, 64);
  return v;
}
__device__ __forceinline__ float blockSum256(float v, float* s4){
  v = waveSum(v);
  __syncthreads();
  if ((threadIdx.x & 63) == 0) s4[threadIdx.x >> 6] = v;
  __syncthreads();
  return s4[0] + s4[1] + s4[2] + s4[3];
}

// ---- async global->LDS, 16B per lane (dest = wave-uniform base + lane*16) ----
__device__ __forceinline__ void g2l16(const void* g, void* l){
  __builtin_amdgcn_global_load_lds((const __attribute__((address_space(1))) uint32_t*)g,
                                   (__attribute__((address_space(3))) uint32_t*)l, 16, 0, 0);
}

// XOR swizzle for 64-elem (128B) rows: 16B-unit u' = u ^ (row&7).  [G4/T2/m173]
__device__ __forceinline__ int swz8(int row, int kp){ return (kp ^ (row & 7)) << 3; }

// ---- MFMA 16x16x32 bf16 via inline asm (D=C in-place) ----
// A/B frag: lane l holds row/col (l&15), k = (l>>4)*8 + e
// D: col = lane&15, row = (lane>>4)*4 + reg   [m89-verified]
__device__ __forceinline__ void mfma_bf16(f32x4& d, u16x8 a, u16x8 b){
  asm volatile("v_mfma_f32_16x16x32_bf16 %0, %1, %2, %0" : "+v"(d) : "v"(a), "v"(b));
}

// 4x4-fragment core over one BK=64 LDS tile; SWA/SWB: operand stored swizzled (lda/ldb==64 only)
template<int SWA, int SWB>
__device__ __forceinline__ void mma_core(const uint16_t* lA, int lda, const uint16_t* lB, int ldb,
                                         f32x4 (&acc)[4][4], int wrow, int wcol, int lane){
  const int rb = lane & 15, ub = lane >> 4;
#pragma unroll
  for (int ks = 0; ks < 2; ks++){
    const int u = ks * 4 + ub;
    u16x8 af[4], bf[4];
#pragma unroll
    for (int m = 0; m < 4; m++){
      int r = wrow + m * 16 + rb;
      int e = SWA ? ((u ^ (r & 7)) << 3) : (u << 3);
      af[m] = *(const u16x8*)&lA[r * lda + e];
    }
#pragma unroll
    for (int n = 0; n < 4; n++){
      int r = wcol + n * 16 + rb;
      int e = SWB ? ((u ^ (r & 7)) << 3) : (u << 3);
      bf[n] = *(const u16x8*)&lB[r * ldb + e];
    }
#pragma unroll
    for (int m = 0; m < 4; m++)
#pragma unroll
      for (int n = 0; n < 4; n++)
        mfma_bf16(acc[m][n], af[m], bf[n]);
  }
}

// ---------------- K0: x NCHW -> NHWC bf16 ----------------
__global__ __launch_bounds__(256) void k_t2b(const float* __restrict__ in, uint16_t* __restrict__ out){
  __shared__ float tile[64][33];   // [c][n]
  int b = blockIdx.z;
  int n0 = blockIdx.x * 32;
  int c0 = blockIdx.y * 64;
  int tx = threadIdx.x, ty = threadIdx.y;   // (32,8)
  const float* src = in + (size_t)b * CC * NN;
#pragma unroll
  for (int i = 0; i < 64; i += 8)
    tile[ty + i][tx] = src[(size_t)(c0 + ty + i) * NN + n0 + tx];
  __syncthreads();
  uint16_t* dst = out + (size_t)b * NN * CC;
#pragma unroll
  for (int i = 0; i < 32; i += 8){
    int r = ty + i;
    u16x2 o; o[0] = f2b(tile[tx * 2][r]); o[1] = f2b(tile[tx * 2 + 1][r]);
    *(u16x2*)&dst[(size_t)(n0 + r) * CC + c0 + tx * 2] = o;
  }
}

// ---------------- K1: 8x8 pooled slots + l2norm -> bf16 (vectorized) ----------------
__global__ __launch_bounds__(256) void k_pool(const uint16_t* __restrict__ xhwcb, uint16_t* __restrict__ slotsNb){
  int bs = blockIdx.x; int b = bs >> 6, s = bs & 63;
  int sy = (s >> 3) * 8, sx = (s & 7) * 8;
  int t = threadIdx.x;
  int c4 = t & 63, pg = t >> 6;      // channel-quad, pixel-group (16 px each)
  const uint16_t* base = xhwcb + (size_t)b * NN * CC;
  float a0 = 0.f, a1 = 0.f, a2 = 0.f, a3 = 0.f;
#pragma unroll
  for (int i = 0; i < 16; i++){
    int p = pg * 16 + i; int py = p >> 3, px = p & 7;
    u16x4 v = *(const u16x4*)&base[(size_t)((sy + py) * WW + sx + px) * CC + c4 * 4];
    a0 += b2f(v[0]); a1 += b2f(v[1]); a2 += b2f(v[2]); a3 += b2f(v[3]);
  }
  __shared__ float sm[4][64][4];
  sm[pg][c4][0] = a0; sm[pg][c4][1] = a1; sm[pg][c4][2] = a2; sm[pg][c4][3] = a3;
  __syncthreads();
  if (t < 64){
    float v0 = (sm[0][t][0] + sm[1][t][0] + sm[2][t][0] + sm[3][t][0]) * (1.0f / 64.0f);
    float v1 = (sm[0][t][1] + sm[1][t][1] + sm[2][t][1] + sm[3][t][1]) * (1.0f / 64.0f);
    float v2 = (sm[0][t][2] + sm[1][t][2] + sm[2][t][2] + sm[3][t][2]) * (1.0f / 64.0f);
    float v3 = (sm[0][t][3] + sm[1][t][3] + sm[2][t][3] + sm[3][t][3]) * (1.0f / 64.0f);
    float ss = waveSum(v0 * v0 + v1 * v1 + v2 * v2 + v3 * v3);
    float inv = 1.0f / fmaxf(sqrtf(ss), 1e-12f);
    u16x4 o; o[0] = f2b(v0 * inv); o[1] = f2b(v1 * inv); o[2] = f2b(v2 * inv); o[3] = f2b(v3 * inv);
    *(u16x4*)&slotsNb[(size_t)bs * CC + t * 4] = o;
  }
}

// ---- wave-per-row LayerNorm on bf16 (xa [+ xb]) -> bf16 (+ inv l2-norm | + padded-interior write) ----
__global__ __launch_bounds__(256) void k_ln_w(const uint16_t* __restrict__ xa, const uint16_t* __restrict__ xb,
                                              const float* __restrict__ w, const float* __restrict__ b,
                                              uint16_t* __restrict__ xoutb, float* __restrict__ rn,
                                              uint16_t* __restrict__ xn2p){
  int row = blockIdx.x * 4 + (threadIdx.x >> 6);
  int lane = threadIdx.x & 63;
  u16x4 va = *(const u16x4*)&xa[(size_t)row * CC + lane * 4];
  float v0 = b2f(va[0]), v1 = b2f(va[1]), v2 = b2f(va[2]), v3 = b2f(va[3]);
  if (xb){
    u16x4 vb = *(const u16x4*)&xb[(size_t)row * CC + lane * 4];
    v0 += b2f(vb[0]); v1 += b2f(vb[1]); v2 += b2f(vb[2]); v3 += b2f(vb[3]);
  }
  float mu = waveSum(v0 + v1 + v2 + v3) * (1.0f / CC);
  float d0 = v0 - mu, d1 = v1 - mu, d2 = v2 - mu, d3 = v3 - mu;
  float var = waveSum(d0 * d0 + d1 * d1 + d2 * d2 + d3 * d3) * (1.0f / CC);
  float inv = rsqrtf(var + 1e-5f);
  float4 wv = *(const float4*)&w[lane * 4];
  float4 bv = *(const float4*)&b[lane * 4];
  float x0 = d0 * inv * wv.x + bv.x;
  float x1 = d1 * inv * wv.y + bv.y;
  float x2 = d2 * inv * wv.z + bv.z;
  float x3 = d3 * inv * wv.w + bv.w;
  u16x4 o; o[0] = f2b(x0); o[1] = f2b(x1); o[2] = f2b(x2); o[3] = f2b(x3);
  *(u16x4*)&xoutb[(size_t)row * CC + lane * 4] = o;
  if (xn2p && lane < 16){
    int bb = row >> 12, n = row & 4095, y = n >> 6, x = n & 63;
    *(u16x4*)&xn2p[(((size_t)(bb * 66 + y + 1)) * 66 + x + 1) * 64 + lane * 4] = o;
  }
  if (rn){
    float ss = waveSum(x0 * x0 + x1 * x1 + x2 * x2 + x3 * x3);
    if (lane == 0) rn[row] = 1.0f / fmaxf(sqrtf(ss), 1e-12f);
  }
}

// ---------------- border zeros for padded image ----------------
__global__ __launch_bounds__(256) void k_zb(uint16_t* __restrict__ xn2p){
  int i = blockIdx.x * 256 + threadIdx.x;   // (b, j<260, c4<16)
  if (i >= 16 * 260 * 16) return;
  int c4 = i & 15; int rest = i >> 4;
  int j = rest % 260; int b = rest / 260;
  int py, px;
  if (j < 66){ py = 0; px = j; }
  else if (j < 132){ py = 65; px = j - 66; }
  else if (j < 196){ py = j - 132 + 1; px = 0; }
  else { py = j - 196 + 1; px = 65; }
  u16x4 z; z[0] = 0; z[1] = 0; z[2] = 0; z[3] = 0;
  *(u16x4*)&xn2p[(((size_t)(b * 66 + py)) * 66 + px) * 64 + c4 * 4] = z;
}

// ---------------- merged weight conversions (wi|wo|w1|w2|pconv|dwT) ----------------
__global__ __launch_bounds__(256) void k_cvtw(const float* __restrict__ wi, const float* __restrict__ wo,
                                              const float* __restrict__ w1, const float* __restrict__ w2,
                                              const float* __restrict__ pw, const float* __restrict__ dww,
                                              uint16_t* __restrict__ wib, uint16_t* __restrict__ wob,
                                              uint16_t* __restrict__ w1b, uint16_t* __restrict__ w2b,
                                              uint16_t* __restrict__ wp2, float* __restrict__ dwwT){
  int i = blockIdx.x * 256 + threadIdx.x;
  if (i < 163840){
    const float* src; uint16_t* dst; int off;
    if (i < 49152){ src = wi; dst = wib; off = i; }
    else if (i < 65536){ src = wo; dst = wob; off = i - 49152; }
    else if (i < 131072){ src = w1; dst = w1b; off = i - 65536; }
    else { src = w2; dst = w2b; off = i - 131072; }
    float4 v = ((const float4*)src)[off];
    u16x4 o;
    o[0] = f2b(v.x); o[1] = f2b(v.y); o[2] = f2b(v.z); o[3] = f2b(v.w);
    *(u16x4*)&dst[(size_t)off * 4] = o;
  } else if (i < 200704){
    int j = i - 163840;
    if (j < 64 * 576){
      int co = j / 576, r = j % 576, tap = r >> 6, ci = r & 63;
      wp2[j] = f2b(pw[(size_t)co * 576 + ci * 9 + tap]);
    }
  } else {
    int j = i - 200704;                         // dwwT[tap][ch] = dww[ch][tap]
    if (j < 9 * HID){
      int tap = j / HID, ch = j % HID;
      dwwT[j] = dww[(size_t)ch * 9 + tap];
    }
  }
}

// ---------------- xn transpose: xnT[b][c][n] = xn[b][n][c] (bf16, LDS-tiled) ----------------
__global__ __launch_bounds__(256) void k_txT(const uint16_t* __restrict__ xnb, uint16_t* __restrict__ xnTb){
  __shared__ uint16_t tile[64 * 66];   // stride 66 u16 -> 33 words: conflict-free scalar access
  int b = blockIdx.z;
  int n0 = blockIdx.x * 64, c0 = blockIdx.y * 64;
  int t = threadIdx.x;
#pragma unroll
  for (int i = 0; i < 16; i++){
    int idx = i * 256 + t;             // 0..4095
    int nr = idx >> 6, c = idx & 63;   // coalesced read (consecutive c)
    tile[c * 66 + nr] = xnb[((size_t)b * NN + n0 + nr) * CC + c0 + c];
  }
  __syncthreads();
#pragma unroll
  for (int i = 0; i < 16; i++){
    int idx = i * 256 + t;
    int cr = idx >> 6, n = idx & 63;   // coalesced write (consecutive n)
    xnTb[((size_t)b * CC + c0 + cr) * NN + n0 + n] = tile[cr * 66 + n];
  }
}

// ---------------- logits GEMM + exp epilogue -> E bf16 [b][s][n] ----------------
__global__ __launch_bounds__(256) void k_logits_mfma(const uint16_t* __restrict__ slotsNb,
                                                     const uint16_t* __restrict__ xnb,
                                                     const float* __restrict__ rn,
                                                     const float* __restrict__ scale_p,
                                                     uint16_t* __restrict__ E){
  __shared__ uint16_t smem[20480];      // lA 64x64 | lB 256x64 ; reused as eT 64x264
  __shared__ float rnS[256];
  uint16_t* lA = smem;
  uint16_t* lB = smem + 64 * 64;
  int t = threadIdx.x, lane = t & 63, w = t >> 6;
  int b = blockIdx.y, n0 = blockIdx.x * 256;
  rnS[t] = rn[b * NN + n0 + t];
  f32x4 acc[4][4];
#pragma unroll
  for (int m = 0; m < 4; m++)
#pragma unroll
    for (int n = 0; n < 4; n++) acc[m][n] = (f32x4){0.f, 0.f, 0.f, 0.f};
  for (int kc = 0; kc < 4; kc++){
#pragma unroll
    for (int i = 0; i < 2; i++){
      int idx = i * 256 + t, row = idx >> 3, kp = idx & 7;
      *(u16x8*)&lA[row * 64 + swz8(row, kp)] = *(const u16x8*)&slotsNb[(size_t)(b * 64 + row) * 256 + kc * 64 + kp * 8];
    }
#pragma unroll
    for (int i = 0; i < 8; i++){
      int idx = i * 256 + t, row = idx >> 3, kp = idx & 7;
      *(u16x8*)&lB[row * 64 + swz8(row, kp)] = *(const u16x8*)&xnb[((size_t)b * NN + n0 + row) * 256 + kc * 64 + kp * 8];
    }
    __syncthreads();
    mma_core<1, 1>(lA, 64, lB, 64, acc, 0, w * 64, lane);
    __syncthreads();
  }
  float scale = scale_p[0];
  int rb4 = (lane >> 4) * 4, cb = lane & 15;
#pragma unroll
  for (int m = 0; m < 4; m++)
#pragma unroll
    for (int n = 0; n < 4; n++)
#pragma unroll
      for (int j = 0; j < 4; j++){
        int s = m * 16 + rb4 + j, nl = w * 64 + n * 16 + cb;
        smem[s * 264 + nl] = f2b(__expf(acc[m][n][j] * scale * rnS[nl]));
      }
  __syncthreads();
#pragma unroll
  for (int i = 0; i < 8; i++){
    int idx = i * 256 + t, row = idx >> 5, cseg = idx & 31;
    *(u16x8*)&E[((size_t)b * 64 + row) * NN + n0 + cseg * 8] = *(const u16x8*)&smem[row * 264 + cseg * 8];
  }
}

// ---------------- z1: invz1[b,s] = 1 / sum_n E (vectorized) ----------------
__global__ __launch_bounds__(256) void k_z1(const uint16_t* __restrict__ E, float* __restrict__ invz1){
  int bs = blockIdx.x, t = threadIdx.x;
  u16x8 v0 = *(const u16x8*)&E[(size_t)bs * NN + t * 16];
  u16x8 v1 = *(const u16x8*)&E[(size_t)bs * NN + t * 16 + 8];
  float s = 0.f;
#pragma unroll
  for (int i = 0; i < 8; i++) s += b2f(v0[i]) + b2f(v1[i]);
  __shared__ float s4[4];
  float z = blockSum256(s, s4);
  if (t == 0) invz1[bs] = 1.0f / z;
}

// ------- slots GEMM (8-way K-split, both operands k-major via xnT; no in-kernel transpose) -------
__global__ __launch_bounds__(256) void k_slots_mfma(const uint16_t* __restrict__ E,
                                                    const uint16_t* __restrict__ xnTb,
                                                    float* __restrict__ part){
  __shared__ uint16_t lA[64 * 64];     // E tile: 64 s x 64 k
  __shared__ uint16_t lB[256 * 64];    // xnT tile: 256 c x 64 k  (40KB total)
  int t = threadIdx.x, lane = t & 63, w = t >> 6;
  int ks = blockIdx.x, b = blockIdx.y;
  f32x4 acc[4][4];
#pragma unroll
  for (int m = 0; m < 4; m++)
#pragma unroll
    for (int n = 0; n < 4; n++) acc[m][n] = (f32x4){0.f, 0.f, 0.f, 0.f};
  for (int kc = 0; kc < 8; kc++){
    int n0 = ks * 512 + kc * 64;
#pragma unroll
    for (int i = 0; i < 2; i++){        // lA: 512 units, 2/thread
      int q = (w * 2 + i) * 64 + lane;
      int row = q >> 3, kpe = swz8(row, q & 7);
      g2l16(&E[((size_t)b * 64 + row) * NN + n0 + kpe], &lA[(w * 2 + i) * 512]);
    }
#pragma unroll
    for (int i = 0; i < 8; i++){        // lB: 2048 units, 8/thread
      int q = (w * 8 + i) * 64 + lane;
      int row = q >> 3, kpe = swz8(row, q & 7);
      g2l16(&xnTb[((size_t)b * CC + row) * NN + n0 + kpe], &lB[(w * 8 + i) * 512]);
    }
    __syncthreads();
    mma_core<1, 1>(lA, 64, lB, 64, acc, 0, w * 64, lane);
    __syncthreads();
  }
  int rb4 = (lane >> 4) * 4, cb = lane & 15;
#pragma unroll
  for (int m = 0; m < 4; m++)
#pragma unroll
    for (int n = 0; n < 4; n++)
#pragma unroll
      for (int j = 0; j < 4; j++){
        int s = m * 16 + rb4 + j, c = w * 64 + n * 16 + cb;
        part[(((size_t)b * 8 + ks) * 64 + s) * 256 + c] = acc[m][n][j];
      }
}

// ---------------- fold partials -> slots bf16 ----------------
__global__ __launch_bounds__(256) void k_fold(const float* __restrict__ part, const float* __restrict__ invz1,
                                              uint16_t* __restrict__ slotsb){
  int i = blockIdx.x * 256 + threadIdx.x;
  int row = i >> 6, c4 = i & 63;
  int b = row >> 6, s = row & 63;
  float4 a = {0.f, 0.f, 0.f, 0.f};
#pragma unroll
  for (int p = 0; p < 8; p++){
    float4 v = *(const float4*)&part[(((size_t)b * 8 + p) * 64 + s) * 256 + c4 * 4];
    a.x += v.x; a.y += v.y; a.z += v.z; a.w += v.w;
  }
  float iz = invz1[row];
  u16x4 o; o[0] = f2b(a.x * iz); o[1] = f2b(a.y * iz); o[2] = f2b(a.z * iz); o[3] = f2b(a.w * iz);
  *(u16x4*)&slotsb[(size_t)row * 256 + c4 * 4] = o;
}

// ---------------- qkv GEMM: [1024 x 768] = slotsb @ wib^T + bi (fp32 out) ----------------
__global__ __launch_bounds__(256) void k_gemm_qkv(const uint16_t* __restrict__ slotsb,
                                                  const uint16_t* __restrict__ wib,
                                                  const float* __restrict__ bi,
                                                  float* __restrict__ qkv){
  __shared__ uint16_t lA[128 * 64];
  __shared__ uint16_t lB[128 * 64];
  int t = threadIdx.x, lane = t & 63, w = t >> 6;
  int wrow = (w >> 1) * 64, wcol = (w & 1) * 64;
  int BR = blockIdx.x * 128, BC = blockIdx.y * 128;
  f32x4 acc[4][4];
#pragma unroll
  for (int m = 0; m < 4; m++)
#pragma unroll
    for (int n = 0; n < 4; n++) acc[m][n] = (f32x4){0.f, 0.f, 0.f, 0.f};
  for (int kc = 0; kc < 4; kc++){
#pragma unroll
    for (int i = 0; i < 4; i++){
      int idx = i * 256 + t, row = idx >> 3, kp = idx & 7;
      *(u16x8*)&lA[row * 64 + swz8(row, kp)] = *(const u16x8*)&slotsb[(size_t)(BR + row) * 256 + kc * 64 + kp * 8];
      *(u16x8*)&lB[row * 64 + swz8(row, kp)] = *(const u16x8*)&wib[(size_t)(BC + row) * 256 + kc * 64 + kp * 8];
    }
    __syncthreads();
    mma_core<1, 1>(lA, 64, lB, 64, acc, wrow, wcol, lane);
    __syncthreads();
  }
  int rb4 = (lane >> 4) * 4, cb = lane & 15;
#pragma unroll
  for (int m = 0; m < 4; m++)
#pragma unroll
    for (int n = 0; n < 4; n++){
      int c = BC + wcol + n * 16 + cb;
      float bias = bi[c];
#pragma unroll
      for (int j = 0; j < 4; j++)
        qkv[(size_t)(BR + wrow + m * 16 + rb4 + j) * 768 + c] = acc[m][n][j] + bias;
    }
}

// ---------------- per (b,h) attention over S=64 -> aob bf16 ----------------
__global__ __launch_bounds__(256) void k_attn(const float* __restrict__ qkv, uint16_t* __restrict__ aob){
  int b = blockIdx.x >> 3, h = blockIdx.x & 7;
  __shared__ float lq[64][33], lk[64][33], lv[64][33];
  __shared__ float sc[64][65];
  int t = threadIdx.x;
  for (int idx = t; idx < 64 * 32; idx += 256){
    int s = idx >> 5, d = idx & 31;
    const float* base = qkv + ((size_t)b * SS + s) * 768 + h * DH + d;
    lq[s][d] = base[0];
    lk[s][d] = base[256];
    lv[s][d] = base[512];
  }
  __syncthreads();
  const float rs = 0.17677669529663687f;
  for (int idx = t; idx < 64 * 64; idx += 256){
    int qq = idx >> 6, kk = idx & 63;
    float a = 0.f;
#pragma unroll
    for (int d = 0; d < 32; d++) a += lq[qq][d] * lk[kk][d];
    sc[qq][kk] = a * rs;
  }
  __syncthreads();
  {
    int r = t >> 2, sub = t & 3;
    float m = -1e30f;
#pragma unroll
    for (int k = sub * 16; k < sub * 16 + 16; k++) m = fmaxf(m, sc[r][k]);
    m = fmaxf(m, __shfl_xor(m, 1, 64));
    m = fmaxf(m, __shfl_xor(m, 2, 64));
    float z = 0.f;
#pragma unroll
    for (int k = sub * 16; k < sub * 16 + 16; k++){
      float e = __expf(sc[r][k] - m); sc[r][k] = e; z += e;
    }
    z += __shfl_xor(z, 1, 64);
    z += __shfl_xor(z, 2, 64);
    float iv = 1.0f / z;
#pragma unroll
    for (int k = sub * 16; k < sub * 16 + 16; k++) sc[r][k] *= iv;
  }
  __syncthreads();
  for (int idx = t; idx < 64 * 32; idx += 256){
    int qq = idx >> 5, d = idx & 31;
    float a = 0.f;
#pragma unroll
    for (int k = 0; k < 64; k++) a += sc[qq][k] * lv[k][d];
    aob[((size_t)b * SS + qq) * CC + h * DH + d] = f2b(a);
  }
}

// ---------------- oproj GEMM: sl2T[b][c][s] = (aob @ wob^T + bo)^T bf16 ----------------
__global__ __launch_bounds__(256) void k_gemm_oproj(const uint16_t* __restrict__ aob,
                                                    const uint16_t* __restrict__ wob,
                                                    const float* __restrict__ bo,
                                                    uint16_t* __restrict__ sl2Tb){
  __shared__ uint16_t lA[128 * 64];
  __shared__ uint16_t lB[128 * 64];
  int t = threadIdx.x, lane = t & 63, w = t >> 6;
  int wrow = (w >> 1) * 64, wcol = (w & 1) * 64;
  int BR = blockIdx.x * 128, BC = blockIdx.y * 128;
  f32x4 acc[4][4];
#pragma unroll
  for (int m = 0; m < 4; m++)
#pragma unroll
    for (int n = 0; n < 4; n++) acc[m][n] = (f32x4){0.f, 0.f, 0.f, 0.f};
  for (int kc = 0; kc < 4; kc++){
#pragma unroll
    for (int i = 0; i < 4; i++){
      int idx = i * 256 + t, row = idx >> 3, kp = idx & 7;
      *(u16x8*)&lA[row * 64 + swz8(row, kp)] = *(const u16x8*)&aob[(size_t)(BR + row) * 256 + kc * 64 + kp * 8];
      *(u16x8*)&lB[row * 64 + swz8(row, kp)] = *(const u16x8*)&wob[(size_t)(BC + row) * 256 + kc * 64 + kp * 8];
    }
    __syncthreads();
    mma_core<1, 1>(lA, 64, lB, 64, acc, wrow, wcol, lane);
    __syncthreads();
  }
  int rb4 = (lane >> 4) * 4, cb = lane & 15;
#pragma unroll
  for (int m = 0; m < 4; m++)
#pragma unroll
    for (int n = 0; n < 4; n++){
      int c = BC + wcol + n * 16 + cb;
      float bias = bo[c];
#pragma unroll
      for (int j = 0; j < 4; j++){
        int r = BR + wrow + m * 16 + rb4 + j;
        int b = r >> 6, s = r & 63;
        sl2Tb[((size_t)b * 256 + c) * 64 + s] = f2b(acc[m][n][j] + bias);
      }
    }
}

// ---------------- mix GEMM (pt fused): mixb[n][c] = (E^T[n][s]/z2[n]) @ sl2T[c][s] ----------------
__global__ __launch_bounds__(256) void k_mix(const uint16_t* __restrict__ E, const uint16_t* __restrict__ sl2Tb,
                                             uint16_t* __restrict__ mixb){
  __shared__ uint16_t lA[128 * 72];    // E^T tile [n_local][s] (padded stride, no swizzle)
  __shared__ uint16_t lB[128 * 64];    // sl2T rows [c][s] (swizzled)
  __shared__ float z2S[128];
  int t = threadIdx.x, lane = t & 63, w = t >> 6;
  int wrow = (w >> 1) * 64, wcol = (w & 1) * 64;
  int BR = blockIdx.x * 128, BC = blockIdx.y * 128, b = blockIdx.z;
#pragma unroll
  for (int i = 0; i < 4; i++){
    int idx = i * 256 + t; int s = idx >> 4, n8 = (idx & 15) * 8;
    u16x8 v = *(const u16x8*)&E[((size_t)b * 64 + s) * NN + BR + n8];
#pragma unroll
    for (int j = 0; j < 8; j++) lA[(n8 + j) * 72 + s] = v[j];
  }
#pragma unroll
  for (int i = 0; i < 4; i++){
    int idx = i * 256 + t, row = idx >> 3, kp = idx & 7;
    *(u16x8*)&lB[row * 64 + swz8(row, kp)] = *(const u16x8*)&sl2Tb[((size_t)b * 256 + BC + row) * 64 + kp * 8];
  }
  __syncthreads();
  if (t < 128){
    float s = 0.f;
#pragma unroll
    for (int k2 = 0; k2 < 64; k2++) s += b2f(lA[t * 72 + k2]);
    z2S[t] = 1.0f / s;
  }
  __syncthreads();
  f32x4 acc[4][4];
#pragma unroll
  for (int m = 0; m < 4; m++)
#pragma unroll
    for (int n = 0; n < 4; n++) acc[m][n] = (f32x4){0.f, 0.f, 0.f, 0.f};
  mma_core<0, 1>(lA, 72, lB, 64, acc, wrow, wcol, lane);
  int rb4 = (lane >> 4) * 4, cb = lane & 15;
#pragma unroll
  for (int m = 0; m < 4; m++)
#pragma unroll
    for (int n = 0; n < 4; n++)
#pragma unroll
      for (int j = 0; j < 4; j++){
        int lrow = wrow + m * 16 + rb4 + j;
        size_t gi = ((size_t)b * NN + BR + lrow) * 256 + BC + wcol + n * 16 + cb;
        mixb[gi] = f2b(acc[m][n][j] * z2S[lrow]);
      }
}

// ---------------- pconv as 9-tap MFMA GEMM (g2l16 + pre-swizzled source) ----------------
__global__ __launch_bounds__(256) void k_pconv_mfma(const uint16_t* __restrict__ xn2p,
                                                    const uint16_t* __restrict__ wp2,
                                                    uint16_t* __restrict__ pcb){
  __shared__ uint16_t lA[256 * 64];
  __shared__ uint16_t lB[64 * 64];
  int t = threadIdx.x, lane = t & 63, w = t >> 6;
  int wrow = w * 64;
  int BR = blockIdx.x * 256;
  f32x4 acc[4][4];
#pragma unroll
  for (int m = 0; m < 4; m++)
#pragma unroll
    for (int n = 0; n < 4; n++) acc[m][n] = (f32x4){0.f, 0.f, 0.f, 0.f};
  for (int tap = 0; tap < 9; tap++){
    int dy = tap / 3 - 1, dx = tap % 3 - 1;
#pragma unroll
    for (int i = 0; i < 8; i++){
      int q = (w * 8 + i) * 64 + lane;
      int row = q >> 3, kpe = swz8(row, q & 7);
      int r = BR + row;
      int b = r >> 12, n = r & 4095, y = n >> 6, x = n & 63;
      size_t p = ((size_t)(b * 66 + (y + 1 + dy)) * 66 + (x + 1 + dx)) * 64 + kpe;
      g2l16(&xn2p[p], &lA[(w * 8 + i) * 512]);
    }
#pragma unroll
    for (int i = 0; i < 2; i++){
      int q = (w * 2 + i) * 64 + lane;
      int row = q >> 3, kpe = swz8(row, q & 7);
      g2l16(&wp2[(size_t)row * 576 + tap * 64 + kpe], &lB[(w * 2 + i) * 512]);
    }
    __syncthreads();
    mma_core<1, 1>(lA, 64, lB, 64, acc, wrow, 0, lane);
    __syncthreads();
  }
  int rb4 = (lane >> 4) * 4, cb = lane & 15;
#pragma unroll
  for (int m = 0; m < 4; m++)
#pragma unroll
    for (int n = 0; n < 4; n++)
#pragma unroll
      for (int j = 0; j < 4; j++)
        pcb[(size_t)(BR + wrow + m * 16 + rb4 + j) * 64 + (n * 16 + cb)] = f2b(acc[m][n][j]);
}

// ---------------- lin1 MFMA + gelu -> Y1b/Y2b (1-D grid 4096, XCD-remapped) ----------------
__global__ __launch_bounds__(256) void k_lin1_mfma(const uint16_t* __restrict__ pcb,
                                                   const uint16_t* __restrict__ xn2b,
                                                   const uint16_t* __restrict__ w1b,
                                                   const float* __restrict__ b1,
                                                   uint16_t* __restrict__ Y1b, uint16_t* __restrict__ Y2b){
  __shared__ uint16_t lA[128 * 64];
  __shared__ uint16_t lB[128 * 64];
  int t = threadIdx.x, lane = t & 63, w = t >> 6;
  int wrow = (w >> 1) * 64, wcol = (w & 1) * 64;
  int bid = blockIdx.x;
  int xcd = bid & 7, i5 = bid >> 3;         // i5 in [0,512)
  int BR = (xcd * 64 + (i5 >> 3)) * 128;
  int BC = (i5 & 7) * 128;
  f32x4 acc[4][4];
#pragma unroll
  for (int m = 0; m < 4; m++)
#pragma unroll
    for (int n = 0; n < 4; n++) acc[m][n] = (f32x4){0.f, 0.f, 0.f, 0.f};
  for (int kc = 0; kc < 4; kc++){
#pragma unroll
    for (int i = 0; i < 4; i++){
      int q = (w * 4 + i) * 64 + lane;
      int row = q >> 3, kpe = swz8(row, q & 7);
      size_t gr = (size_t)(BR + row);
      const uint16_t* src = (kc == 0) ? &pcb[gr * 64 + kpe] : &xn2b[gr * 256 + kc * 64 + kpe];
      g2l16(src, &lA[(w * 4 + i) * 512]);
      g2l16(&w1b[(size_t)(BC + row) * 256 + kc * 64 + kpe], &lB[(w * 4 + i) * 512]);
    }
    __syncthreads();
    mma_core<1, 1>(lA, 64, lB, 64, acc, wrow, wcol, lane);
    __syncthreads();
  }
  int rb4 = (lane >> 4) * 4, cb = lane & 15;
#pragma unroll
  for (int m = 0; m < 4; m++){
#pragma unroll
    for (int n = 0; n < 4; n++){
      int c = BC + wcol + n * 16 + cb;
      float bias = b1[c];
#pragma unroll
      for (int j = 0; j < 4; j++){
        size_t r = (size_t)(BR + wrow + m * 16 + rb4 + j);
        uint16_t h = f2b(gelu_fast(acc[m][n][j] + bias));
        if (c < HID) Y1b[r * HID + c] = h;
        else         Y2b[r * HID + (c - HID)] = h;
      }
    }
  }
}

// ------- dwconv 3x3 + gelu, fused *Y2 — LDS-tiled: block = 16px (row seg) × 128ch -------
// grid (256 = 64rows × 4segs, 4 ch-chunks, BB). Halo tile 3×18×128 staged once; zero borders.
__global__ __launch_bounds__(256) void k_dwconv(const uint16_t* __restrict__ Y1b,
                                                const float* __restrict__ dwwT,   // [tap][512]
                                                const float* __restrict__ dwb,
                                                const uint16_t* __restrict__ Y2b,
                                                uint16_t* __restrict__ YPb){
  __shared__ uint16_t lds[3 * 18 * 136];   // px-stride 136 elems (272B) -> bank-shift 4/px
  int b = blockIdx.z, chunk = blockIdx.y;
  int y = blockIdx.x >> 2, seg = blockIdx.x & 3;
  int x0 = seg * 16;
  int t = threadIdx.x;
  const uint16_t* base = Y1b + (size_t)b * NN * HID + chunk * 128;
  const u16x8 z = {0, 0, 0, 0, 0, 0, 0, 0};
#pragma unroll
  for (int i = 0; i < 4; i++){
    int idx = i * 256 + t;
    if (idx < 864){                         // 3 rows × 18 px × 16 ch-groups
      int g8 = idx & 15, rest = idx >> 4;
      int c = rest % 18, r = rest / 18;
      int ry = y + r - 1, xx = x0 + c - 1;
      u16x8 v = z;
      if (ry >= 0 && ry < HH && xx >= 0 && xx < WW)
        v = *(const u16x8*)&base[(size_t)(ry * WW + xx) * HID + g8 * 8];
      *(u16x8*)&lds[(r * 18 + c) * 136 + g8 * 8] = v;
    }
  }
  __syncthreads();
  int px = t >> 4, g8 = t & 15;
  int cg = chunk * 128 + g8 * 8;
  int n = y * WW + x0 + px;
  u16x8 y2 = *(const u16x8*)&Y2b[((size_t)b * NN + n) * HID + cg];
  float acc[8];
  {
    float4 b0 = *(const float4*)&dwb[cg];
    float4 b1 = *(const float4*)&dwb[cg + 4];
    acc[0] = b0.x; acc[1] = b0.y; acc[2] = b0.z; acc[3] = b0.w;
    acc[4] = b1.x; acc[5] = b1.y; acc[6] = b1.z; acc[7] = b1.w;
  }
#pragma unroll
  for (int r = 0; r < 3; r++)
#pragma unroll
    for (int dx = 0; dx < 3; dx++){
      u16x8 v = *(const u16x8*)&lds[(r * 18 + px + dx) * 136 + g8 * 8];
      const float* wt = &dwwT[(r * 3 + dx) * HID + cg];
      float4 w0 = *(const float4*)wt;
      float4 w1 = *(const float4*)(wt + 4);
      acc[0] += b2f(v[0]) * w0.x; acc[1] += b2f(v[1]) * w0.y;
      acc[2] += b2f(v[2]) * w0.z; acc[3] += b2f(v[3]) * w0.w;
      acc[4] += b2f(v[4]) * w1.x; acc[5] += b2f(v[5]) * w1.y;
      acc[6] += b2f(v[6]) * w1.z; acc[7] += b2f(v[7]) * w1.w;
    }
  u16x8 o;
#pragma unroll
  for (int j = 0; j < 8; j++) o[j] = f2b(gelu_fast(acc[j]) * b2f(y2[j]));
  *(u16x8*)&YPb[((size_t)b * NN + n) * HID + cg] = o;
}

// ---------------- lin2 MFMA: deltab = YP @ w2^T + b2 (1-D grid 1024, XCD-remapped) ----------------
__global__ __launch_bounds__(256) void k_lin2_mfma(const uint16_t* __restrict__ YPb,
                                                   const uint16_t* __restrict__ w2b,
                                                   const float* __restrict__ b2,
                                                   uint16_t* __restrict__ deltab){
  __shared__ uint16_t lA[128 * 64];
  __shared__ uint16_t lB[128 * 64];
  int t = threadIdx.x, lane = t & 63, w = t >> 6;
  int wrow = (w >> 1) * 64, wcol = (w & 1) * 64;
  int bid = blockIdx.x;
  int xcd = bid & 7, i5 = bid >> 3;         // i5 in [0,128)
  int BR = (xcd * 64 + (i5 >> 1)) * 128;
  int BC = (i5 & 1) * 128;
  f32x4 acc[4][4];
#pragma unroll
  for (int m = 0; m < 4; m++)
#pragma unroll
    for (int n = 0; n < 4; n++) acc[m][n] = (f32x4){0.f, 0.f, 0.f, 0.f};
  for (int kc = 0; kc < 8; kc++){
#pragma unroll
    for (int i = 0; i < 4; i++){
      int q = (w * 4 + i) * 64 + lane;
      int row = q >> 3, kpe = swz8(row, q & 7);
      g2l16(&YPb[(size_t)(BR + row) * HID + kc * 64 + kpe], &lA[(w * 4 + i) * 512]);
      g2l16(&w2b[(size_t)(BC + row) * HID + kc * 64 + kpe], &lB[(w * 4 + i) * 512]);
    }
    __syncthreads();
    mma_core<1, 1>(lA, 64, lB, 64, acc, wrow, wcol, lane);
    __syncthreads();
  }
  int rb4 = (lane >> 4) * 4, cb = lane & 15;
#pragma unroll
  for (int m = 0; m < 4; m++){
#pragma unroll
    for (int n = 0; n < 4; n++){
      int c = BC + wcol + n * 16 + cb;
      float bias = b2[c];
#pragma unroll
      for (int j = 0; j < 4; j++){
        size_t gr = (size_t)(BR + wrow + m * 16 + rb4 + j);
        deltab[gr * CC + c] = f2b(acc[m][n][j] + bias);
      }
    }
  }
}

// ---------------- final: v = mixb+deltab; out0 = xhwcb + v (NCHW), out1 = -v ----------------
__global__ __launch_bounds__(256) void k_final2(const uint16_t* __restrict__ mixb,
                                                const uint16_t* __restrict__ deltab,
                                                const uint16_t* __restrict__ xhwcb,
                                                float* __restrict__ out){
  __shared__ float t0[64 * 68];
  __shared__ float t1[64 * 68];
  int b = blockIdx.z;
  int n0 = blockIdx.x * 64, c0 = blockIdx.y * 64;
  int t = threadIdx.x;
#pragma unroll
  for (int i = 0; i < 4; i++){
    int idx = i * 256 + t, row = idx >> 4, c4 = idx & 15;
    size_t gp = ((size_t)b * NN + n0 + row) * CC + c0 + c4 * 4;
    u16x4 m = *(const u16x4*)&mixb[gp];
    u16x4 d = *(const u16x4*)&deltab[gp];
    u16x4 xh = *(const u16x4*)&xhwcb[gp];
    f32x4 v0, v1;
#pragma unroll
    for (int j = 0; j < 4; j++){
      float v = b2f(m[j]) + b2f(d[j]);
      v0[j] = b2f(xh[j]) + v;
      v1[j] = -v;
    }
    *(f32x4*)&t0[row * 68 + c4 * 4] = v0;
    *(f32x4*)&t1[row * 68 + c4 * 4] = v1;
  }
  __syncthreads();
  int cl = t >> 2, seg = t & 3;
  float* o1 = out + (size_t)BB * CC * NN;
  size_t gbase = ((size_t)(b * CC + c0 + cl)) * NN + n0 + seg * 16;
#pragma unroll
  for (int k = 0; k < 4; k++){
    float4 a, c;
    a.x = t0[(seg * 16 + k * 4 + 0) * 68 + cl];
    a.y = t0[(seg * 16 + k * 4 + 1) * 68 + cl];
    a.z = t0[(seg * 16 + k * 4 + 2) * 68 + cl];
    a.w = t0[(seg * 16 + k * 4 + 3) * 68 + cl];
    c.x = t1[(seg * 16 + k * 4 + 0) * 68 + cl];
    c.y = t1[(seg * 16 + k * 4 + 1) * 68 + cl];
    c.z = t1[(seg * 16 + k * 4 + 2) * 68 + cl];
    c.w = t1[(seg * 16 + k * 4 + 3) * 68 + cl];
    *(float4*)&out[gbase + k * 4] = a;
    *(float4*)&o1[gbase + k * 4] = c;
  }
}

extern "C" void kernel_launch(void* const* d_in, const int* in_sizes, int n_in,
                              void* d_out, int out_size, void* d_ws, size_t ws_size,
                              hipStream_t stream){
  const float* x       = (const float*)d_in[0];
  const float* scale_p = (const float*)d_in[1];
  const float* n1w     = (const float*)d_in[2];
  const float* n1b     = (const float*)d_in[3];
  const float* wi      = (const float*)d_in[4];
  const float* bi      = (const float*)d_in[5];
  const float* wo      = (const float*)d_in[6];
  const float* bo      = (const float*)d_in[7];
  const float* n2w     = (const float*)d_in[8];
  const float* n2b     = (const float*)d_in[9];
  const float* pw      = (const float*)d_in[10];
  const float* w1      = (const float*)d_in[11];
  const float* b1      = (const float*)d_in[12];
  const float* dww     = (const float*)d_in[13];
  const float* dwb     = (const float*)d_in[14];
  const float* w2      = (const float*)d_in[15];
  const float* b2      = (const float*)d_in[16];

  // ---- workspace layout (float units) — total ≈ 451 MB, ws = 512 MiB ----
  float* base = (float*)d_ws;
  size_t off = 0;
  float* part = base + off; off += (size_t)BB * 8 * SS * CC;
  float* QKV  = base + off; off += (size_t)BB * SS * 3 * CC;
  float* RN   = base + off; off += (size_t)BB * NN;
  float* IZ1  = base + off; off += (size_t)BB * SS;
  float* dwwT = base + off; off += (size_t)9 * HID;
  uint16_t* slotsNb = (uint16_t*)(base + off); off += (size_t)BB * SS * CC / 2;
  uint16_t* slotsb  = (uint16_t*)(base + off); off += (size_t)BB * SS * CC / 2;
  uint16_t* aob     = (uint16_t*)(base + off); off += (size_t)BB * SS * CC / 2;
  uint16_t* sl2Tb   = (uint16_t*)(base + off); off += (size_t)BB * CC * SS / 2;
  uint16_t* xhwcb   = (uint16_t*)(base + off); off += (size_t)BB * NN * CC / 2;
  uint16_t* xnb     = (uint16_t*)(base + off); off += (size_t)BB * NN * CC / 2;
  uint16_t* xnTb    = (uint16_t*)(base + off); off += (size_t)BB * NN * CC / 2;   // xn transposed [b][c][n]
  uint16_t* mixb    = (uint16_t*)(base + off); off += (size_t)BB * NN * CC / 2;
  uint16_t* deltab  = (uint16_t*)(base + off); off += (size_t)BB * NN * CC / 2;
  uint16_t* E       = (uint16_t*)(base + off); off += (size_t)BB * SS * NN / 2;
  uint16_t* w1b     = (uint16_t*)(base + off); off += (size_t)(2 * HID) * CC / 2;
  uint16_t* w2b     = (uint16_t*)(base + off); off += (size_t)CC * HID / 2;
  uint16_t* wib     = (uint16_t*)(base + off); off += (size_t)(3 * CC) * CC / 2;
  uint16_t* wob     = (uint16_t*)(base + off); off += (size_t)CC * CC / 2;
  uint16_t* wp2     = (uint16_t*)(base + off); off += (size_t)64 * 576 / 2 + 16;
  uint16_t* Y1b     = (uint16_t*)(base + off); off += (size_t)BB * NN * HID / 2;
  uint16_t* Y2b     = (uint16_t*)(base + off); off += (size_t)BB * NN * HID / 2;
  uint16_t* YPb     = (uint16_t*)(base + off); off += (size_t)BB * NN * HID / 2;
  uint16_t* xn2b    = (uint16_t*)(base + off); off += (size_t)BB * NN * CC / 2;
  uint16_t* xn2p    = (uint16_t*)(base + off); off += (size_t)BB * 66 * 66 * 64 / 2;
  uint16_t* pcb     = (uint16_t*)(base + off); off += (size_t)BB * NN * 64 / 2;
  if (ws_size < off * sizeof(float)) return;
  float* OUT = (float*)d_out;

  dim3 tb2(32, 8);
  // ---- slot-mixing phase ----
  k_t2b<<<dim3(NN / 32, CC / 64, BB), tb2, 0, stream>>>(x, xhwcb);
  k_pool<<<BB * SS, 256, 0, stream>>>(xhwcb, slotsNb);
  k_ln_w<<<BB * NN / 4, 256, 0, stream>>>(xhwcb, (const uint16_t*)nullptr, n1w, n1b, xnb, RN,
                                          (uint16_t*)nullptr);
  k_cvtw<<<803, 256, 0, stream>>>(wi, wo, w1, w2, pw, dww, wib, wob, w1b, w2b, wp2, dwwT);
  k_zb<<<(16 * 260 * 16 + 255) / 256, 256, 0, stream>>>(xn2p);
  k_logits_mfma<<<dim3(NN / 256, BB), 256, 0, stream>>>(slotsNb, xnb, RN, scale_p, E);
  k_txT<<<dim3(NN / 64, CC / 64, BB), 256, 0, stream>>>(xnb, xnTb);
  k_z1<<<BB * SS, 256, 0, stream>>>(E, IZ1);
  k_slots_mfma<<<dim3(8, BB), 256, 0, stream>>>(E, xnTb, part);
  k_fold<<<(BB * SS * CC / 4) / 256, 256, 0, stream>>>(part, IZ1, slotsb);
  k_gemm_qkv<<<dim3(8, 6), 256, 0, stream>>>(slotsb, wib, bi, QKV);
  k_attn<<<BB * NHEAD, 256, 0, stream>>>(QKV, aob);
  k_gemm_oproj<<<dim3(8, 2), 256, 0, stream>>>(aob, wob, bo, sl2Tb);
  k_mix<<<dim3(NN / 128, CC / 128, BB), 256, 0, stream>>>(E, sl2Tb, mixb);
  // ---- FRFN phase ----
  k_ln_w<<<BB * NN / 4, 256, 0, stream>>>(xhwcb, mixb, n2w, n2b, xn2b, (float*)nullptr, xn2p);
  k_pconv_mfma<<<BB * NN / 256, 256, 0, stream>>>(xn2p, wp2, pcb);
  k_lin1_mfma<<<4096, 256, 0, stream>>>(pcb, xn2b, w1b, b1, Y1b, Y2b);
  k_dwconv<<<dim3(256, 4, BB), 256, 0, stream>>>(Y1b, dwwT, dwb, Y2b, YPb);
  k_lin2_mfma<<<1024, 256, 0, stream>>>(YPb, w2b, b2, deltab);
  // ---- fused residual/transpose output ----
  k_final2<<<dim3(NN / 64, CC / 64, BB), 256, 0, stream>>>(mixb, deltab, xhwcb, OUT);
}

// Round 19
// 409.620 us; speedup vs baseline: 1.4999x; 1.0470x over previous
//
#include <hip/hip_runtime.h>
#include <hip/hip_bf16.h>
#include <stdint.h>
#include <math.h>

#define BB 16
#define CC 256
#define HH 64
#define WW 64
#define NN 4096   // HH*WW
#define SS 64
#define NHEAD 8
#define DH 32
#define HID 512
#define DC 64

typedef float    f32x4  __attribute__((ext_vector_type(4)));
typedef uint16_t u16x8  __attribute__((ext_vector_type(8)));
typedef uint16_t u16x4  __attribute__((ext_vector_type(4)));
typedef uint16_t u16x2  __attribute__((ext_vector_type(2)));

// tanh-gelu in sigmoid form: 0.5x(1+tanh(u)) == x*e^z/(e^z+1), z=2u  (identical math, fewer ops)
__device__ __forceinline__ float gelu_fast(float x){
  float z = x * (1.5957691216057308f + 0.07135481627613705f * x * x);
  float e = __expf(z);
  float r = __builtin_amdgcn_rcpf(e + 1.0f);
  return x * e * r;
}
__device__ __forceinline__ uint16_t f2b(float f){
  union { float f; uint32_t u; } v; v.f = f;
  uint32_t r = v.u + 0x7fffu + ((v.u >> 16) & 1u);
  return (uint16_t)(r >> 16);
}
__device__ __forceinline__ float b2f(uint16_t h){
  union { uint32_t u; float f; } v; v.u = ((uint32_t)h) << 16;
  return v.f;
}

__device__ __forceinline__ float waveSum(float v){
#pragma unroll
  for (int m = 32; m >= 1; m >>= 1) v += __shfl_xor(v, m, 64);
  return v;
}
__device__ __forceinline__ float blockSum256(float v, float* s4){
  v = waveSum(v);
  __syncthreads();
  if ((threadIdx.x & 63) == 0) s4[threadIdx.x >> 6] = v;
  __syncthreads();
  return s4[0] + s4[1] + s4[2] + s4[3];
}

// ---- async global->LDS, 16B per lane (dest = wave-uniform base + lane*16) ----
__device__ __forceinline__ void g2l16(const void* g, void* l){
  __builtin_amdgcn_global_load_lds((const __attribute__((address_space(1))) uint32_t*)g,
                                   (__attribute__((address_space(3))) uint32_t*)l, 16, 0, 0);
}

// XOR swizzle for 64-elem (128B) rows: 16B-unit u' = u ^ (row&7).  [G4/T2/m173]
__device__ __forceinline__ int swz8(int row, int kp){ return (kp ^ (row & 7)) << 3; }

// ---- MFMA 16x16x32 bf16 via inline asm (D=C in-place) ----
// A/B frag: lane l holds row/col (l&15), k = (l>>4)*8 + e
// D: col = lane&15, row = (lane>>4)*4 + reg   [m89-verified]
__device__ __forceinline__ void mfma_bf16(f32x4& d, u16x8 a, u16x8 b){
  asm volatile("v_mfma_f32_16x16x32_bf16 %0, %1, %2, %0" : "+v"(d) : "v"(a), "v"(b));
}

// 4x4-fragment core over one BK=64 LDS tile; SWA/SWB: operand stored swizzled (lda/ldb==64 only)
template<int SWA, int SWB>
__device__ __forceinline__ void mma_core(const uint16_t* lA, int lda, const uint16_t* lB, int ldb,
                                         f32x4 (&acc)[4][4], int wrow, int wcol, int lane){
  const int rb = lane & 15, ub = lane >> 4;
#pragma unroll
  for (int ks = 0; ks < 2; ks++){
    const int u = ks * 4 + ub;
    u16x8 af[4], bf[4];
#pragma unroll
    for (int m = 0; m < 4; m++){
      int r = wrow + m * 16 + rb;
      int e = SWA ? ((u ^ (r & 7)) << 3) : (u << 3);
      af[m] = *(const u16x8*)&lA[r * lda + e];
    }
#pragma unroll
    for (int n = 0; n < 4; n++){
      int r = wcol + n * 16 + rb;
      int e = SWB ? ((u ^ (r & 7)) << 3) : (u << 3);
      bf[n] = *(const u16x8*)&lB[r * ldb + e];
    }
#pragma unroll
    for (int m = 0; m < 4; m++)
#pragma unroll
      for (int n = 0; n < 4; n++)
        mfma_bf16(acc[m][n], af[m], bf[n]);
  }
}

// ---------------- K0: x NCHW -> NHWC bf16 ----------------
__global__ __launch_bounds__(256) void k_t2b(const float* __restrict__ in, uint16_t* __restrict__ out){
  __shared__ float tile[64][33];   // [c][n]
  int b = blockIdx.z;
  int n0 = blockIdx.x * 32;
  int c0 = blockIdx.y * 64;
  int tx = threadIdx.x, ty = threadIdx.y;   // (32,8)
  const float* src = in + (size_t)b * CC * NN;
#pragma unroll
  for (int i = 0; i < 64; i += 8)
    tile[ty + i][tx] = src[(size_t)(c0 + ty + i) * NN + n0 + tx];
  __syncthreads();
  uint16_t* dst = out + (size_t)b * NN * CC;
#pragma unroll
  for (int i = 0; i < 32; i += 8){
    int r = ty + i;
    u16x2 o; o[0] = f2b(tile[tx * 2][r]); o[1] = f2b(tile[tx * 2 + 1][r]);
    *(u16x2*)&dst[(size_t)(n0 + r) * CC + c0 + tx * 2] = o;
  }
}

// ---------------- K1: 8x8 pooled slots + l2norm -> bf16 (vectorized) ----------------
__global__ __launch_bounds__(256) void k_pool(const uint16_t* __restrict__ xhwcb, uint16_t* __restrict__ slotsNb){
  int bs = blockIdx.x; int b = bs >> 6, s = bs & 63;
  int sy = (s >> 3) * 8, sx = (s & 7) * 8;
  int t = threadIdx.x;
  int c4 = t & 63, pg = t >> 6;      // channel-quad, pixel-group (16 px each)
  const uint16_t* base = xhwcb + (size_t)b * NN * CC;
  float a0 = 0.f, a1 = 0.f, a2 = 0.f, a3 = 0.f;
#pragma unroll
  for (int i = 0; i < 16; i++){
    int p = pg * 16 + i; int py = p >> 3, px = p & 7;
    u16x4 v = *(const u16x4*)&base[(size_t)((sy + py) * WW + sx + px) * CC + c4 * 4];
    a0 += b2f(v[0]); a1 += b2f(v[1]); a2 += b2f(v[2]); a3 += b2f(v[3]);
  }
  __shared__ float sm[4][64][4];
  sm[pg][c4][0] = a0; sm[pg][c4][1] = a1; sm[pg][c4][2] = a2; sm[pg][c4][3] = a3;
  __syncthreads();
  if (t < 64){
    float v0 = (sm[0][t][0] + sm[1][t][0] + sm[2][t][0] + sm[3][t][0]) * (1.0f / 64.0f);
    float v1 = (sm[0][t][1] + sm[1][t][1] + sm[2][t][1] + sm[3][t][1]) * (1.0f / 64.0f);
    float v2 = (sm[0][t][2] + sm[1][t][2] + sm[2][t][2] + sm[3][t][2]) * (1.0f / 64.0f);
    float v3 = (sm[0][t][3] + sm[1][t][3] + sm[2][t][3] + sm[3][t][3]) * (1.0f / 64.0f);
    float ss = waveSum(v0 * v0 + v1 * v1 + v2 * v2 + v3 * v3);
    float inv = 1.0f / fmaxf(sqrtf(ss), 1e-12f);
    u16x4 o; o[0] = f2b(v0 * inv); o[1] = f2b(v1 * inv); o[2] = f2b(v2 * inv); o[3] = f2b(v3 * inv);
    *(u16x4*)&slotsNb[(size_t)bs * CC + t * 4] = o;
  }
}

// ---- wave-per-row LayerNorm on bf16 (xa [+ xb]) -> bf16 (+ inv l2-norm | + padded-interior write) ----
__global__ __launch_bounds__(256) void k_ln_w(const uint16_t* __restrict__ xa, const uint16_t* __restrict__ xb,
                                              const float* __restrict__ w, const float* __restrict__ b,
                                              uint16_t* __restrict__ xoutb, float* __restrict__ rn,
                                              uint16_t* __restrict__ xn2p){
  int row = blockIdx.x * 4 + (threadIdx.x >> 6);
  int lane = threadIdx.x & 63;
  u16x4 va = *(const u16x4*)&xa[(size_t)row * CC + lane * 4];
  float v0 = b2f(va[0]), v1 = b2f(va[1]), v2 = b2f(va[2]), v3 = b2f(va[3]);
  if (xb){
    u16x4 vb = *(const u16x4*)&xb[(size_t)row * CC + lane * 4];
    v0 += b2f(vb[0]); v1 += b2f(vb[1]); v2 += b2f(vb[2]); v3 += b2f(vb[3]);
  }
  float mu = waveSum(v0 + v1 + v2 + v3) * (1.0f / CC);
  float d0 = v0 - mu, d1 = v1 - mu, d2 = v2 - mu, d3 = v3 - mu;
  float var = waveSum(d0 * d0 + d1 * d1 + d2 * d2 + d3 * d3) * (1.0f / CC);
  float inv = rsqrtf(var + 1e-5f);
  float4 wv = *(const float4*)&w[lane * 4];
  float4 bv = *(const float4*)&b[lane * 4];
  float x0 = d0 * inv * wv.x + bv.x;
  float x1 = d1 * inv * wv.y + bv.y;
  float x2 = d2 * inv * wv.z + bv.z;
  float x3 = d3 * inv * wv.w + bv.w;
  u16x4 o; o[0] = f2b(x0); o[1] = f2b(x1); o[2] = f2b(x2); o[3] = f2b(x3);
  *(u16x4*)&xoutb[(size_t)row * CC + lane * 4] = o;
  if (xn2p && lane < 16){
    int bb = row >> 12, n = row & 4095, y = n >> 6, x = n & 63;
    *(u16x4*)&xn2p[(((size_t)(bb * 66 + y + 1)) * 66 + x + 1) * 64 + lane * 4] = o;
  }
  if (rn){
    float ss = waveSum(x0 * x0 + x1 * x1 + x2 * x2 + x3 * x3);
    if (lane == 0) rn[row] = 1.0f / fmaxf(sqrtf(ss), 1e-12f);
  }
}

// ---------------- border zeros for padded image ----------------
__global__ __launch_bounds__(256) void k_zb(uint16_t* __restrict__ xn2p){
  int i = blockIdx.x * 256 + threadIdx.x;   // (b, j<260, c4<16)
  if (i >= 16 * 260 * 16) return;
  int c4 = i & 15; int rest = i >> 4;
  int j = rest % 260; int b = rest / 260;
  int py, px;
  if (j < 66){ py = 0; px = j; }
  else if (j < 132){ py = 65; px = j - 66; }
  else if (j < 196){ py = j - 132 + 1; px = 0; }
  else { py = j - 196 + 1; px = 65; }
  u16x4 z; z[0] = 0; z[1] = 0; z[2] = 0; z[3] = 0;
  *(u16x4*)&xn2p[(((size_t)(b * 66 + py)) * 66 + px) * 64 + c4 * 4] = z;
}

// ---------------- merged weight conversions (wi|wo|w1|w2|pconv|dwT) ----------------
__global__ __launch_bounds__(256) void k_cvtw(const float* __restrict__ wi, const float* __restrict__ wo,
                                              const float* __restrict__ w1, const float* __restrict__ w2,
                                              const float* __restrict__ pw, const float* __restrict__ dww,
                                              uint16_t* __restrict__ wib, uint16_t* __restrict__ wob,
                                              uint16_t* __restrict__ w1b, uint16_t* __restrict__ w2b,
                                              uint16_t* __restrict__ wp2, float* __restrict__ dwwT){
  int i = blockIdx.x * 256 + threadIdx.x;
  if (i < 163840){
    const float* src; uint16_t* dst; int off;
    if (i < 49152){ src = wi; dst = wib; off = i; }
    else if (i < 65536){ src = wo; dst = wob; off = i - 49152; }
    else if (i < 131072){ src = w1; dst = w1b; off = i - 65536; }
    else { src = w2; dst = w2b; off = i - 131072; }
    float4 v = ((const float4*)src)[off];
    u16x4 o;
    o[0] = f2b(v.x); o[1] = f2b(v.y); o[2] = f2b(v.z); o[3] = f2b(v.w);
    *(u16x4*)&dst[(size_t)off * 4] = o;
  } else if (i < 200704){
    int j = i - 163840;
    if (j < 64 * 576){
      int co = j / 576, r = j % 576, tap = r >> 6, ci = r & 63;
      wp2[j] = f2b(pw[(size_t)co * 576 + ci * 9 + tap]);
    }
  } else {
    int j = i - 200704;                         // dwwT[tap][ch] = dww[ch][tap]
    if (j < 9 * HID){
      int tap = j / HID, ch = j % HID;
      dwwT[j] = dww[(size_t)ch * 9 + tap];
    }
  }
}

// ---------------- xn transpose: xnT[b][c][n] = xn[b][n][c] (bf16, LDS-tiled) ----------------
__global__ __launch_bounds__(256) void k_txT(const uint16_t* __restrict__ xnb, uint16_t* __restrict__ xnTb){
  __shared__ uint16_t tile[64 * 66];   // stride 66 u16 -> conflict-light scalar access
  int b = blockIdx.z;
  int n0 = blockIdx.x * 64, c0 = blockIdx.y * 64;
  int t = threadIdx.x;
#pragma unroll
  for (int i = 0; i < 16; i++){
    int idx = i * 256 + t;             // 0..4095
    int nr = idx >> 6, c = idx & 63;   // coalesced read (consecutive c)
    tile[c * 66 + nr] = xnb[((size_t)b * NN + n0 + nr) * CC + c0 + c];
  }
  __syncthreads();
#pragma unroll
  for (int i = 0; i < 16; i++){
    int idx = i * 256 + t;
    int cr = idx >> 6, n = idx & 63;   // coalesced write (consecutive n)
    xnTb[((size_t)b * CC + c0 + cr) * NN + n0 + n] = tile[cr * 66 + n];
  }
}

// ---------------- logits GEMM + exp epilogue -> E bf16 [b][s][n] ----------------
__global__ __launch_bounds__(256) void k_logits_mfma(const uint16_t* __restrict__ slotsNb,
                                                     const uint16_t* __restrict__ xnb,
                                                     const float* __restrict__ rn,
                                                     const float* __restrict__ scale_p,
                                                     uint16_t* __restrict__ E){
  __shared__ uint16_t smem[20480];      // lA 64x64 | lB 256x64 ; reused as eT 64x264
  __shared__ float rnS[256];
  uint16_t* lA = smem;
  uint16_t* lB = smem + 64 * 64;
  int t = threadIdx.x, lane = t & 63, w = t >> 6;
  int b = blockIdx.y, n0 = blockIdx.x * 256;
  rnS[t] = rn[b * NN + n0 + t];
  f32x4 acc[4][4];
#pragma unroll
  for (int m = 0; m < 4; m++)
#pragma unroll
    for (int n = 0; n < 4; n++) acc[m][n] = (f32x4){0.f, 0.f, 0.f, 0.f};
  for (int kc = 0; kc < 4; kc++){
#pragma unroll
    for (int i = 0; i < 2; i++){
      int idx = i * 256 + t, row = idx >> 3, kp = idx & 7;
      *(u16x8*)&lA[row * 64 + swz8(row, kp)] = *(const u16x8*)&slotsNb[(size_t)(b * 64 + row) * 256 + kc * 64 + kp * 8];
    }
#pragma unroll
    for (int i = 0; i < 8; i++){
      int idx = i * 256 + t, row = idx >> 3, kp = idx & 7;
      *(u16x8*)&lB[row * 64 + swz8(row, kp)] = *(const u16x8*)&xnb[((size_t)b * NN + n0 + row) * 256 + kc * 64 + kp * 8];
    }
    __syncthreads();
    mma_core<1, 1>(lA, 64, lB, 64, acc, 0, w * 64, lane);
    __syncthreads();
  }
  float scale = scale_p[0];
  int rb4 = (lane >> 4) * 4, cb = lane & 15;
#pragma unroll
  for (int m = 0; m < 4; m++)
#pragma unroll
    for (int n = 0; n < 4; n++)
#pragma unroll
      for (int j = 0; j < 4; j++){
        int s = m * 16 + rb4 + j, nl = w * 64 + n * 16 + cb;
        smem[s * 264 + nl] = f2b(__expf(acc[m][n][j] * scale * rnS[nl]));
      }
  __syncthreads();
#pragma unroll
  for (int i = 0; i < 8; i++){
    int idx = i * 256 + t, row = idx >> 5, cseg = idx & 31;
    *(u16x8*)&E[((size_t)b * 64 + row) * NN + n0 + cseg * 8] = *(const u16x8*)&smem[row * 264 + cseg * 8];
  }
}

// ---------------- z1: invz1[b,s] = 1 / sum_n E (vectorized) ----------------
__global__ __launch_bounds__(256) void k_z1(const uint16_t* __restrict__ E, float* __restrict__ invz1){
  int bs = blockIdx.x, t = threadIdx.x;
  u16x8 v0 = *(const u16x8*)&E[(size_t)bs * NN + t * 16];
  u16x8 v1 = *(const u16x8*)&E[(size_t)bs * NN + t * 16 + 8];
  float s = 0.f;
#pragma unroll
  for (int i = 0; i < 8; i++) s += b2f(v0[i]) + b2f(v1[i]);
  __shared__ float s4[4];
  float z = blockSum256(s, s4);
  if (t == 0) invz1[bs] = 1.0f / z;
}

// ------- slots GEMM (8-way K-split, both operands k-major via xnT; no in-kernel transpose) -------
__global__ __launch_bounds__(256) void k_slots_mfma(const uint16_t* __restrict__ E,
                                                    const uint16_t* __restrict__ xnTb,
                                                    float* __restrict__ part){
  __shared__ uint16_t lA[64 * 64];     // E tile: 64 s x 64 k
  __shared__ uint16_t lB[256 * 64];    // xnT tile: 256 c x 64 k  (40KB total)
  int t = threadIdx.x, lane = t & 63, w = t >> 6;
  int ks = blockIdx.x, b = blockIdx.y;
  f32x4 acc[4][4];
#pragma unroll
  for (int m = 0; m < 4; m++)
#pragma unroll
    for (int n = 0; n < 4; n++) acc[m][n] = (f32x4){0.f, 0.f, 0.f, 0.f};
  for (int kc = 0; kc < 8; kc++){
    int n0 = ks * 512 + kc * 64;
#pragma unroll
    for (int i = 0; i < 2; i++){        // lA: 512 units, 2/thread
      int q = (w * 2 + i) * 64 + lane;
      int row = q >> 3, kpe = swz8(row, q & 7);
      g2l16(&E[((size_t)b * 64 + row) * NN + n0 + kpe], &lA[(w * 2 + i) * 512]);
    }
#pragma unroll
    for (int i = 0; i < 8; i++){        // lB: 2048 units, 8/thread
      int q = (w * 8 + i) * 64 + lane;
      int row = q >> 3, kpe = swz8(row, q & 7);
      g2l16(&xnTb[((size_t)b * CC + row) * NN + n0 + kpe], &lB[(w * 8 + i) * 512]);
    }
    __syncthreads();
    mma_core<1, 1>(lA, 64, lB, 64, acc, 0, w * 64, lane);
    __syncthreads();
  }
  int rb4 = (lane >> 4) * 4, cb = lane & 15;
#pragma unroll
  for (int m = 0; m < 4; m++)
#pragma unroll
    for (int n = 0; n < 4; n++)
#pragma unroll
      for (int j = 0; j < 4; j++){
        int s = m * 16 + rb4 + j, c = w * 64 + n * 16 + cb;
        part[(((size_t)b * 8 + ks) * 64 + s) * 256 + c] = acc[m][n][j];
      }
}

// ---------------- fold partials -> slots bf16 ----------------
__global__ __launch_bounds__(256) void k_fold(const float* __restrict__ part, const float* __restrict__ invz1,
                                              uint16_t* __restrict__ slotsb){
  int i = blockIdx.x * 256 + threadIdx.x;
  int row = i >> 6, c4 = i & 63;
  int b = row >> 6, s = row & 63;
  float4 a = {0.f, 0.f, 0.f, 0.f};
#pragma unroll
  for (int p = 0; p < 8; p++){
    float4 v = *(const float4*)&part[(((size_t)b * 8 + p) * 64 + s) * 256 + c4 * 4];
    a.x += v.x; a.y += v.y; a.z += v.z; a.w += v.w;
  }
  float iz = invz1[row];
  u16x4 o; o[0] = f2b(a.x * iz); o[1] = f2b(a.y * iz); o[2] = f2b(a.z * iz); o[3] = f2b(a.w * iz);
  *(u16x4*)&slotsb[(size_t)row * 256 + c4 * 4] = o;
}

// ---------------- qkv GEMM: [1024 x 768] = slotsb @ wib^T + bi (fp32 out) ----------------
__global__ __launch_bounds__(256) void k_gemm_qkv(const uint16_t* __restrict__ slotsb,
                                                  const uint16_t* __restrict__ wib,
                                                  const float* __restrict__ bi,
                                                  float* __restrict__ qkv){
  __shared__ uint16_t lA[128 * 64];
  __shared__ uint16_t lB[128 * 64];
  int t = threadIdx.x, lane = t & 63, w = t >> 6;
  int wrow = (w >> 1) * 64, wcol = (w & 1) * 64;
  int BR = blockIdx.x * 128, BC = blockIdx.y * 128;
  f32x4 acc[4][4];
#pragma unroll
  for (int m = 0; m < 4; m++)
#pragma unroll
    for (int n = 0; n < 4; n++) acc[m][n] = (f32x4){0.f, 0.f, 0.f, 0.f};
  for (int kc = 0; kc < 4; kc++){
#pragma unroll
    for (int i = 0; i < 4; i++){
      int idx = i * 256 + t, row = idx >> 3, kp = idx & 7;
      *(u16x8*)&lA[row * 64 + swz8(row, kp)] = *(const u16x8*)&slotsb[(size_t)(BR + row) * 256 + kc * 64 + kp * 8];
      *(u16x8*)&lB[row * 64 + swz8(row, kp)] = *(const u16x8*)&wib[(size_t)(BC + row) * 256 + kc * 64 + kp * 8];
    }
    __syncthreads();
    mma_core<1, 1>(lA, 64, lB, 64, acc, wrow, wcol, lane);
    __syncthreads();
  }
  int rb4 = (lane >> 4) * 4, cb = lane & 15;
#pragma unroll
  for (int m = 0; m < 4; m++)
#pragma unroll
    for (int n = 0; n < 4; n++){
      int c = BC + wcol + n * 16 + cb;
      float bias = bi[c];
#pragma unroll
      for (int j = 0; j < 4; j++)
        qkv[(size_t)(BR + wrow + m * 16 + rb4 + j) * 768 + c] = acc[m][n][j] + bias;
    }
}

// ---------------- per (b,h) attention over S=64 -> aob bf16 ----------------
__global__ __launch_bounds__(256) void k_attn(const float* __restrict__ qkv, uint16_t* __restrict__ aob){
  int b = blockIdx.x >> 3, h = blockIdx.x & 7;
  __shared__ float lq[64][33], lk[64][33], lv[64][33];
  __shared__ float sc[64][65];
  int t = threadIdx.x;
  for (int idx = t; idx < 64 * 32; idx += 256){
    int s = idx >> 5, d = idx & 31;
    const float* base = qkv + ((size_t)b * SS + s) * 768 + h * DH + d;
    lq[s][d] = base[0];
    lk[s][d] = base[256];
    lv[s][d] = base[512];
  }
  __syncthreads();
  const float rs = 0.17677669529663687f;
  for (int idx = t; idx < 64 * 64; idx += 256){
    int qq = idx >> 6, kk = idx & 63;
    float a = 0.f;
#pragma unroll
    for (int d = 0; d < 32; d++) a += lq[qq][d] * lk[kk][d];
    sc[qq][kk] = a * rs;
  }
  __syncthreads();
  {
    int r = t >> 2, sub = t & 3;
    float m = -1e30f;
#pragma unroll
    for (int k = sub * 16; k < sub * 16 + 16; k++) m = fmaxf(m, sc[r][k]);
    m = fmaxf(m, __shfl_xor(m, 1, 64));
    m = fmaxf(m, __shfl_xor(m, 2, 64));
    float z = 0.f;
#pragma unroll
    for (int k = sub * 16; k < sub * 16 + 16; k++){
      float e = __expf(sc[r][k] - m); sc[r][k] = e; z += e;
    }
    z += __shfl_xor(z, 1, 64);
    z += __shfl_xor(z, 2, 64);
    float iv = 1.0f / z;
#pragma unroll
    for (int k = sub * 16; k < sub * 16 + 16; k++) sc[r][k] *= iv;
  }
  __syncthreads();
  for (int idx = t; idx < 64 * 32; idx += 256){
    int qq = idx >> 5, d = idx & 31;
    float a = 0.f;
#pragma unroll
    for (int k = 0; k < 64; k++) a += sc[qq][k] * lv[k][d];
    aob[((size_t)b * SS + qq) * CC + h * DH + d] = f2b(a);
  }
}

// ---------------- oproj GEMM: sl2T[b][c][s] = (aob @ wob^T + bo)^T bf16 ----------------
__global__ __launch_bounds__(256) void k_gemm_oproj(const uint16_t* __restrict__ aob,
                                                    const uint16_t* __restrict__ wob,
                                                    const float* __restrict__ bo,
                                                    uint16_t* __restrict__ sl2Tb){
  __shared__ uint16_t lA[128 * 64];
  __shared__ uint16_t lB[128 * 64];
  int t = threadIdx.x, lane = t & 63, w = t >> 6;
  int wrow = (w >> 1) * 64, wcol = (w & 1) * 64;
  int BR = blockIdx.x * 128, BC = blockIdx.y * 128;
  f32x4 acc[4][4];
#pragma unroll
  for (int m = 0; m < 4; m++)
#pragma unroll
    for (int n = 0; n < 4; n++) acc[m][n] = (f32x4){0.f, 0.f, 0.f, 0.f};
  for (int kc = 0; kc < 4; kc++){
#pragma unroll
    for (int i = 0; i < 4; i++){
      int idx = i * 256 + t, row = idx >> 3, kp = idx & 7;
      *(u16x8*)&lA[row * 64 + swz8(row, kp)] = *(const u16x8*)&aob[(size_t)(BR + row) * 256 + kc * 64 + kp * 8];
      *(u16x8*)&lB[row * 64 + swz8(row, kp)] = *(const u16x8*)&wob[(size_t)(BC + row) * 256 + kc * 64 + kp * 8];
    }
    __syncthreads();
    mma_core<1, 1>(lA, 64, lB, 64, acc, wrow, wcol, lane);
    __syncthreads();
  }
  int rb4 = (lane >> 4) * 4, cb = lane & 15;
#pragma unroll
  for (int m = 0; m < 4; m++)
#pragma unroll
    for (int n = 0; n < 4; n++){
      int c = BC + wcol + n * 16 + cb;
      float bias = bo[c];
#pragma unroll
      for (int j = 0; j < 4; j++){
        int r = BR + wrow + m * 16 + rb4 + j;
        int b = r >> 6, s = r & 63;
        sl2Tb[((size_t)b * 256 + c) * 64 + s] = f2b(acc[m][n][j] + bias);
      }
    }
}

// ---------------- mix GEMM (pt fused): mixb[n][c] = (E^T[n][s]/z2[n]) @ sl2T[c][s] ----------------
__global__ __launch_bounds__(256) void k_mix(const uint16_t* __restrict__ E, const uint16_t* __restrict__ sl2Tb,
                                             uint16_t* __restrict__ mixb){
  __shared__ uint16_t lA[128 * 72];    // E^T tile [n_local][s] (padded stride, no swizzle)
  __shared__ uint16_t lB[128 * 64];    // sl2T rows [c][s] (swizzled)
  __shared__ float z2S[128];
  int t = threadIdx.x, lane = t & 63, w = t >> 6;
  int wrow = (w >> 1) * 64, wcol = (w & 1) * 64;
  int BR = blockIdx.x * 128, BC = blockIdx.y * 128, b = blockIdx.z;
#pragma unroll
  for (int i = 0; i < 4; i++){
    int idx = i * 256 + t; int s = idx >> 4, n8 = (idx & 15) * 8;
    u16x8 v = *(const u16x8*)&E[((size_t)b * 64 + s) * NN + BR + n8];
#pragma unroll
    for (int j = 0; j < 8; j++) lA[(n8 + j) * 72 + s] = v[j];
  }
#pragma unroll
  for (int i = 0; i < 4; i++){
    int idx = i * 256 + t, row = idx >> 3, kp = idx & 7;
    *(u16x8*)&lB[row * 64 + swz8(row, kp)] = *(const u16x8*)&sl2Tb[((size_t)b * 256 + BC + row) * 64 + kp * 8];
  }
  __syncthreads();
  if (t < 128){
    float s = 0.f;
#pragma unroll
    for (int k2 = 0; k2 < 64; k2++) s += b2f(lA[t * 72 + k2]);
    z2S[t] = 1.0f / s;
  }
  __syncthreads();
  f32x4 acc[4][4];
#pragma unroll
  for (int m = 0; m < 4; m++)
#pragma unroll
    for (int n = 0; n < 4; n++) acc[m][n] = (f32x4){0.f, 0.f, 0.f, 0.f};
  mma_core<0, 1>(lA, 72, lB, 64, acc, wrow, wcol, lane);
  int rb4 = (lane >> 4) * 4, cb = lane & 15;
#pragma unroll
  for (int m = 0; m < 4; m++)
#pragma unroll
    for (int n = 0; n < 4; n++)
#pragma unroll
      for (int j = 0; j < 4; j++){
        int lrow = wrow + m * 16 + rb4 + j;
        size_t gi = ((size_t)b * NN + BR + lrow) * 256 + BC + wcol + n * 16 + cb;
        mixb[gi] = f2b(acc[m][n][j] * z2S[lrow]);
      }
}

// ---------------- pconv as 9-tap MFMA GEMM (g2l16 + pre-swizzled source) ----------------
__global__ __launch_bounds__(256) void k_pconv_mfma(const uint16_t* __restrict__ xn2p,
                                                    const uint16_t* __restrict__ wp2,
                                                    uint16_t* __restrict__ pcb){
  __shared__ uint16_t lA[256 * 64];
  __shared__ uint16_t lB[64 * 64];
  int t = threadIdx.x, lane = t & 63, w = t >> 6;
  int wrow = w * 64;
  int BR = blockIdx.x * 256;
  f32x4 acc[4][4];
#pragma unroll
  for (int m = 0; m < 4; m++)
#pragma unroll
    for (int n = 0; n < 4; n++) acc[m][n] = (f32x4){0.f, 0.f, 0.f, 0.f};
  for (int tap = 0; tap < 9; tap++){
    int dy = tap / 3 - 1, dx = tap % 3 - 1;
#pragma unroll
    for (int i = 0; i < 8; i++){
      int q = (w * 8 + i) * 64 + lane;
      int row = q >> 3, kpe = swz8(row, q & 7);
      int r = BR + row;
      int b = r >> 12, n = r & 4095, y = n >> 6, x = n & 63;
      size_t p = ((size_t)(b * 66 + (y + 1 + dy)) * 66 + (x + 1 + dx)) * 64 + kpe;
      g2l16(&xn2p[p], &lA[(w * 8 + i) * 512]);
    }
#pragma unroll
    for (int i = 0; i < 2; i++){
      int q = (w * 2 + i) * 64 + lane;
      int row = q >> 3, kpe = swz8(row, q & 7);
      g2l16(&wp2[(size_t)row * 576 + tap * 64 + kpe], &lB[(w * 2 + i) * 512]);
    }
    __syncthreads();
    mma_core<1, 1>(lA, 64, lB, 64, acc, wrow, 0, lane);
    __syncthreads();
  }
  int rb4 = (lane >> 4) * 4, cb = lane & 15;
#pragma unroll
  for (int m = 0; m < 4; m++)
#pragma unroll
    for (int j = 0; j < 4; j++){
      uint16_t* rp = &pcb[(size_t)(BR + wrow + m * 16 + rb4 + j) * 64 + cb];
#pragma unroll
      for (int n = 0; n < 4; n++)
        rp[n * 16] = f2b(acc[m][n][j]);
    }
}

// ---------------- lin1 MFMA + gelu -> Y1b/Y2b (1-D grid 4096, XCD-remapped) ----------------
// Epilogue: bias hoist + block-uniform dst + (m,j)-outer loop -> const-offset stores
__global__ __launch_bounds__(256) void k_lin1_mfma(const uint16_t* __restrict__ pcb,
                                                   const uint16_t* __restrict__ xn2b,
                                                   const uint16_t* __restrict__ w1b,
                                                   const float* __restrict__ b1,
                                                   uint16_t* __restrict__ Y1b, uint16_t* __restrict__ Y2b){
  __shared__ uint16_t lA[128 * 64];
  __shared__ uint16_t lB[128 * 64];
  int t = threadIdx.x, lane = t & 63, w = t >> 6;
  int wrow = (w >> 1) * 64, wcol = (w & 1) * 64;
  int bid = blockIdx.x;
  int xcd = bid & 7, i5 = bid >> 3;         // i5 in [0,512)
  int BR = (xcd * 64 + (i5 >> 3)) * 128;
  int BC = (i5 & 7) * 128;
  f32x4 acc[4][4];
#pragma unroll
  for (int m = 0; m < 4; m++)
#pragma unroll
    for (int n = 0; n < 4; n++) acc[m][n] = (f32x4){0.f, 0.f, 0.f, 0.f};
  for (int kc = 0; kc < 4; kc++){
#pragma unroll
    for (int i = 0; i < 4; i++){
      int q = (w * 4 + i) * 64 + lane;
      int row = q >> 3, kpe = swz8(row, q & 7);
      size_t gr = (size_t)(BR + row);
      const uint16_t* src = (kc == 0) ? &pcb[gr * 64 + kpe] : &xn2b[gr * 256 + kc * 64 + kpe];
      g2l16(src, &lA[(w * 4 + i) * 512]);
      g2l16(&w1b[(size_t)(BC + row) * 256 + kc * 64 + kpe], &lB[(w * 4 + i) * 512]);
    }
    __syncthreads();
    mma_core<1, 1>(lA, 64, lB, 64, acc, wrow, wcol, lane);
    __syncthreads();
  }
  int rb4 = (lane >> 4) * 4, cb = lane & 15;
  float bias[4];
#pragma unroll
  for (int n = 0; n < 4; n++) bias[n] = b1[BC + wcol + n * 16 + cb];
  // block-uniform routing: [BC, BC+128) entirely on one side of HID=512
  uint16_t* dst = (BC < HID) ? (Y1b + BC + wcol + cb) : (Y2b + (BC - HID) + wcol + cb);
#pragma unroll
  for (int m = 0; m < 4; m++)
#pragma unroll
    for (int j = 0; j < 4; j++){
      uint16_t* rp = dst + (size_t)(BR + wrow + m * 16 + rb4 + j) * HID;
#pragma unroll
      for (int n = 0; n < 4; n++)
        rp[n * 16] = f2b(gelu_fast(acc[m][n][j] + bias[n]));
    }
}

// ------- dwconv 3x3 + gelu, fused *Y2 — LDS-tiled: block = 16px (row seg) × 128ch -------
// grid (256 = 64rows × 4segs, 4 ch-chunks, BB). Halo tile 3×18×128 staged once; zero borders.
__global__ __launch_bounds__(256) void k_dwconv(const uint16_t* __restrict__ Y1b,
                                                const float* __restrict__ dwwT,   // [tap][512]
                                                const float* __restrict__ dwb,
                                                const uint16_t* __restrict__ Y2b,
                                                uint16_t* __restrict__ YPb){
  __shared__ uint16_t lds[3 * 18 * 136];   // px-stride 136 elems (272B) -> bank-shift 4/px
  int b = blockIdx.z, chunk = blockIdx.y;
  int y = blockIdx.x >> 2, seg = blockIdx.x & 3;
  int x0 = seg * 16;
  int t = threadIdx.x;
  const uint16_t* base = Y1b + (size_t)b * NN * HID + chunk * 128;
  const u16x8 z = {0, 0, 0, 0, 0, 0, 0, 0};
#pragma unroll
  for (int i = 0; i < 4; i++){
    int idx = i * 256 + t;
    if (idx < 864){                         // 3 rows × 18 px × 16 ch-groups
      int g8 = idx & 15, rest = idx >> 4;
      int c = rest % 18, r = rest / 18;
      int ry = y + r - 1, xx = x0 + c - 1;
      u16x8 v = z;
      if (ry >= 0 && ry < HH && xx >= 0 && xx < WW)
        v = *(const u16x8*)&base[(size_t)(ry * WW + xx) * HID + g8 * 8];
      *(u16x8*)&lds[(r * 18 + c) * 136 + g8 * 8] = v;
    }
  }
  __syncthreads();
  int px = t >> 4, g8 = t & 15;
  int cg = chunk * 128 + g8 * 8;
  int n = y * WW + x0 + px;
  u16x8 y2 = *(const u16x8*)&Y2b[((size_t)b * NN + n) * HID + cg];
  float acc[8];
  {
    float4 b0 = *(const float4*)&dwb[cg];
    float4 b1 = *(const float4*)&dwb[cg + 4];
    acc[0] = b0.x; acc[1] = b0.y; acc[2] = b0.z; acc[3] = b0.w;
    acc[4] = b1.x; acc[5] = b1.y; acc[6] = b1.z; acc[7] = b1.w;
  }
#pragma unroll
  for (int r = 0; r < 3; r++)
#pragma unroll
    for (int dx = 0; dx < 3; dx++){
      u16x8 v = *(const u16x8*)&lds[(r * 18 + px + dx) * 136 + g8 * 8];
      const float* wt = &dwwT[(r * 3 + dx) * HID + cg];
      float4 w0 = *(const float4*)wt;
      float4 w1 = *(const float4*)(wt + 4);
      acc[0] += b2f(v[0]) * w0.x; acc[1] += b2f(v[1]) * w0.y;
      acc[2] += b2f(v[2]) * w0.z; acc[3] += b2f(v[3]) * w0.w;
      acc[4] += b2f(v[4]) * w1.x; acc[5] += b2f(v[5]) * w1.y;
      acc[6] += b2f(v[6]) * w1.z; acc[7] += b2f(v[7]) * w1.w;
    }
  u16x8 o;
#pragma unroll
  for (int j = 0; j < 8; j++) o[j] = f2b(gelu_fast(acc[j]) * b2f(y2[j]));
  *(u16x8*)&YPb[((size_t)b * NN + n) * HID + cg] = o;
}

// ---------------- lin2 MFMA: deltab = YP @ w2^T + b2 (1-D grid 1024, XCD-remapped) ----------------
__global__ __launch_bounds__(256) void k_lin2_mfma(const uint16_t* __restrict__ YPb,
                                                   const uint16_t* __restrict__ w2b,
                                                   const float* __restrict__ b2,
                                                   uint16_t* __restrict__ deltab){
  __shared__ uint16_t lA[128 * 64];
  __shared__ uint16_t lB[128 * 64];
  int t = threadIdx.x, lane = t & 63, w = t >> 6;
  int wrow = (w >> 1) * 64, wcol = (w & 1) * 64;
  int bid = blockIdx.x;
  int xcd = bid & 7, i5 = bid >> 3;         // i5 in [0,128)
  int BR = (xcd * 64 + (i5 >> 1)) * 128;
  int BC = (i5 & 1) * 128;
  f32x4 acc[4][4];
#pragma unroll
  for (int m = 0; m < 4; m++)
#pragma unroll
    for (int n = 0; n < 4; n++) acc[m][n] = (f32x4){0.f, 0.f, 0.f, 0.f};
  for (int kc = 0; kc < 8; kc++){
#pragma unroll
    for (int i = 0; i < 4; i++){
      int q = (w * 4 + i) * 64 + lane;
      int row = q >> 3, kpe = swz8(row, q & 7);
      g2l16(&YPb[(size_t)(BR + row) * HID + kc * 64 + kpe], &lA[(w * 4 + i) * 512]);
      g2l16(&w2b[(size_t)(BC + row) * HID + kc * 64 + kpe], &lB[(w * 4 + i) * 512]);
    }
    __syncthreads();
    mma_core<1, 1>(lA, 64, lB, 64, acc, wrow, wcol, lane);
    __syncthreads();
  }
  int rb4 = (lane >> 4) * 4, cb = lane & 15;
  float bias[4];
#pragma unroll
  for (int n = 0; n < 4; n++) bias[n] = b2[BC + wcol + n * 16 + cb];
  uint16_t* dst = deltab + BC + wcol + cb;
#pragma unroll
  for (int m = 0; m < 4; m++)
#pragma unroll
    for (int j = 0; j < 4; j++){
      uint16_t* rp = dst + (size_t)(BR + wrow + m * 16 + rb4 + j) * CC;
#pragma unroll
      for (int n = 0; n < 4; n++)
        rp[n * 16] = f2b(acc[m][n][j] + bias[n]);
    }
}

// ---------------- final: v = mixb+deltab; out0 = xhwcb + v (NCHW), out1 = -v ----------------
__global__ __launch_bounds__(256) void k_final2(const uint16_t* __restrict__ mixb,
                                                const uint16_t* __restrict__ deltab,
                                                const uint16_t* __restrict__ xhwcb,
                                                float* __restrict__ out){
  __shared__ float t0[64 * 68];
  __shared__ float t1[64 * 68];
  int b = blockIdx.z;
  int n0 = blockIdx.x * 64, c0 = blockIdx.y * 64;
  int t = threadIdx.x;
#pragma unroll
  for (int i = 0; i < 4; i++){
    int idx = i * 256 + t, row = idx >> 4, c4 = idx & 15;
    size_t gp = ((size_t)b * NN + n0 + row) * CC + c0 + c4 * 4;
    u16x4 m = *(const u16x4*)&mixb[gp];
    u16x4 d = *(const u16x4*)&deltab[gp];
    u16x4 xh = *(const u16x4*)&xhwcb[gp];
    f32x4 v0, v1;
#pragma unroll
    for (int j = 0; j < 4; j++){
      float v = b2f(m[j]) + b2f(d[j]);
      v0[j] = b2f(xh[j]) + v;
      v1[j] = -v;
    }
    *(f32x4*)&t0[row * 68 + c4 * 4] = v0;
    *(f32x4*)&t1[row * 68 + c4 * 4] = v1;
  }
  __syncthreads();
  int cl = t >> 2, seg = t & 3;
  float* o1 = out + (size_t)BB * CC * NN;
  size_t gbase = ((size_t)(b * CC + c0 + cl)) * NN + n0 + seg * 16;
#pragma unroll
  for (int k = 0; k < 4; k++){
    float4 a, c;
    a.x = t0[(seg * 16 + k * 4 + 0) * 68 + cl];
    a.y = t0[(seg * 16 + k * 4 + 1) * 68 + cl];
    a.z = t0[(seg * 16 + k * 4 + 2) * 68 + cl];
    a.w = t0[(seg * 16 + k * 4 + 3) * 68 + cl];
    c.x = t1[(seg * 16 + k * 4 + 0) * 68 + cl];
    c.y = t1[(seg * 16 + k * 4 + 1) * 68 + cl];
    c.z = t1[(seg * 16 + k * 4 + 2) * 68 + cl];
    c.w = t1[(seg * 16 + k * 4 + 3) * 68 + cl];
    *(float4*)&out[gbase + k * 4] = a;
    *(float4*)&o1[gbase + k * 4] = c;
  }
}

extern "C" void kernel_launch(void* const* d_in, const int* in_sizes, int n_in,
                              void* d_out, int out_size, void* d_ws, size_t ws_size,
                              hipStream_t stream){
  const float* x       = (const float*)d_in[0];
  const float* scale_p = (const float*)d_in[1];
  const float* n1w     = (const float*)d_in[2];
  const float* n1b     = (const float*)d_in[3];
  const float* wi      = (const float*)d_in[4];
  const float* bi      = (const float*)d_in[5];
  const float* wo      = (const float*)d_in[6];
  const float* bo      = (const float*)d_in[7];
  const float* n2w     = (const float*)d_in[8];
  const float* n2b     = (const float*)d_in[9];
  const float* pw      = (const float*)d_in[10];
  const float* w1      = (const float*)d_in[11];
  const float* b1      = (const float*)d_in[12];
  const float* dww     = (const float*)d_in[13];
  const float* dwb     = (const float*)d_in[14];
  const float* w2      = (const float*)d_in[15];
  const float* b2      = (const float*)d_in[16];

  // ---- workspace layout (float units) — total ≈ 451 MB, ws = 512 MiB ----
  float* base = (float*)d_ws;
  size_t off = 0;
  float* part = base + off; off += (size_t)BB * 8 * SS * CC;
  float* QKV  = base + off; off += (size_t)BB * SS * 3 * CC;
  float* RN   = base + off; off += (size_t)BB * NN;
  float* IZ1  = base + off; off += (size_t)BB * SS;
  float* dwwT = base + off; off += (size_t)9 * HID;
  uint16_t* slotsNb = (uint16_t*)(base + off); off += (size_t)BB * SS * CC / 2;
  uint16_t* slotsb  = (uint16_t*)(base + off); off += (size_t)BB * SS * CC / 2;
  uint16_t* aob     = (uint16_t*)(base + off); off += (size_t)BB * SS * CC / 2;
  uint16_t* sl2Tb   = (uint16_t*)(base + off); off += (size_t)BB * CC * SS / 2;
  uint16_t* xhwcb   = (uint16_t*)(base + off); off += (size_t)BB * NN * CC / 2;
  uint16_t* xnb     = (uint16_t*)(base + off); off += (size_t)BB * NN * CC / 2;
  uint16_t* xnTb    = (uint16_t*)(base + off); off += (size_t)BB * NN * CC / 2;   // xn transposed [b][c][n]
  uint16_t* mixb    = (uint16_t*)(base + off); off += (size_t)BB * NN * CC / 2;
  uint16_t* deltab  = (uint16_t*)(base + off); off += (size_t)BB * NN * CC / 2;
  uint16_t* E       = (uint16_t*)(base + off); off += (size_t)BB * SS * NN / 2;
  uint16_t* w1b     = (uint16_t*)(base + off); off += (size_t)(2 * HID) * CC / 2;
  uint16_t* w2b     = (uint16_t*)(base + off); off += (size_t)CC * HID / 2;
  uint16_t* wib     = (uint16_t*)(base + off); off += (size_t)(3 * CC) * CC / 2;
  uint16_t* wob     = (uint16_t*)(base + off); off += (size_t)CC * CC / 2;
  uint16_t* wp2     = (uint16_t*)(base + off); off += (size_t)64 * 576 / 2 + 16;
  uint16_t* Y1b     = (uint16_t*)(base + off); off += (size_t)BB * NN * HID / 2;
  uint16_t* Y2b     = (uint16_t*)(base + off); off += (size_t)BB * NN * HID / 2;
  uint16_t* YPb     = (uint16_t*)(base + off); off += (size_t)BB * NN * HID / 2;
  uint16_t* xn2b    = (uint16_t*)(base + off); off += (size_t)BB * NN * CC / 2;
  uint16_t* xn2p    = (uint16_t*)(base + off); off += (size_t)BB * 66 * 66 * 64 / 2;
  uint16_t* pcb     = (uint16_t*)(base + off); off += (size_t)BB * NN * 64 / 2;
  if (ws_size < off * sizeof(float)) return;
  float* OUT = (float*)d_out;

  dim3 tb2(32, 8);
  // ---- slot-mixing phase ----
  k_t2b<<<dim3(NN / 32, CC / 64, BB), tb2, 0, stream>>>(x, xhwcb);
  k_pool<<<BB * SS, 256, 0, stream>>>(xhwcb, slotsNb);
  k_ln_w<<<BB * NN / 4, 256, 0, stream>>>(xhwcb, (const uint16_t*)nullptr, n1w, n1b, xnb, RN,
                                          (uint16_t*)nullptr);
  k_cvtw<<<803, 256, 0, stream>>>(wi, wo, w1, w2, pw, dww, wib, wob, w1b, w2b, wp2, dwwT);
  k_zb<<<(16 * 260 * 16 + 255) / 256, 256, 0, stream>>>(xn2p);
  k_logits_mfma<<<dim3(NN / 256, BB), 256, 0, stream>>>(slotsNb, xnb, RN, scale_p, E);
  k_txT<<<dim3(NN / 64, CC / 64, BB), 256, 0, stream>>>(xnb, xnTb);
  k_z1<<<BB * SS, 256, 0, stream>>>(E, IZ1);
  k_slots_mfma<<<dim3(8, BB), 256, 0, stream>>>(E, xnTb, part);
  k_fold<<<(BB * SS * CC / 4) / 256, 256, 0, stream>>>(part, IZ1, slotsb);
  k_gemm_qkv<<<dim3(8, 6), 256, 0, stream>>>(slotsb, wib, bi, QKV);
  k_attn<<<BB * NHEAD, 256, 0, stream>>>(QKV, aob);
  k_gemm_oproj<<<dim3(8, 2), 256, 0, stream>>>(aob, wob, bo, sl2Tb);
  k_mix<<<dim3(NN / 128, CC / 128, BB), 256, 0, stream>>>(E, sl2Tb, mixb);
  // ---- FRFN phase ----
  k_ln_w<<<BB * NN / 4, 256, 0, stream>>>(xhwcb, mixb, n2w, n2b, xn2b, (float*)nullptr, xn2p);
  k_pconv_mfma<<<BB * NN / 256, 256, 0, stream>>>(xn2p, wp2, pcb);
  k_lin1_mfma<<<4096, 256, 0, stream>>>(pcb, xn2b, w1b, b1, Y1b, Y2b);
  k_dwconv<<<dim3(256, 4, BB), 256, 0, stream>>>(Y1b, dwwT, dwb, Y2b, YPb);
  k_lin2_mfma<<<1024, 256, 0, stream>>>(YPb, w2b, b2, deltab);
  // ---- fused residual/transpose output ----
  k_final2<<<dim3(NN / 64, CC / 64, BB), 256, 0, stream>>>(mixb, deltab, xhwcb, OUT);
}

// Round 20
// 409.093 us; speedup vs baseline: 1.5018x; 1.0013x over previous
//
#include <hip/hip_runtime.h>
#include <hip/hip_bf16.h>
#include <stdint.h>
#include <math.h>

#define BB 16
#define CC 256
#define HH 64
#define WW 64
#define NN 4096   // HH*WW
#define SS 64
#define NHEAD 8
#define DH 32
#define HID 512
#define DC 64

typedef float    f32x4  __attribute__((ext_vector_type(4)));
typedef float    f32x2  __attribute__((ext_vector_type(2)));
typedef uint32_t u32x4  __attribute__((ext_vector_type(4)));
typedef uint16_t u16x8  __attribute__((ext_vector_type(8)));
typedef uint16_t u16x4  __attribute__((ext_vector_type(4)));
typedef uint16_t u16x2  __attribute__((ext_vector_type(2)));

// tanh-gelu in sigmoid form: 0.5x(1+tanh(u)) == x*e^z/(e^z+1), z=2u  (identical math, fewer ops)
__device__ __forceinline__ float gelu_fast(float x){
  float z = x * (1.5957691216057308f + 0.07135481627613705f * x * x);
  float e = __expf(z);
  float r = __builtin_amdgcn_rcpf(e + 1.0f);
  return x * e * r;
}
__device__ __forceinline__ uint16_t f2b(float f){
  union { float f; uint32_t u; } v; v.f = f;
  uint32_t r = v.u + 0x7fffu + ((v.u >> 16) & 1u);
  return (uint16_t)(r >> 16);
}
__device__ __forceinline__ float b2f(uint16_t h){
  union { uint32_t u; float f; } v; v.u = ((uint32_t)h) << 16;
  return v.f;
}
// unpack 2 packed bf16 (one dword) -> float2 (2 VALU ops)
__device__ __forceinline__ f32x2 bpair(uint32_t u){
  union { uint32_t u; float f; } lo, hi;
  lo.u = u << 16; hi.u = u & 0xffff0000u;
  return (f32x2){lo.f, hi.f};
}

__device__ __forceinline__ float waveSum(float v){
#pragma unroll
  for (int m = 32; m >= 1; m >>= 1) v += __shfl_xor(v, m, 64);
  return v;
}
__device__ __forceinline__ float blockSum256(float v, float* s4){
  v = waveSum(v);
  __syncthreads();
  if ((threadIdx.x & 63) == 0) s4[threadIdx.x >> 6] = v;
  __syncthreads();
  return s4[0] + s4[1] + s4[2] + s4[3];
}

// ---- async global->LDS, 16B per lane (dest = wave-uniform base + lane*16) ----
__device__ __forceinline__ void g2l16(const void* g, void* l){
  __builtin_amdgcn_global_load_lds((const __attribute__((address_space(1))) uint32_t*)g,
                                   (__attribute__((address_space(3))) uint32_t*)l, 16, 0, 0);
}

// XOR swizzle for 64-elem (128B) rows: 16B-unit u' = u ^ (row&7).  [G4/T2/m173]
__device__ __forceinline__ int swz8(int row, int kp){ return (kp ^ (row & 7)) << 3; }

// ---- MFMA 16x16x32 bf16 via inline asm (D=C in-place) ----
// A/B frag: lane l holds row/col (l&15), k = (l>>4)*8 + e
// D: col = lane&15, row = (lane>>4)*4 + reg   [m89-verified]
__device__ __forceinline__ void mfma_bf16(f32x4& d, u16x8 a, u16x8 b){
  asm volatile("v_mfma_f32_16x16x32_bf16 %0, %1, %2, %0" : "+v"(d) : "v"(a), "v"(b));
}

// 4x4-fragment core over one BK=64 LDS tile; SWA/SWB: operand stored swizzled (lda/ldb==64 only)
template<int SWA, int SWB>
__device__ __forceinline__ void mma_core(const uint16_t* lA, int lda, const uint16_t* lB, int ldb,
                                         f32x4 (&acc)[4][4], int wrow, int wcol, int lane){
  const int rb = lane & 15, ub = lane >> 4;
#pragma unroll
  for (int ks = 0; ks < 2; ks++){
    const int u = ks * 4 + ub;
    u16x8 af[4], bf[4];
#pragma unroll
    for (int m = 0; m < 4; m++){
      int r = wrow + m * 16 + rb;
      int e = SWA ? ((u ^ (r & 7)) << 3) : (u << 3);
      af[m] = *(const u16x8*)&lA[r * lda + e];
    }
#pragma unroll
    for (int n = 0; n < 4; n++){
      int r = wcol + n * 16 + rb;
      int e = SWB ? ((u ^ (r & 7)) << 3) : (u << 3);
      bf[n] = *(const u16x8*)&lB[r * ldb + e];
    }
#pragma unroll
    for (int m = 0; m < 4; m++)
#pragma unroll
      for (int n = 0; n < 4; n++)
        mfma_bf16(acc[m][n], af[m], bf[n]);
  }
}

// ---------------- K0: x NCHW -> NHWC bf16 ----------------
__global__ __launch_bounds__(256) void k_t2b(const float* __restrict__ in, uint16_t* __restrict__ out){
  __shared__ float tile[64][33];   // [c][n]
  int b = blockIdx.z;
  int n0 = blockIdx.x * 32;
  int c0 = blockIdx.y * 64;
  int tx = threadIdx.x, ty = threadIdx.y;   // (32,8)
  const float* src = in + (size_t)b * CC * NN;
#pragma unroll
  for (int i = 0; i < 64; i += 8)
    tile[ty + i][tx] = src[(size_t)(c0 + ty + i) * NN + n0 + tx];
  __syncthreads();
  uint16_t* dst = out + (size_t)b * NN * CC;
#pragma unroll
  for (int i = 0; i < 32; i += 8){
    int r = ty + i;
    u16x2 o; o[0] = f2b(tile[tx * 2][r]); o[1] = f2b(tile[tx * 2 + 1][r]);
    *(u16x2*)&dst[(size_t)(n0 + r) * CC + c0 + tx * 2] = o;
  }
}

// ---------------- K1: 8x8 pooled slots + l2norm -> bf16 (vectorized) ----------------
__global__ __launch_bounds__(256) void k_pool(const uint16_t* __restrict__ xhwcb, uint16_t* __restrict__ slotsNb){
  int bs = blockIdx.x; int b = bs >> 6, s = bs & 63;
  int sy = (s >> 3) * 8, sx = (s & 7) * 8;
  int t = threadIdx.x;
  int c4 = t & 63, pg = t >> 6;      // channel-quad, pixel-group (16 px each)
  const uint16_t* base = xhwcb + (size_t)b * NN * CC;
  float a0 = 0.f, a1 = 0.f, a2 = 0.f, a3 = 0.f;
#pragma unroll
  for (int i = 0; i < 16; i++){
    int p = pg * 16 + i; int py = p >> 3, px = p & 7;
    u16x4 v = *(const u16x4*)&base[(size_t)((sy + py) * WW + sx + px) * CC + c4 * 4];
    a0 += b2f(v[0]); a1 += b2f(v[1]); a2 += b2f(v[2]); a3 += b2f(v[3]);
  }
  __shared__ float sm[4][64][4];
  sm[pg][c4][0] = a0; sm[pg][c4][1] = a1; sm[pg][c4][2] = a2; sm[pg][c4][3] = a3;
  __syncthreads();
  if (t < 64){
    float v0 = (sm[0][t][0] + sm[1][t][0] + sm[2][t][0] + sm[3][t][0]) * (1.0f / 64.0f);
    float v1 = (sm[0][t][1] + sm[1][t][1] + sm[2][t][1] + sm[3][t][1]) * (1.0f / 64.0f);
    float v2 = (sm[0][t][2] + sm[1][t][2] + sm[2][t][2] + sm[3][t][2]) * (1.0f / 64.0f);
    float v3 = (sm[0][t][3] + sm[1][t][3] + sm[2][t][3] + sm[3][t][3]) * (1.0f / 64.0f);
    float ss = waveSum(v0 * v0 + v1 * v1 + v2 * v2 + v3 * v3);
    float inv = 1.0f / fmaxf(sqrtf(ss), 1e-12f);
    u16x4 o; o[0] = f2b(v0 * inv); o[1] = f2b(v1 * inv); o[2] = f2b(v2 * inv); o[3] = f2b(v3 * inv);
    *(u16x4*)&slotsNb[(size_t)bs * CC + t * 4] = o;
  }
}

// ---- wave-per-row LayerNorm on bf16 (xa [+ xb]) -> bf16 (+ inv l2-norm | + padded-interior write) ----
__global__ __launch_bounds__(256) void k_ln_w(const uint16_t* __restrict__ xa, const uint16_t* __restrict__ xb,
                                              const float* __restrict__ w, const float* __restrict__ b,
                                              uint16_t* __restrict__ xoutb, float* __restrict__ rn,
                                              uint16_t* __restrict__ xn2p){
  int row = blockIdx.x * 4 + (threadIdx.x >> 6);
  int lane = threadIdx.x & 63;
  u16x4 va = *(const u16x4*)&xa[(size_t)row * CC + lane * 4];
  float v0 = b2f(va[0]), v1 = b2f(va[1]), v2 = b2f(va[2]), v3 = b2f(va[3]);
  if (xb){
    u16x4 vb = *(const u16x4*)&xb[(size_t)row * CC + lane * 4];
    v0 += b2f(vb[0]); v1 += b2f(vb[1]); v2 += b2f(vb[2]); v3 += b2f(vb[3]);
  }
  float mu = waveSum(v0 + v1 + v2 + v3) * (1.0f / CC);
  float d0 = v0 - mu, d1 = v1 - mu, d2 = v2 - mu, d3 = v3 - mu;
  float var = waveSum(d0 * d0 + d1 * d1 + d2 * d2 + d3 * d3) * (1.0f / CC);
  float inv = rsqrtf(var + 1e-5f);
  float4 wv = *(const float4*)&w[lane * 4];
  float4 bv = *(const float4*)&b[lane * 4];
  float x0 = d0 * inv * wv.x + bv.x;
  float x1 = d1 * inv * wv.y + bv.y;
  float x2 = d2 * inv * wv.z + bv.z;
  float x3 = d3 * inv * wv.w + bv.w;
  u16x4 o; o[0] = f2b(x0); o[1] = f2b(x1); o[2] = f2b(x2); o[3] = f2b(x3);
  *(u16x4*)&xoutb[(size_t)row * CC + lane * 4] = o;
  if (xn2p && lane < 16){
    int bb = row >> 12, n = row & 4095, y = n >> 6, x = n & 63;
    *(u16x4*)&xn2p[(((size_t)(bb * 66 + y + 1)) * 66 + x + 1) * 64 + lane * 4] = o;
  }
  if (rn){
    float ss = waveSum(x0 * x0 + x1 * x1 + x2 * x2 + x3 * x3);
    if (lane == 0) rn[row] = 1.0f / fmaxf(sqrtf(ss), 1e-12f);
  }
}

// ---------------- border zeros for padded image ----------------
__global__ __launch_bounds__(256) void k_zb(uint16_t* __restrict__ xn2p){
  int i = blockIdx.x * 256 + threadIdx.x;   // (b, j<260, c4<16)
  if (i >= 16 * 260 * 16) return;
  int c4 = i & 15; int rest = i >> 4;
  int j = rest % 260; int b = rest / 260;
  int py, px;
  if (j < 66){ py = 0; px = j; }
  else if (j < 132){ py = 65; px = j - 66; }
  else if (j < 196){ py = j - 132 + 1; px = 0; }
  else { py = j - 196 + 1; px = 65; }
  u16x4 z; z[0] = 0; z[1] = 0; z[2] = 0; z[3] = 0;
  *(u16x4*)&xn2p[(((size_t)(b * 66 + py)) * 66 + px) * 64 + c4 * 4] = z;
}

// ---------------- merged weight conversions (wi|wo|w1|w2|pconv|dwT) ----------------
__global__ __launch_bounds__(256) void k_cvtw(const float* __restrict__ wi, const float* __restrict__ wo,
                                              const float* __restrict__ w1, const float* __restrict__ w2,
                                              const float* __restrict__ pw, const float* __restrict__ dww,
                                              uint16_t* __restrict__ wib, uint16_t* __restrict__ wob,
                                              uint16_t* __restrict__ w1b, uint16_t* __restrict__ w2b,
                                              uint16_t* __restrict__ wp2, float* __restrict__ dwwT){
  int i = blockIdx.x * 256 + threadIdx.x;
  if (i < 163840){
    const float* src; uint16_t* dst; int off;
    if (i < 49152){ src = wi; dst = wib; off = i; }
    else if (i < 65536){ src = wo; dst = wob; off = i - 49152; }
    else if (i < 131072){ src = w1; dst = w1b; off = i - 65536; }
    else { src = w2; dst = w2b; off = i - 131072; }
    float4 v = ((const float4*)src)[off];
    u16x4 o;
    o[0] = f2b(v.x); o[1] = f2b(v.y); o[2] = f2b(v.z); o[3] = f2b(v.w);
    *(u16x4*)&dst[(size_t)off * 4] = o;
  } else if (i < 200704){
    int j = i - 163840;
    if (j < 64 * 576){
      int co = j / 576, r = j % 576, tap = r >> 6, ci = r & 63;
      wp2[j] = f2b(pw[(size_t)co * 576 + ci * 9 + tap]);
    }
  } else {
    int j = i - 200704;                         // dwwT[tap][ch] = dww[ch][tap]
    if (j < 9 * HID){
      int tap = j / HID, ch = j % HID;
      dwwT[j] = dww[(size_t)ch * 9 + tap];
    }
  }
}

// ---------------- xn transpose: xnT[b][c][n] = xn[b][n][c] (bf16, LDS-tiled) ----------------
__global__ __launch_bounds__(256) void k_txT(const uint16_t* __restrict__ xnb, uint16_t* __restrict__ xnTb){
  __shared__ uint16_t tile[64 * 66];   // stride 66 u16 -> conflict-light scalar access
  int b = blockIdx.z;
  int n0 = blockIdx.x * 64, c0 = blockIdx.y * 64;
  int t = threadIdx.x;
#pragma unroll
  for (int i = 0; i < 16; i++){
    int idx = i * 256 + t;             // 0..4095
    int nr = idx >> 6, c = idx & 63;   // coalesced read (consecutive c)
    tile[c * 66 + nr] = xnb[((size_t)b * NN + n0 + nr) * CC + c0 + c];
  }
  __syncthreads();
#pragma unroll
  for (int i = 0; i < 16; i++){
    int idx = i * 256 + t;
    int cr = idx >> 6, n = idx & 63;   // coalesced write (consecutive n)
    xnTb[((size_t)b * CC + c0 + cr) * NN + n0 + n] = tile[cr * 66 + n];
  }
}

// ---------------- logits GEMM + exp epilogue -> E bf16 [b][s][n] ----------------
__global__ __launch_bounds__(256) void k_logits_mfma(const uint16_t* __restrict__ slotsNb,
                                                     const uint16_t* __restrict__ xnb,
                                                     const float* __restrict__ rn,
                                                     const float* __restrict__ scale_p,
                                                     uint16_t* __restrict__ E){
  __shared__ uint16_t smem[20480];      // lA 64x64 | lB 256x64 ; reused as eT 64x264
  __shared__ float rnS[256];
  uint16_t* lA = smem;
  uint16_t* lB = smem + 64 * 64;
  int t = threadIdx.x, lane = t & 63, w = t >> 6;
  int b = blockIdx.y, n0 = blockIdx.x * 256;
  rnS[t] = rn[b * NN + n0 + t];
  f32x4 acc[4][4];
#pragma unroll
  for (int m = 0; m < 4; m++)
#pragma unroll
    for (int n = 0; n < 4; n++) acc[m][n] = (f32x4){0.f, 0.f, 0.f, 0.f};
  for (int kc = 0; kc < 4; kc++){
#pragma unroll
    for (int i = 0; i < 2; i++){
      int idx = i * 256 + t, row = idx >> 3, kp = idx & 7;
      *(u16x8*)&lA[row * 64 + swz8(row, kp)] = *(const u16x8*)&slotsNb[(size_t)(b * 64 + row) * 256 + kc * 64 + kp * 8];
    }
#pragma unroll
    for (int i = 0; i < 8; i++){
      int idx = i * 256 + t, row = idx >> 3, kp = idx & 7;
      *(u16x8*)&lB[row * 64 + swz8(row, kp)] = *(const u16x8*)&xnb[((size_t)b * NN + n0 + row) * 256 + kc * 64 + kp * 8];
    }
    __syncthreads();
    mma_core<1, 1>(lA, 64, lB, 64, acc, 0, w * 64, lane);
    __syncthreads();
  }
  float scale = scale_p[0];
  int rb4 = (lane >> 4) * 4, cb = lane & 15;
#pragma unroll
  for (int m = 0; m < 4; m++)
#pragma unroll
    for (int n = 0; n < 4; n++)
#pragma unroll
      for (int j = 0; j < 4; j++){
        int s = m * 16 + rb4 + j, nl = w * 64 + n * 16 + cb;
        smem[s * 264 + nl] = f2b(__expf(acc[m][n][j] * scale * rnS[nl]));
      }
  __syncthreads();
#pragma unroll
  for (int i = 0; i < 8; i++){
    int idx = i * 256 + t, row = idx >> 5, cseg = idx & 31;
    *(u16x8*)&E[((size_t)b * 64 + row) * NN + n0 + cseg * 8] = *(const u16x8*)&smem[row * 264 + cseg * 8];
  }
}

// ---------------- z1: invz1[b,s] = 1 / sum_n E (vectorized) ----------------
__global__ __launch_bounds__(256) void k_z1(const uint16_t* __restrict__ E, float* __restrict__ invz1){
  int bs = blockIdx.x, t = threadIdx.x;
  u16x8 v0 = *(const u16x8*)&E[(size_t)bs * NN + t * 16];
  u16x8 v1 = *(const u16x8*)&E[(size_t)bs * NN + t * 16 + 8];
  float s = 0.f;
#pragma unroll
  for (int i = 0; i < 8; i++) s += b2f(v0[i]) + b2f(v1[i]);
  __shared__ float s4[4];
  float z = blockSum256(s, s4);
  if (t == 0) invz1[bs] = 1.0f / z;
}

// ------- slots GEMM (8-way K-split, both operands k-major via xnT; no in-kernel transpose) -------
__global__ __launch_bounds__(256) void k_slots_mfma(const uint16_t* __restrict__ E,
                                                    const uint16_t* __restrict__ xnTb,
                                                    float* __restrict__ part){
  __shared__ uint16_t lA[64 * 64];     // E tile: 64 s x 64 k
  __shared__ uint16_t lB[256 * 64];    // xnT tile: 256 c x 64 k  (40KB total)
  int t = threadIdx.x, lane = t & 63, w = t >> 6;
  int ks = blockIdx.x, b = blockIdx.y;
  f32x4 acc[4][4];
#pragma unroll
  for (int m = 0; m < 4; m++)
#pragma unroll
    for (int n = 0; n < 4; n++) acc[m][n] = (f32x4){0.f, 0.f, 0.f, 0.f};
  for (int kc = 0; kc < 8; kc++){
    int n0 = ks * 512 + kc * 64;
#pragma unroll
    for (int i = 0; i < 2; i++){        // lA: 512 units, 2/thread
      int q = (w * 2 + i) * 64 + lane;
      int row = q >> 3, kpe = swz8(row, q & 7);
      g2l16(&E[((size_t)b * 64 + row) * NN + n0 + kpe], &lA[(w * 2 + i) * 512]);
    }
#pragma unroll
    for (int i = 0; i < 8; i++){        // lB: 2048 units, 8/thread
      int q = (w * 8 + i) * 64 + lane;
      int row = q >> 3, kpe = swz8(row, q & 7);
      g2l16(&xnTb[((size_t)b * CC + row) * NN + n0 + kpe], &lB[(w * 8 + i) * 512]);
    }
    __syncthreads();
    mma_core<1, 1>(lA, 64, lB, 64, acc, 0, w * 64, lane);
    __syncthreads();
  }
  int rb4 = (lane >> 4) * 4, cb = lane & 15;
#pragma unroll
  for (int m = 0; m < 4; m++)
#pragma unroll
    for (int n = 0; n < 4; n++)
#pragma unroll
      for (int j = 0; j < 4; j++){
        int s = m * 16 + rb4 + j, c = w * 64 + n * 16 + cb;
        part[(((size_t)b * 8 + ks) * 64 + s) * 256 + c] = acc[m][n][j];
      }
}

// ---------------- fold partials -> slots bf16 ----------------
__global__ __launch_bounds__(256) void k_fold(const float* __restrict__ part, const float* __restrict__ invz1,
                                              uint16_t* __restrict__ slotsb){
  int i = blockIdx.x * 256 + threadIdx.x;
  int row = i >> 6, c4 = i & 63;
  int b = row >> 6, s = row & 63;
  float4 a = {0.f, 0.f, 0.f, 0.f};
#pragma unroll
  for (int p = 0; p < 8; p++){
    float4 v = *(const float4*)&part[(((size_t)b * 8 + p) * 64 + s) * 256 + c4 * 4];
    a.x += v.x; a.y += v.y; a.z += v.z; a.w += v.w;
  }
  float iz = invz1[row];
  u16x4 o; o[0] = f2b(a.x * iz); o[1] = f2b(a.y * iz); o[2] = f2b(a.z * iz); o[3] = f2b(a.w * iz);
  *(u16x4*)&slotsb[(size_t)row * 256 + c4 * 4] = o;
}

// ---------------- qkv GEMM: [1024 x 768] = slotsb @ wib^T + bi (fp32 out) ----------------
__global__ __launch_bounds__(256) void k_gemm_qkv(const uint16_t* __restrict__ slotsb,
                                                  const uint16_t* __restrict__ wib,
                                                  const float* __restrict__ bi,
                                                  float* __restrict__ qkv){
  __shared__ uint16_t lA[128 * 64];
  __shared__ uint16_t lB[128 * 64];
  int t = threadIdx.x, lane = t & 63, w = t >> 6;
  int wrow = (w >> 1) * 64, wcol = (w & 1) * 64;
  int BR = blockIdx.x * 128, BC = blockIdx.y * 128;
  f32x4 acc[4][4];
#pragma unroll
  for (int m = 0; m < 4; m++)
#pragma unroll
    for (int n = 0; n < 4; n++) acc[m][n] = (f32x4){0.f, 0.f, 0.f, 0.f};
  for (int kc = 0; kc < 4; kc++){
#pragma unroll
    for (int i = 0; i < 4; i++){
      int idx = i * 256 + t, row = idx >> 3, kp = idx & 7;
      *(u16x8*)&lA[row * 64 + swz8(row, kp)] = *(const u16x8*)&slotsb[(size_t)(BR + row) * 256 + kc * 64 + kp * 8];
      *(u16x8*)&lB[row * 64 + swz8(row, kp)] = *(const u16x8*)&wib[(size_t)(BC + row) * 256 + kc * 64 + kp * 8];
    }
    __syncthreads();
    mma_core<1, 1>(lA, 64, lB, 64, acc, wrow, wcol, lane);
    __syncthreads();
  }
  int rb4 = (lane >> 4) * 4, cb = lane & 15;
#pragma unroll
  for (int m = 0; m < 4; m++)
#pragma unroll
    for (int n = 0; n < 4; n++){
      int c = BC + wcol + n * 16 + cb;
      float bias = bi[c];
#pragma unroll
      for (int j = 0; j < 4; j++)
        qkv[(size_t)(BR + wrow + m * 16 + rb4 + j) * 768 + c] = acc[m][n][j] + bias;
    }
}

// ---------------- per (b,h) attention over S=64 -> aob bf16 ----------------
__global__ __launch_bounds__(256) void k_attn(const float* __restrict__ qkv, uint16_t* __restrict__ aob){
  int b = blockIdx.x >> 3, h = blockIdx.x & 7;
  __shared__ float lq[64][33], lk[64][33], lv[64][33];
  __shared__ float sc[64][65];
  int t = threadIdx.x;
  for (int idx = t; idx < 64 * 32; idx += 256){
    int s = idx >> 5, d = idx & 31;
    const float* base = qkv + ((size_t)b * SS + s) * 768 + h * DH + d;
    lq[s][d] = base[0];
    lk[s][d] = base[256];
    lv[s][d] = base[512];
  }
  __syncthreads();
  const float rs = 0.17677669529663687f;
  for (int idx = t; idx < 64 * 64; idx += 256){
    int qq = idx >> 6, kk = idx & 63;
    float a = 0.f;
#pragma unroll
    for (int d = 0; d < 32; d++) a += lq[qq][d] * lk[kk][d];
    sc[qq][kk] = a * rs;
  }
  __syncthreads();
  {
    int r = t >> 2, sub = t & 3;
    float m = -1e30f;
#pragma unroll
    for (int k = sub * 16; k < sub * 16 + 16; k++) m = fmaxf(m, sc[r][k]);
    m = fmaxf(m, __shfl_xor(m, 1, 64));
    m = fmaxf(m, __shfl_xor(m, 2, 64));
    float z = 0.f;
#pragma unroll
    for (int k = sub * 16; k < sub * 16 + 16; k++){
      float e = __expf(sc[r][k] - m); sc[r][k] = e; z += e;
    }
    z += __shfl_xor(z, 1, 64);
    z += __shfl_xor(z, 2, 64);
    float iv = 1.0f / z;
#pragma unroll
    for (int k = sub * 16; k < sub * 16 + 16; k++) sc[r][k] *= iv;
  }
  __syncthreads();
  for (int idx = t; idx < 64 * 32; idx += 256){
    int qq = idx >> 5, d = idx & 31;
    float a = 0.f;
#pragma unroll
    for (int k = 0; k < 64; k++) a += sc[qq][k] * lv[k][d];
    aob[((size_t)b * SS + qq) * CC + h * DH + d] = f2b(a);
  }
}

// ---------------- oproj GEMM: sl2T[b][c][s] = (aob @ wob^T + bo)^T bf16 ----------------
__global__ __launch_bounds__(256) void k_gemm_oproj(const uint16_t* __restrict__ aob,
                                                    const uint16_t* __restrict__ wob,
                                                    const float* __restrict__ bo,
                                                    uint16_t* __restrict__ sl2Tb){
  __shared__ uint16_t lA[128 * 64];
  __shared__ uint16_t lB[128 * 64];
  int t = threadIdx.x, lane = t & 63, w = t >> 6;
  int wrow = (w >> 1) * 64, wcol = (w & 1) * 64;
  int BR = blockIdx.x * 128, BC = blockIdx.y * 128;
  f32x4 acc[4][4];
#pragma unroll
  for (int m = 0; m < 4; m++)
#pragma unroll
    for (int n = 0; n < 4; n++) acc[m][n] = (f32x4){0.f, 0.f, 0.f, 0.f};
  for (int kc = 0; kc < 4; kc++){
#pragma unroll
    for (int i = 0; i < 4; i++){
      int idx = i * 256 + t, row = idx >> 3, kp = idx & 7;
      *(u16x8*)&lA[row * 64 + swz8(row, kp)] = *(const u16x8*)&aob[(size_t)(BR + row) * 256 + kc * 64 + kp * 8];
      *(u16x8*)&lB[row * 64 + swz8(row, kp)] = *(const u16x8*)&wob[(size_t)(BC + row) * 256 + kc * 64 + kp * 8];
    }
    __syncthreads();
    mma_core<1, 1>(lA, 64, lB, 64, acc, wrow, wcol, lane);
    __syncthreads();
  }
  int rb4 = (lane >> 4) * 4, cb = lane & 15;
#pragma unroll
  for (int m = 0; m < 4; m++)
#pragma unroll
    for (int n = 0; n < 4; n++){
      int c = BC + wcol + n * 16 + cb;
      float bias = bo[c];
#pragma unroll
      for (int j = 0; j < 4; j++){
        int r = BR + wrow + m * 16 + rb4 + j;
        int b = r >> 6, s = r & 63;
        sl2Tb[((size_t)b * 256 + c) * 64 + s] = f2b(acc[m][n][j] + bias);
      }
    }
}

// ---------------- mix GEMM (pt fused): mixb[n][c] = (E^T[n][s]/z2[n]) @ sl2T[c][s] ----------------
__global__ __launch_bounds__(256) void k_mix(const uint16_t* __restrict__ E, const uint16_t* __restrict__ sl2Tb,
                                             uint16_t* __restrict__ mixb){
  __shared__ uint16_t lA[128 * 72];    // E^T tile [n_local][s] (padded stride, no swizzle)
  __shared__ uint16_t lB[128 * 64];    // sl2T rows [c][s] (swizzled)
  __shared__ float z2S[128];
  int t = threadIdx.x, lane = t & 63, w = t >> 6;
  int wrow = (w >> 1) * 64, wcol = (w & 1) * 64;
  int BR = blockIdx.x * 128, BC = blockIdx.y * 128, b = blockIdx.z;
#pragma unroll
  for (int i = 0; i < 4; i++){
    int idx = i * 256 + t; int s = idx >> 4, n8 = (idx & 15) * 8;
    u16x8 v = *(const u16x8*)&E[((size_t)b * 64 + s) * NN + BR + n8];
#pragma unroll
    for (int j = 0; j < 8; j++) lA[(n8 + j) * 72 + s] = v[j];
  }
#pragma unroll
  for (int i = 0; i < 4; i++){
    int idx = i * 256 + t, row = idx >> 3, kp = idx & 7;
    *(u16x8*)&lB[row * 64 + swz8(row, kp)] = *(const u16x8*)&sl2Tb[((size_t)b * 256 + BC + row) * 64 + kp * 8];
  }
  __syncthreads();
  if (t < 128){
    float s = 0.f;
#pragma unroll
    for (int k2 = 0; k2 < 64; k2++) s += b2f(lA[t * 72 + k2]);
    z2S[t] = 1.0f / s;
  }
  __syncthreads();
  f32x4 acc[4][4];
#pragma unroll
  for (int m = 0; m < 4; m++)
#pragma unroll
    for (int n = 0; n < 4; n++) acc[m][n] = (f32x4){0.f, 0.f, 0.f, 0.f};
  mma_core<0, 1>(lA, 72, lB, 64, acc, wrow, wcol, lane);
  int rb4 = (lane >> 4) * 4, cb = lane & 15;
#pragma unroll
  for (int m = 0; m < 4; m++)
#pragma unroll
    for (int n = 0; n < 4; n++)
#pragma unroll
      for (int j = 0; j < 4; j++){
        int lrow = wrow + m * 16 + rb4 + j;
        size_t gi = ((size_t)b * NN + BR + lrow) * 256 + BC + wcol + n * 16 + cb;
        mixb[gi] = f2b(acc[m][n][j] * z2S[lrow]);
      }
}

// ------- pconv as 9-tap MFMA GEMM, halo staged ONCE (6 padded rows in LDS; taps read in-place) -------
__global__ __launch_bounds__(256) void k_pconv_mfma(const uint16_t* __restrict__ xn2p,
                                                    const uint16_t* __restrict__ wp2,
                                                    uint16_t* __restrict__ pcb){
  __shared__ uint16_t lS[3328 * 8];    // 53.2KB: 6x66 rows x 64ch (3168 units used, tail pad)
  __shared__ uint16_t lB[64 * 64];
  int t = threadIdx.x, lane = t & 63, w = t >> 6;
  int wrow = w * 64;
  int BR = blockIdx.x * 256;
  int b = BR >> 12, y0 = (BR & 4095) >> 6;   // 4 image rows y0..y0+3 -> padded rows y0..y0+5
  // ---- stage halo once: linear copy of 6 padded rows, source pre-swizzled by row li
  size_t G0 = ((size_t)(b * 66 + y0) * 66) * 64;
#pragma unroll
  for (int i = 0; i < 13; i++){
    int q = i * 256 + t;               // 16B unit index (tail >3168 loads pad; memory-safe: pcb follows)
    int li = q >> 3, kp = q & 7;
    g2l16(&xn2p[G0 + (size_t)li * 64 + ((kp ^ (li & 7)) << 3)], &lS[q * 8]);
  }
  const int rb = lane & 15, ub = lane >> 4;
  int li0[4];
#pragma unroll
  for (int m = 0; m < 4; m++){
    int r = wrow + m * 16 + rb;        // output px 0..255
    li0[m] = ((r >> 6) + 1) * 66 + (r & 63) + 1;
  }
  f32x4 acc[4][4];
#pragma unroll
  for (int m = 0; m < 4; m++)
#pragma unroll
    for (int n = 0; n < 4; n++) acc[m][n] = (f32x4){0.f, 0.f, 0.f, 0.f};
#pragma unroll
  for (int tap = 0; tap < 9; tap++){
    const int doff = (tap / 3 - 1) * 66 + (tap % 3 - 1);
#pragma unroll
    for (int i = 0; i < 2; i++){
      int q = (w * 2 + i) * 64 + lane;
      int row = q >> 3, kpe = swz8(row, q & 7);
      g2l16(&wp2[(size_t)row * 576 + tap * 64 + kpe], &lB[(w * 2 + i) * 512]);
    }
    __syncthreads();                   // drains lS (first tap) + lB(tap)
#pragma unroll
    for (int ks = 0; ks < 2; ks++){
      const int u = ks * 4 + ub;
      u16x8 af[4], bf[4];
#pragma unroll
      for (int m = 0; m < 4; m++){
        int li = li0[m] + doff;
        af[m] = *(const u16x8*)&lS[li * 64 + ((u ^ (li & 7)) << 3)];
      }
#pragma unroll
      for (int n = 0; n < 4; n++){
        int r = n * 16 + rb;
        bf[n] = *(const u16x8*)&lB[r * 64 + ((u ^ (r & 7)) << 3)];
      }
#pragma unroll
      for (int m = 0; m < 4; m++)
#pragma unroll
        for (int n = 0; n < 4; n++)
          mfma_bf16(acc[m][n], af[m], bf[n]);
    }
    __syncthreads();                   // protect lB before next tap's restage
  }
  int rb4 = (lane >> 4) * 4, cb = lane & 15;
#pragma unroll
  for (int m = 0; m < 4; m++)
#pragma unroll
    for (int j = 0; j < 4; j++){
      uint16_t* rp = &pcb[(size_t)(BR + wrow + m * 16 + rb4 + j) * 64 + cb];
#pragma unroll
      for (int n = 0; n < 4; n++)
        rp[n * 16] = f2b(acc[m][n][j]);
    }
}

// ---------------- lin1 MFMA + gelu -> Y1b/Y2b (1-D grid 4096, XCD-remapped) ----------------
// Epilogue: bias hoist + block-uniform dst + (m,j)-outer loop -> const-offset stores
__global__ __launch_bounds__(256) void k_lin1_mfma(const uint16_t* __restrict__ pcb,
                                                   const uint16_t* __restrict__ xn2b,
                                                   const uint16_t* __restrict__ w1b,
                                                   const float* __restrict__ b1,
                                                   uint16_t* __restrict__ Y1b, uint16_t* __restrict__ Y2b){
  __shared__ uint16_t lA[128 * 64];
  __shared__ uint16_t lB[128 * 64];
  int t = threadIdx.x, lane = t & 63, w = t >> 6;
  int wrow = (w >> 1) * 64, wcol = (w & 1) * 64;
  int bid = blockIdx.x;
  int xcd = bid & 7, i5 = bid >> 3;         // i5 in [0,512)
  int BR = (xcd * 64 + (i5 >> 3)) * 128;
  int BC = (i5 & 7) * 128;
  f32x4 acc[4][4];
#pragma unroll
  for (int m = 0; m < 4; m++)
#pragma unroll
    for (int n = 0; n < 4; n++) acc[m][n] = (f32x4){0.f, 0.f, 0.f, 0.f};
  for (int kc = 0; kc < 4; kc++){
#pragma unroll
    for (int i = 0; i < 4; i++){
      int q = (w * 4 + i) * 64 + lane;
      int row = q >> 3, kpe = swz8(row, q & 7);
      size_t gr = (size_t)(BR + row);
      const uint16_t* src = (kc == 0) ? &pcb[gr * 64 + kpe] : &xn2b[gr * 256 + kc * 64 + kpe];
      g2l16(src, &lA[(w * 4 + i) * 512]);
      g2l16(&w1b[(size_t)(BC + row) * 256 + kc * 64 + kpe], &lB[(w * 4 + i) * 512]);
    }
    __syncthreads();
    mma_core<1, 1>(lA, 64, lB, 64, acc, wrow, wcol, lane);
    __syncthreads();
  }
  int rb4 = (lane >> 4) * 4, cb = lane & 15;
  float bias[4];
#pragma unroll
  for (int n = 0; n < 4; n++) bias[n] = b1[BC + wcol + n * 16 + cb];
  // block-uniform routing: [BC, BC+128) entirely on one side of HID=512
  uint16_t* dst = (BC < HID) ? (Y1b + BC + wcol + cb) : (Y2b + (BC - HID) + wcol + cb);
#pragma unroll
  for (int m = 0; m < 4; m++)
#pragma unroll
    for (int j = 0; j < 4; j++){
      uint16_t* rp = dst + (size_t)(BR + wrow + m * 16 + rb4 + j) * HID;
#pragma unroll
      for (int n = 0; n < 4; n++)
        rp[n * 16] = f2b(gelu_fast(acc[m][n][j] + bias[n]));
    }
}

// ------- dwconv 3x3 + gelu, fused *Y2 — LDS-tiled, packed-f32 (v_pk_fma) inner loop -------
// grid (256 = 64rows × 4segs, 4 ch-chunks, BB). Halo tile 3×18×128 staged once; zero borders.
__global__ __launch_bounds__(256) void k_dwconv(const uint16_t* __restrict__ Y1b,
                                                const float* __restrict__ dwwT,   // [tap][512]
                                                const float* __restrict__ dwb,
                                                const uint16_t* __restrict__ Y2b,
                                                uint16_t* __restrict__ YPb){
  __shared__ uint16_t lds[3 * 18 * 136];   // px-stride 136 elems (272B)
  int b = blockIdx.z, chunk = blockIdx.y;
  int y = blockIdx.x >> 2, seg = blockIdx.x & 3;
  int x0 = seg * 16;
  int t = threadIdx.x;
  const uint16_t* base = Y1b + (size_t)b * NN * HID + chunk * 128;
  const u16x8 z = {0, 0, 0, 0, 0, 0, 0, 0};
#pragma unroll
  for (int i = 0; i < 4; i++){
    int idx = i * 256 + t;
    if (idx < 864){                         // 3 rows × 18 px × 16 ch-groups
      int g8 = idx & 15, rest = idx >> 4;
      int c = rest % 18, r = rest / 18;
      int ry = y + r - 1, xx = x0 + c - 1;
      u16x8 v = z;
      if (ry >= 0 && ry < HH && xx >= 0 && xx < WW)
        v = *(const u16x8*)&base[(size_t)(ry * WW + xx) * HID + g8 * 8];
      *(u16x8*)&lds[(r * 18 + c) * 136 + g8 * 8] = v;
    }
  }
  __syncthreads();
  int px = t >> 4, g8 = t & 15;
  int cg = chunk * 128 + g8 * 8;
  int n = y * WW + x0 + px;
  u32x4 y2v = *(const u32x4*)&Y2b[((size_t)b * NN + n) * HID + cg];
  f32x2 acc2[4];
  {
    float4 b0 = *(const float4*)&dwb[cg];
    float4 b1 = *(const float4*)&dwb[cg + 4];
    acc2[0] = (f32x2){b0.x, b0.y}; acc2[1] = (f32x2){b0.z, b0.w};
    acc2[2] = (f32x2){b1.x, b1.y}; acc2[3] = (f32x2){b1.z, b1.w};
  }
#pragma unroll
  for (int r = 0; r < 3; r++)
#pragma unroll
    for (int dx = 0; dx < 3; dx++){
      u32x4 v = *(const u32x4*)&lds[(r * 18 + px + dx) * 136 + g8 * 8];
      const f32x2* wt = (const f32x2*)&dwwT[(r * 3 + dx) * HID + cg];
      acc2[0] += bpair(v[0]) * wt[0];
      acc2[1] += bpair(v[1]) * wt[1];
      acc2[2] += bpair(v[2]) * wt[2];
      acc2[3] += bpair(v[3]) * wt[3];
    }
  u16x8 o;
#pragma unroll
  for (int j = 0; j < 4; j++){
    f32x2 yy = bpair(y2v[j]);
    float g0 = gelu_fast(acc2[j].x) * yy.x;
    float g1 = gelu_fast(acc2[j].y) * yy.y;
    o[2 * j] = f2b(g0); o[2 * j + 1] = f2b(g1);
  }
  *(u16x8*)&YPb[((size_t)b * NN + n) * HID + cg] = o;
}

// ---------------- lin2 MFMA: deltab = YP @ w2^T + b2 (1-D grid 1024, XCD-remapped) ----------------
__global__ __launch_bounds__(256) void k_lin2_mfma(const uint16_t* __restrict__ YPb,
                                                   const uint16_t* __restrict__ w2b,
                                                   const float* __restrict__ b2,
                                                   uint16_t* __restrict__ deltab){
  __shared__ uint16_t lA[128 * 64];
  __shared__ uint16_t lB[128 * 64];
  int t = threadIdx.x, lane = t & 63, w = t >> 6;
  int wrow = (w >> 1) * 64, wcol = (w & 1) * 64;
  int bid = blockIdx.x;
  int xcd = bid & 7, i5 = bid >> 3;         // i5 in [0,128)
  int BR = (xcd * 64 + (i5 >> 1)) * 128;
  int BC = (i5 & 1) * 128;
  f32x4 acc[4][4];
#pragma unroll
  for (int m = 0; m < 4; m++)
#pragma unroll
    for (int n = 0; n < 4; n++) acc[m][n] = (f32x4){0.f, 0.f, 0.f, 0.f};
  for (int kc = 0; kc < 8; kc++){
#pragma unroll
    for (int i = 0; i < 4; i++){
      int q = (w * 4 + i) * 64 + lane;
      int row = q >> 3, kpe = swz8(row, q & 7);
      g2l16(&YPb[(size_t)(BR + row) * HID + kc * 64 + kpe], &lA[(w * 4 + i) * 512]);
      g2l16(&w2b[(size_t)(BC + row) * HID + kc * 64 + kpe], &lB[(w * 4 + i) * 512]);
    }
    __syncthreads();
    mma_core<1, 1>(lA, 64, lB, 64, acc, wrow, wcol, lane);
    __syncthreads();
  }
  int rb4 = (lane >> 4) * 4, cb = lane & 15;
  float bias[4];
#pragma unroll
  for (int n = 0; n < 4; n++) bias[n] = b2[BC + wcol + n * 16 + cb];
  uint16_t* dst = deltab + BC + wcol + cb;
#pragma unroll
  for (int m = 0; m < 4; m++)
#pragma unroll
    for (int j = 0; j < 4; j++){
      uint16_t* rp = dst + (size_t)(BR + wrow + m * 16 + rb4 + j) * CC;
#pragma unroll
      for (int n = 0; n < 4; n++)
        rp[n * 16] = f2b(acc[m][n][j] + bias[n]);
    }
}

// ---------------- final: v = mixb+deltab; out0 = xhwcb + v (NCHW), out1 = -v ----------------
__global__ __launch_bounds__(256) void k_final2(const uint16_t* __restrict__ mixb,
                                                const uint16_t* __restrict__ deltab,
                                                const uint16_t* __restrict__ xhwcb,
                                                float* __restrict__ out){
  __shared__ float t0[64 * 68];
  __shared__ float t1[64 * 68];
  int b = blockIdx.z;
  int n0 = blockIdx.x * 64, c0 = blockIdx.y * 64;
  int t = threadIdx.x;
#pragma unroll
  for (int i = 0; i < 4; i++){
    int idx = i * 256 + t, row = idx >> 4, c4 = idx & 15;
    size_t gp = ((size_t)b * NN + n0 + row) * CC + c0 + c4 * 4;
    u16x4 m = *(const u16x4*)&mixb[gp];
    u16x4 d = *(const u16x4*)&deltab[gp];
    u16x4 xh = *(const u16x4*)&xhwcb[gp];
    f32x4 v0, v1;
#pragma unroll
    for (int j = 0; j < 4; j++){
      float v = b2f(m[j]) + b2f(d[j]);
      v0[j] = b2f(xh[j]) + v;
      v1[j] = -v;
    }
    *(f32x4*)&t0[row * 68 + c4 * 4] = v0;
    *(f32x4*)&t1[row * 68 + c4 * 4] = v1;
  }
  __syncthreads();
  int cl = t >> 2, seg = t & 3;
  float* o1 = out + (size_t)BB * CC * NN;
  size_t gbase = ((size_t)(b * CC + c0 + cl)) * NN + n0 + seg * 16;
#pragma unroll
  for (int k = 0; k < 4; k++){
    float4 a, c;
    a.x = t0[(seg * 16 + k * 4 + 0) * 68 + cl];
    a.y = t0[(seg * 16 + k * 4 + 1) * 68 + cl];
    a.z = t0[(seg * 16 + k * 4 + 2) * 68 + cl];
    a.w = t0[(seg * 16 + k * 4 + 3) * 68 + cl];
    c.x = t1[(seg * 16 + k * 4 + 0) * 68 + cl];
    c.y = t1[(seg * 16 + k * 4 + 1) * 68 + cl];
    c.z = t1[(seg * 16 + k * 4 + 2) * 68 + cl];
    c.w = t1[(seg * 16 + k * 4 + 3) * 68 + cl];
    *(float4*)&out[gbase + k * 4] = a;
    *(float4*)&o1[gbase + k * 4] = c;
  }
}

extern "C" void kernel_launch(void* const* d_in, const int* in_sizes, int n_in,
                              void* d_out, int out_size, void* d_ws, size_t ws_size,
                              hipStream_t stream){
  const float* x       = (const float*)d_in[0];
  const float* scale_p = (const float*)d_in[1];
  const float* n1w     = (const float*)d_in[2];
  const float* n1b     = (const float*)d_in[3];
  const float* wi      = (const float*)d_in[4];
  const float* bi      = (const float*)d_in[5];
  const float* wo      = (const float*)d_in[6];
  const float* bo      = (const float*)d_in[7];
  const float* n2w     = (const float*)d_in[8];
  const float* n2b     = (const float*)d_in[9];
  const float* pw      = (const float*)d_in[10];
  const float* w1      = (const float*)d_in[11];
  const float* b1      = (const float*)d_in[12];
  const float* dww     = (const float*)d_in[13];
  const float* dwb     = (const float*)d_in[14];
  const float* w2      = (const float*)d_in[15];
  const float* b2      = (const float*)d_in[16];

  // ---- workspace layout (float units) — total ≈ 451 MB, ws = 512 MiB ----
  float* base = (float*)d_ws;
  size_t off = 0;
  float* part = base + off; off += (size_t)BB * 8 * SS * CC;
  float* QKV  = base + off; off += (size_t)BB * SS * 3 * CC;
  float* RN   = base + off; off += (size_t)BB * NN;
  float* IZ1  = base + off; off += (size_t)BB * SS;
  float* dwwT = base + off; off += (size_t)9 * HID;
  uint16_t* slotsNb = (uint16_t*)(base + off); off += (size_t)BB * SS * CC / 2;
  uint16_t* slotsb  = (uint16_t*)(base + off); off += (size_t)BB * SS * CC / 2;
  uint16_t* aob     = (uint16_t*)(base + off); off += (size_t)BB * SS * CC / 2;
  uint16_t* sl2Tb   = (uint16_t*)(base + off); off += (size_t)BB * CC * SS / 2;
  uint16_t* xhwcb   = (uint16_t*)(base + off); off += (size_t)BB * NN * CC / 2;
  uint16_t* xnb     = (uint16_t*)(base + off); off += (size_t)BB * NN * CC / 2;
  uint16_t* xnTb    = (uint16_t*)(base + off); off += (size_t)BB * NN * CC / 2;   // xn transposed [b][c][n]
  uint16_t* mixb    = (uint16_t*)(base + off); off += (size_t)BB * NN * CC / 2;
  uint16_t* deltab  = (uint16_t*)(base + off); off += (size_t)BB * NN * CC / 2;
  uint16_t* E       = (uint16_t*)(base + off); off += (size_t)BB * SS * NN / 2;
  uint16_t* w1b     = (uint16_t*)(base + off); off += (size_t)(2 * HID) * CC / 2;
  uint16_t* w2b     = (uint16_t*)(base + off); off += (size_t)CC * HID / 2;
  uint16_t* wib     = (uint16_t*)(base + off); off += (size_t)(3 * CC) * CC / 2;
  uint16_t* wob     = (uint16_t*)(base + off); off += (size_t)CC * CC / 2;
  uint16_t* wp2     = (uint16_t*)(base + off); off += (size_t)64 * 576 / 2 + 16;
  uint16_t* Y1b     = (uint16_t*)(base + off); off += (size_t)BB * NN * HID / 2;
  uint16_t* Y2b     = (uint16_t*)(base + off); off += (size_t)BB * NN * HID / 2;
  uint16_t* YPb     = (uint16_t*)(base + off); off += (size_t)BB * NN * HID / 2;
  uint16_t* xn2b    = (uint16_t*)(base + off); off += (size_t)BB * NN * CC / 2;
  uint16_t* xn2p    = (uint16_t*)(base + off); off += (size_t)BB * 66 * 66 * 64 / 2;
  uint16_t* pcb     = (uint16_t*)(base + off); off += (size_t)BB * NN * 64 / 2;   // follows xn2p (pconv tail-read safety)
  if (ws_size < off * sizeof(float)) return;
  float* OUT = (float*)d_out;

  dim3 tb2(32, 8);
  // ---- slot-mixing phase ----
  k_t2b<<<dim3(NN / 32, CC / 64, BB), tb2, 0, stream>>>(x, xhwcb);
  k_pool<<<BB * SS, 256, 0, stream>>>(xhwcb, slotsNb);
  k_ln_w<<<BB * NN / 4, 256, 0, stream>>>(xhwcb, (const uint16_t*)nullptr, n1w, n1b, xnb, RN,
                                          (uint16_t*)nullptr);
  k_cvtw<<<803, 256, 0, stream>>>(wi, wo, w1, w2, pw, dww, wib, wob, w1b, w2b, wp2, dwwT);
  k_zb<<<(16 * 260 * 16 + 255) / 256, 256, 0, stream>>>(xn2p);
  k_logits_mfma<<<dim3(NN / 256, BB), 256, 0, stream>>>(slotsNb, xnb, RN, scale_p, E);
  k_txT<<<dim3(NN / 64, CC / 64, BB), 256, 0, stream>>>(xnb, xnTb);
  k_z1<<<BB * SS, 256, 0, stream>>>(E, IZ1);
  k_slots_mfma<<<dim3(8, BB), 256, 0, stream>>>(E, xnTb, part);
  k_fold<<<(BB * SS * CC / 4) / 256, 256, 0, stream>>>(part, IZ1, slotsb);
  k_gemm_qkv<<<dim3(8, 6), 256, 0, stream>>>(slotsb, wib, bi, QKV);
  k_attn<<<BB * NHEAD, 256, 0, stream>>>(QKV, aob);
  k_gemm_oproj<<<dim3(8, 2), 256, 0, stream>>>(aob, wob, bo, sl2Tb);
  k_mix<<<dim3(NN / 128, CC / 128, BB), 256, 0, stream>>>(E, sl2Tb, mixb);
  // ---- FRFN phase ----
  k_ln_w<<<BB * NN / 4, 256, 0, stream>>>(xhwcb, mixb, n2w, n2b, xn2b, (float*)nullptr, xn2p);
  k_pconv_mfma<<<BB * NN / 256, 256, 0, stream>>>(xn2p, wp2, pcb);
  k_lin1_mfma<<<4096, 256, 0, stream>>>(pcb, xn2b, w1b, b1, Y1b, Y2b);
  k_dwconv<<<dim3(256, 4, BB), 256, 0, stream>>>(Y1b, dwwT, dwb, Y2b, YPb);
  k_lin2_mfma<<<1024, 256, 0, stream>>>(YPb, w2b, b2, deltab);
  // ---- fused residual/transpose output ----
  k_final2<<<dim3(NN / 64, CC / 64, BB), 256, 0, stream>>>(mixb, deltab, xhwcb, OUT);
}

// Round 21
// 407.516 us; speedup vs baseline: 1.5076x; 1.0039x over previous
//
#include <hip/hip_runtime.h>
#include <hip/hip_bf16.h>
#include <stdint.h>
#include <math.h>

#define BB 16
#define CC 256
#define HH 64
#define WW 64
#define NN 4096   // HH*WW
#define SS 64
#define NHEAD 8
#define DH 32
#define HID 512
#define DC 64

typedef float    f32x4  __attribute__((ext_vector_type(4)));
typedef float    f32x2  __attribute__((ext_vector_type(2)));
typedef uint32_t u32x4  __attribute__((ext_vector_type(4)));
typedef uint16_t u16x8  __attribute__((ext_vector_type(8)));
typedef uint16_t u16x4  __attribute__((ext_vector_type(4)));
typedef uint16_t u16x2  __attribute__((ext_vector_type(2)));

// tanh-gelu in sigmoid form: 0.5x(1+tanh(u)) == x*e^z/(e^z+1), z=2u  (identical math, fewer ops)
__device__ __forceinline__ float gelu_fast(float x){
  float z = x * (1.5957691216057308f + 0.07135481627613705f * x * x);
  float e = __expf(z);
  float r = __builtin_amdgcn_rcpf(e + 1.0f);
  return x * e * r;
}
__device__ __forceinline__ uint16_t f2b(float f){
  union { float f; uint32_t u; } v; v.f = f;
  uint32_t r = v.u + 0x7fffu + ((v.u >> 16) & 1u);
  return (uint16_t)(r >> 16);
}
__device__ __forceinline__ float b2f(uint16_t h){
  union { uint32_t u; float f; } v; v.u = ((uint32_t)h) << 16;
  return v.f;
}
// unpack 2 packed bf16 (one dword) -> float2 (2 VALU ops)
__device__ __forceinline__ f32x2 bpair(uint32_t u){
  union { uint32_t u; float f; } lo, hi;
  lo.u = u << 16; hi.u = u & 0xffff0000u;
  return (f32x2){lo.f, hi.f};
}
// dual-FP32 packed FMA: d = a*b + d  (VOP3P, gfx90a+)
__device__ __forceinline__ void pkfma(f32x2& d, f32x2 a, f32x2 b){
  asm("v_pk_fma_f32 %0, %1, %2, %0" : "+v"(d) : "v"(a), "v"(b));
}

__device__ __forceinline__ float waveSum(float v){
#pragma unroll
  for (int m = 32; m >= 1; m >>= 1) v += __shfl_xor(v, m, 64);
  return v;
}
__device__ __forceinline__ float blockSum256(float v, float* s4){
  v = waveSum(v);
  __syncthreads();
  if ((threadIdx.x & 63) == 0) s4[threadIdx.x >> 6] = v;
  __syncthreads();
  return s4[0] + s4[1] + s4[2] + s4[3];
}

// ---- async global->LDS, 16B per lane (dest = wave-uniform base + lane*16) ----
__device__ __forceinline__ void g2l16(const void* g, void* l){
  __builtin_amdgcn_global_load_lds((const __attribute__((address_space(1))) uint32_t*)g,
                                   (__attribute__((address_space(3))) uint32_t*)l, 16, 0, 0);
}

// XOR swizzle for 64-elem (128B) rows: 16B-unit u' = u ^ (row&7).  [G4/T2/m173]
__device__ __forceinline__ int swz8(int row, int kp){ return (kp ^ (row & 7)) << 3; }

// ---- MFMA 16x16x32 bf16 via inline asm (D=C in-place) ----
// A/B frag: lane l holds row/col (l&15), k = (l>>4)*8 + e
// D: col = lane&15, row = (lane>>4)*4 + reg   [m89-verified]
__device__ __forceinline__ void mfma_bf16(f32x4& d, u16x8 a, u16x8 b){
  asm volatile("v_mfma_f32_16x16x32_bf16 %0, %1, %2, %0" : "+v"(d) : "v"(a), "v"(b));
}

// 4x4-fragment core over one BK=64 LDS tile; SWA/SWB: operand stored swizzled (lda/ldb==64 only)
template<int SWA, int SWB>
__device__ __forceinline__ void mma_core(const uint16_t* lA, int lda, const uint16_t* lB, int ldb,
                                         f32x4 (&acc)[4][4], int wrow, int wcol, int lane){
  const int rb = lane & 15, ub = lane >> 4;
#pragma unroll
  for (int ks = 0; ks < 2; ks++){
    const int u = ks * 4 + ub;
    u16x8 af[4], bf[4];
#pragma unroll
    for (int m = 0; m < 4; m++){
      int r = wrow + m * 16 + rb;
      int e = SWA ? ((u ^ (r & 7)) << 3) : (u << 3);
      af[m] = *(const u16x8*)&lA[r * lda + e];
    }
#pragma unroll
    for (int n = 0; n < 4; n++){
      int r = wcol + n * 16 + rb;
      int e = SWB ? ((u ^ (r & 7)) << 3) : (u << 3);
      bf[n] = *(const u16x8*)&lB[r * ldb + e];
    }
#pragma unroll
    for (int m = 0; m < 4; m++)
#pragma unroll
      for (int n = 0; n < 4; n++)
        mfma_bf16(acc[m][n], af[m], bf[n]);
  }
}

// ---------------- K0: x NCHW -> NHWC bf16 ----------------
__global__ __launch_bounds__(256) void k_t2b(const float* __restrict__ in, uint16_t* __restrict__ out){
  __shared__ float tile[64][33];   // [c][n]
  int b = blockIdx.z;
  int n0 = blockIdx.x * 32;
  int c0 = blockIdx.y * 64;
  int tx = threadIdx.x, ty = threadIdx.y;   // (32,8)
  const float* src = in + (size_t)b * CC * NN;
#pragma unroll
  for (int i = 0; i < 64; i += 8)
    tile[ty + i][tx] = src[(size_t)(c0 + ty + i) * NN + n0 + tx];
  __syncthreads();
  uint16_t* dst = out + (size_t)b * NN * CC;
#pragma unroll
  for (int i = 0; i < 32; i += 8){
    int r = ty + i;
    u16x2 o; o[0] = f2b(tile[tx * 2][r]); o[1] = f2b(tile[tx * 2 + 1][r]);
    *(u16x2*)&dst[(size_t)(n0 + r) * CC + c0 + tx * 2] = o;
  }
}

// ---------------- K1: 8x8 pooled slots + l2norm -> bf16 (vectorized) ----------------
__global__ __launch_bounds__(256) void k_pool(const uint16_t* __restrict__ xhwcb, uint16_t* __restrict__ slotsNb){
  int bs = blockIdx.x; int b = bs >> 6, s = bs & 63;
  int sy = (s >> 3) * 8, sx = (s & 7) * 8;
  int t = threadIdx.x;
  int c4 = t & 63, pg = t >> 6;      // channel-quad, pixel-group (16 px each)
  const uint16_t* base = xhwcb + (size_t)b * NN * CC;
  float a0 = 0.f, a1 = 0.f, a2 = 0.f, a3 = 0.f;
#pragma unroll
  for (int i = 0; i < 16; i++){
    int p = pg * 16 + i; int py = p >> 3, px = p & 7;
    u16x4 v = *(const u16x4*)&base[(size_t)((sy + py) * WW + sx + px) * CC + c4 * 4];
    a0 += b2f(v[0]); a1 += b2f(v[1]); a2 += b2f(v[2]); a3 += b2f(v[3]);
  }
  __shared__ float sm[4][64][4];
  sm[pg][c4][0] = a0; sm[pg][c4][1] = a1; sm[pg][c4][2] = a2; sm[pg][c4][3] = a3;
  __syncthreads();
  if (t < 64){
    float v0 = (sm[0][t][0] + sm[1][t][0] + sm[2][t][0] + sm[3][t][0]) * (1.0f / 64.0f);
    float v1 = (sm[0][t][1] + sm[1][t][1] + sm[2][t][1] + sm[3][t][1]) * (1.0f / 64.0f);
    float v2 = (sm[0][t][2] + sm[1][t][2] + sm[2][t][2] + sm[3][t][2]) * (1.0f / 64.0f);
    float v3 = (sm[0][t][3] + sm[1][t][3] + sm[2][t][3] + sm[3][t][3]) * (1.0f / 64.0f);
    float ss = waveSum(v0 * v0 + v1 * v1 + v2 * v2 + v3 * v3);
    float inv = 1.0f / fmaxf(sqrtf(ss), 1e-12f);
    u16x4 o; o[0] = f2b(v0 * inv); o[1] = f2b(v1 * inv); o[2] = f2b(v2 * inv); o[3] = f2b(v3 * inv);
    *(u16x4*)&slotsNb[(size_t)bs * CC + t * 4] = o;
  }
}

// ---- wave-per-row LayerNorm on bf16 (xa [+ xb]) -> bf16 (+ inv l2-norm | + padded-interior write) ----
__global__ __launch_bounds__(256) void k_ln_w(const uint16_t* __restrict__ xa, const uint16_t* __restrict__ xb,
                                              const float* __restrict__ w, const float* __restrict__ b,
                                              uint16_t* __restrict__ xoutb, float* __restrict__ rn,
                                              uint16_t* __restrict__ xn2p){
  int row = blockIdx.x * 4 + (threadIdx.x >> 6);
  int lane = threadIdx.x & 63;
  u16x4 va = *(const u16x4*)&xa[(size_t)row * CC + lane * 4];
  float v0 = b2f(va[0]), v1 = b2f(va[1]), v2 = b2f(va[2]), v3 = b2f(va[3]);
  if (xb){
    u16x4 vb = *(const u16x4*)&xb[(size_t)row * CC + lane * 4];
    v0 += b2f(vb[0]); v1 += b2f(vb[1]); v2 += b2f(vb[2]); v3 += b2f(vb[3]);
  }
  float mu = waveSum(v0 + v1 + v2 + v3) * (1.0f / CC);
  float d0 = v0 - mu, d1 = v1 - mu, d2 = v2 - mu, d3 = v3 - mu;
  float var = waveSum(d0 * d0 + d1 * d1 + d2 * d2 + d3 * d3) * (1.0f / CC);
  float inv = rsqrtf(var + 1e-5f);
  float4 wv = *(const float4*)&w[lane * 4];
  float4 bv = *(const float4*)&b[lane * 4];
  float x0 = d0 * inv * wv.x + bv.x;
  float x1 = d1 * inv * wv.y + bv.y;
  float x2 = d2 * inv * wv.z + bv.z;
  float x3 = d3 * inv * wv.w + bv.w;
  u16x4 o; o[0] = f2b(x0); o[1] = f2b(x1); o[2] = f2b(x2); o[3] = f2b(x3);
  *(u16x4*)&xoutb[(size_t)row * CC + lane * 4] = o;
  if (xn2p && lane < 16){
    int bb = row >> 12, n = row & 4095, y = n >> 6, x = n & 63;
    *(u16x4*)&xn2p[(((size_t)(bb * 66 + y + 1)) * 66 + x + 1) * 64 + lane * 4] = o;
  }
  if (rn){
    float ss = waveSum(x0 * x0 + x1 * x1 + x2 * x2 + x3 * x3);
    if (lane == 0) rn[row] = 1.0f / fmaxf(sqrtf(ss), 1e-12f);
  }
}

// ---------------- border zeros for padded image ----------------
__global__ __launch_bounds__(256) void k_zb(uint16_t* __restrict__ xn2p){
  int i = blockIdx.x * 256 + threadIdx.x;   // (b, j<260, c4<16)
  if (i >= 16 * 260 * 16) return;
  int c4 = i & 15; int rest = i >> 4;
  int j = rest % 260; int b = rest / 260;
  int py, px;
  if (j < 66){ py = 0; px = j; }
  else if (j < 132){ py = 65; px = j - 66; }
  else if (j < 196){ py = j - 132 + 1; px = 0; }
  else { py = j - 196 + 1; px = 65; }
  u16x4 z; z[0] = 0; z[1] = 0; z[2] = 0; z[3] = 0;
  *(u16x4*)&xn2p[(((size_t)(b * 66 + py)) * 66 + px) * 64 + c4 * 4] = z;
}

// ---------------- merged weight conversions (wi|wo|w1|w2|pconv|dwT) ----------------
__global__ __launch_bounds__(256) void k_cvtw(const float* __restrict__ wi, const float* __restrict__ wo,
                                              const float* __restrict__ w1, const float* __restrict__ w2,
                                              const float* __restrict__ pw, const float* __restrict__ dww,
                                              uint16_t* __restrict__ wib, uint16_t* __restrict__ wob,
                                              uint16_t* __restrict__ w1b, uint16_t* __restrict__ w2b,
                                              uint16_t* __restrict__ wp2, float* __restrict__ dwwT){
  int i = blockIdx.x * 256 + threadIdx.x;
  if (i < 163840){
    const float* src; uint16_t* dst; int off;
    if (i < 49152){ src = wi; dst = wib; off = i; }
    else if (i < 65536){ src = wo; dst = wob; off = i - 49152; }
    else if (i < 131072){ src = w1; dst = w1b; off = i - 65536; }
    else { src = w2; dst = w2b; off = i - 131072; }
    float4 v = ((const float4*)src)[off];
    u16x4 o;
    o[0] = f2b(v.x); o[1] = f2b(v.y); o[2] = f2b(v.z); o[3] = f2b(v.w);
    *(u16x4*)&dst[(size_t)off * 4] = o;
  } else if (i < 200704){
    int j = i - 163840;
    if (j < 64 * 576){
      int co = j / 576, r = j % 576, tap = r >> 6, ci = r & 63;
      wp2[j] = f2b(pw[(size_t)co * 576 + ci * 9 + tap]);
    }
  } else {
    int j = i - 200704;                         // dwwT[tap][ch] = dww[ch][tap]
    if (j < 9 * HID){
      int tap = j / HID, ch = j % HID;
      dwwT[j] = dww[(size_t)ch * 9 + tap];
    }
  }
}

// ---------------- xn transpose: xnT[b][c][n] = xn[b][n][c] (bf16, LDS-tiled) ----------------
__global__ __launch_bounds__(256) void k_txT(const uint16_t* __restrict__ xnb, uint16_t* __restrict__ xnTb){
  __shared__ uint16_t tile[64 * 66];   // stride 66 u16 -> conflict-light scalar access
  int b = blockIdx.z;
  int n0 = blockIdx.x * 64, c0 = blockIdx.y * 64;
  int t = threadIdx.x;
#pragma unroll
  for (int i = 0; i < 16; i++){
    int idx = i * 256 + t;             // 0..4095
    int nr = idx >> 6, c = idx & 63;   // coalesced read (consecutive c)
    tile[c * 66 + nr] = xnb[((size_t)b * NN + n0 + nr) * CC + c0 + c];
  }
  __syncthreads();
#pragma unroll
  for (int i = 0; i < 16; i++){
    int idx = i * 256 + t;
    int cr = idx >> 6, n = idx & 63;   // coalesced write (consecutive n)
    xnTb[((size_t)b * CC + c0 + cr) * NN + n0 + n] = tile[cr * 66 + n];
  }
}

// ---------------- logits GEMM + exp epilogue -> E bf16 [b][s][n] ----------------
__global__ __launch_bounds__(256) void k_logits_mfma(const uint16_t* __restrict__ slotsNb,
                                                     const uint16_t* __restrict__ xnb,
                                                     const float* __restrict__ rn,
                                                     const float* __restrict__ scale_p,
                                                     uint16_t* __restrict__ E){
  __shared__ uint16_t smem[20480];      // lA 64x64 | lB 256x64 ; reused as eT 64x264
  __shared__ float rnS[256];
  uint16_t* lA = smem;
  uint16_t* lB = smem + 64 * 64;
  int t = threadIdx.x, lane = t & 63, w = t >> 6;
  int b = blockIdx.y, n0 = blockIdx.x * 256;
  rnS[t] = rn[b * NN + n0 + t];
  f32x4 acc[4][4];
#pragma unroll
  for (int m = 0; m < 4; m++)
#pragma unroll
    for (int n = 0; n < 4; n++) acc[m][n] = (f32x4){0.f, 0.f, 0.f, 0.f};
  for (int kc = 0; kc < 4; kc++){
#pragma unroll
    for (int i = 0; i < 2; i++){
      int idx = i * 256 + t, row = idx >> 3, kp = idx & 7;
      *(u16x8*)&lA[row * 64 + swz8(row, kp)] = *(const u16x8*)&slotsNb[(size_t)(b * 64 + row) * 256 + kc * 64 + kp * 8];
    }
#pragma unroll
    for (int i = 0; i < 8; i++){
      int idx = i * 256 + t, row = idx >> 3, kp = idx & 7;
      *(u16x8*)&lB[row * 64 + swz8(row, kp)] = *(const u16x8*)&xnb[((size_t)b * NN + n0 + row) * 256 + kc * 64 + kp * 8];
    }
    __syncthreads();
    mma_core<1, 1>(lA, 64, lB, 64, acc, 0, w * 64, lane);
    __syncthreads();
  }
  float scale = scale_p[0];
  int rb4 = (lane >> 4) * 4, cb = lane & 15;
#pragma unroll
  for (int m = 0; m < 4; m++)
#pragma unroll
    for (int n = 0; n < 4; n++)
#pragma unroll
      for (int j = 0; j < 4; j++){
        int s = m * 16 + rb4 + j, nl = w * 64 + n * 16 + cb;
        smem[s * 264 + nl] = f2b(__expf(acc[m][n][j] * scale * rnS[nl]));
      }
  __syncthreads();
#pragma unroll
  for (int i = 0; i < 8; i++){
    int idx = i * 256 + t, row = idx >> 5, cseg = idx & 31;
    *(u16x8*)&E[((size_t)b * 64 + row) * NN + n0 + cseg * 8] = *(const u16x8*)&smem[row * 264 + cseg * 8];
  }
}

// ---------------- z1: invz1[b,s] = 1 / sum_n E (vectorized) ----------------
__global__ __launch_bounds__(256) void k_z1(const uint16_t* __restrict__ E, float* __restrict__ invz1){
  int bs = blockIdx.x, t = threadIdx.x;
  u16x8 v0 = *(const u16x8*)&E[(size_t)bs * NN + t * 16];
  u16x8 v1 = *(const u16x8*)&E[(size_t)bs * NN + t * 16 + 8];
  float s = 0.f;
#pragma unroll
  for (int i = 0; i < 8; i++) s += b2f(v0[i]) + b2f(v1[i]);
  __shared__ float s4[4];
  float z = blockSum256(s, s4);
  if (t == 0) invz1[bs] = 1.0f / z;
}

// ------- slots GEMM (8-way K-split, both operands k-major via xnT; no in-kernel transpose) -------
__global__ __launch_bounds__(256) void k_slots_mfma(const uint16_t* __restrict__ E,
                                                    const uint16_t* __restrict__ xnTb,
                                                    float* __restrict__ part){
  __shared__ uint16_t lA[64 * 64];     // E tile: 64 s x 64 k
  __shared__ uint16_t lB[256 * 64];    // xnT tile: 256 c x 64 k  (40KB total)
  int t = threadIdx.x, lane = t & 63, w = t >> 6;
  int ks = blockIdx.x, b = blockIdx.y;
  f32x4 acc[4][4];
#pragma unroll
  for (int m = 0; m < 4; m++)
#pragma unroll
    for (int n = 0; n < 4; n++) acc[m][n] = (f32x4){0.f, 0.f, 0.f, 0.f};
  for (int kc = 0; kc < 8; kc++){
    int n0 = ks * 512 + kc * 64;
#pragma unroll
    for (int i = 0; i < 2; i++){        // lA: 512 units, 2/thread
      int q = (w * 2 + i) * 64 + lane;
      int row = q >> 3, kpe = swz8(row, q & 7);
      g2l16(&E[((size_t)b * 64 + row) * NN + n0 + kpe], &lA[(w * 2 + i) * 512]);
    }
#pragma unroll
    for (int i = 0; i < 8; i++){        // lB: 2048 units, 8/thread
      int q = (w * 8 + i) * 64 + lane;
      int row = q >> 3, kpe = swz8(row, q & 7);
      g2l16(&xnTb[((size_t)b * CC + row) * NN + n0 + kpe], &lB[(w * 8 + i) * 512]);
    }
    __syncthreads();
    mma_core<1, 1>(lA, 64, lB, 64, acc, 0, w * 64, lane);
    __syncthreads();
  }
  int rb4 = (lane >> 4) * 4, cb = lane & 15;
#pragma unroll
  for (int m = 0; m < 4; m++)
#pragma unroll
    for (int n = 0; n < 4; n++)
#pragma unroll
      for (int j = 0; j < 4; j++){
        int s = m * 16 + rb4 + j, c = w * 64 + n * 16 + cb;
        part[(((size_t)b * 8 + ks) * 64 + s) * 256 + c] = acc[m][n][j];
      }
}

// ---------------- fold partials -> slots bf16 ----------------
__global__ __launch_bounds__(256) void k_fold(const float* __restrict__ part, const float* __restrict__ invz1,
                                              uint16_t* __restrict__ slotsb){
  int i = blockIdx.x * 256 + threadIdx.x;
  int row = i >> 6, c4 = i & 63;
  int b = row >> 6, s = row & 63;
  float4 a = {0.f, 0.f, 0.f, 0.f};
#pragma unroll
  for (int p = 0; p < 8; p++){
    float4 v = *(const float4*)&part[(((size_t)b * 8 + p) * 64 + s) * 256 + c4 * 4];
    a.x += v.x; a.y += v.y; a.z += v.z; a.w += v.w;
  }
  float iz = invz1[row];
  u16x4 o; o[0] = f2b(a.x * iz); o[1] = f2b(a.y * iz); o[2] = f2b(a.z * iz); o[3] = f2b(a.w * iz);
  *(u16x4*)&slotsb[(size_t)row * 256 + c4 * 4] = o;
}

// ---------------- qkv GEMM: [1024 x 768] = slotsb @ wib^T + bi (fp32 out) ----------------
__global__ __launch_bounds__(256) void k_gemm_qkv(const uint16_t* __restrict__ slotsb,
                                                  const uint16_t* __restrict__ wib,
                                                  const float* __restrict__ bi,
                                                  float* __restrict__ qkv){
  __shared__ uint16_t lA[128 * 64];
  __shared__ uint16_t lB[128 * 64];
  int t = threadIdx.x, lane = t & 63, w = t >> 6;
  int wrow = (w >> 1) * 64, wcol = (w & 1) * 64;
  int BR = blockIdx.x * 128, BC = blockIdx.y * 128;
  f32x4 acc[4][4];
#pragma unroll
  for (int m = 0; m < 4; m++)
#pragma unroll
    for (int n = 0; n < 4; n++) acc[m][n] = (f32x4){0.f, 0.f, 0.f, 0.f};
  for (int kc = 0; kc < 4; kc++){
#pragma unroll
    for (int i = 0; i < 4; i++){
      int idx = i * 256 + t, row = idx >> 3, kp = idx & 7;
      *(u16x8*)&lA[row * 64 + swz8(row, kp)] = *(const u16x8*)&slotsb[(size_t)(BR + row) * 256 + kc * 64 + kp * 8];
      *(u16x8*)&lB[row * 64 + swz8(row, kp)] = *(const u16x8*)&wib[(size_t)(BC + row) * 256 + kc * 64 + kp * 8];
    }
    __syncthreads();
    mma_core<1, 1>(lA, 64, lB, 64, acc, wrow, wcol, lane);
    __syncthreads();
  }
  int rb4 = (lane >> 4) * 4, cb = lane & 15;
#pragma unroll
  for (int m = 0; m < 4; m++)
#pragma unroll
    for (int n = 0; n < 4; n++){
      int c = BC + wcol + n * 16 + cb;
      float bias = bi[c];
#pragma unroll
      for (int j = 0; j < 4; j++)
        qkv[(size_t)(BR + wrow + m * 16 + rb4 + j) * 768 + c] = acc[m][n][j] + bias;
    }
}

// ---------------- per (b,h) attention over S=64 -> aob bf16 ----------------
__global__ __launch_bounds__(256) void k_attn(const float* __restrict__ qkv, uint16_t* __restrict__ aob){
  int b = blockIdx.x >> 3, h = blockIdx.x & 7;
  __shared__ float lq[64][33], lk[64][33], lv[64][33];
  __shared__ float sc[64][65];
  int t = threadIdx.x;
  for (int idx = t; idx < 64 * 32; idx += 256){
    int s = idx >> 5, d = idx & 31;
    const float* base = qkv + ((size_t)b * SS + s) * 768 + h * DH + d;
    lq[s][d] = base[0];
    lk[s][d] = base[256];
    lv[s][d] = base[512];
  }
  __syncthreads();
  const float rs = 0.17677669529663687f;
  for (int idx = t; idx < 64 * 64; idx += 256){
    int qq = idx >> 6, kk = idx & 63;
    float a = 0.f;
#pragma unroll
    for (int d = 0; d < 32; d++) a += lq[qq][d] * lk[kk][d];
    sc[qq][kk] = a * rs;
  }
  __syncthreads();
  {
    int r = t >> 2, sub = t & 3;
    float m = -1e30f;
#pragma unroll
    for (int k = sub * 16; k < sub * 16 + 16; k++) m = fmaxf(m, sc[r][k]);
    m = fmaxf(m, __shfl_xor(m, 1, 64));
    m = fmaxf(m, __shfl_xor(m, 2, 64));
    float z = 0.f;
#pragma unroll
    for (int k = sub * 16; k < sub * 16 + 16; k++){
      float e = __expf(sc[r][k] - m); sc[r][k] = e; z += e;
    }
    z += __shfl_xor(z, 1, 64);
    z += __shfl_xor(z, 2, 64);
    float iv = 1.0f / z;
#pragma unroll
    for (int k = sub * 16; k < sub * 16 + 16; k++) sc[r][k] *= iv;
  }
  __syncthreads();
  for (int idx = t; idx < 64 * 32; idx += 256){
    int qq = idx >> 5, d = idx & 31;
    float a = 0.f;
#pragma unroll
    for (int k = 0; k < 64; k++) a += sc[qq][k] * lv[k][d];
    aob[((size_t)b * SS + qq) * CC + h * DH + d] = f2b(a);
  }
}

// ---------------- oproj GEMM: sl2T[b][c][s] = (aob @ wob^T + bo)^T bf16 ----------------
__global__ __launch_bounds__(256) void k_gemm_oproj(const uint16_t* __restrict__ aob,
                                                    const uint16_t* __restrict__ wob,
                                                    const float* __restrict__ bo,
                                                    uint16_t* __restrict__ sl2Tb){
  __shared__ uint16_t lA[128 * 64];
  __shared__ uint16_t lB[128 * 64];
  int t = threadIdx.x, lane = t & 63, w = t >> 6;
  int wrow = (w >> 1) * 64, wcol = (w & 1) * 64;
  int BR = blockIdx.x * 128, BC = blockIdx.y * 128;
  f32x4 acc[4][4];
#pragma unroll
  for (int m = 0; m < 4; m++)
#pragma unroll
    for (int n = 0; n < 4; n++) acc[m][n] = (f32x4){0.f, 0.f, 0.f, 0.f};
  for (int kc = 0; kc < 4; kc++){
#pragma unroll
    for (int i = 0; i < 4; i++){
      int idx = i * 256 + t, row = idx >> 3, kp = idx & 7;
      *(u16x8*)&lA[row * 64 + swz8(row, kp)] = *(const u16x8*)&aob[(size_t)(BR + row) * 256 + kc * 64 + kp * 8];
      *(u16x8*)&lB[row * 64 + swz8(row, kp)] = *(const u16x8*)&wob[(size_t)(BC + row) * 256 + kc * 64 + kp * 8];
    }
    __syncthreads();
    mma_core<1, 1>(lA, 64, lB, 64, acc, wrow, wcol, lane);
    __syncthreads();
  }
  int rb4 = (lane >> 4) * 4, cb = lane & 15;
#pragma unroll
  for (int m = 0; m < 4; m++)
#pragma unroll
    for (int n = 0; n < 4; n++){
      int c = BC + wcol + n * 16 + cb;
      float bias = bo[c];
#pragma unroll
      for (int j = 0; j < 4; j++){
        int r = BR + wrow + m * 16 + rb4 + j;
        int b = r >> 6, s = r & 63;
        sl2Tb[((size_t)b * 256 + c) * 64 + s] = f2b(acc[m][n][j] + bias);
      }
    }
}

// ---------------- mix GEMM (pt fused): mixb[n][c] = (E^T[n][s]/z2[n]) @ sl2T[c][s] ----------------
__global__ __launch_bounds__(256) void k_mix(const uint16_t* __restrict__ E, const uint16_t* __restrict__ sl2Tb,
                                             uint16_t* __restrict__ mixb){
  __shared__ uint16_t lA[128 * 72];    // E^T tile [n_local][s] (padded stride, no swizzle)
  __shared__ uint16_t lB[128 * 64];    // sl2T rows [c][s] (swizzled)
  __shared__ float z2S[128];
  int t = threadIdx.x, lane = t & 63, w = t >> 6;
  int wrow = (w >> 1) * 64, wcol = (w & 1) * 64;
  int BR = blockIdx.x * 128, BC = blockIdx.y * 128, b = blockIdx.z;
#pragma unroll
  for (int i = 0; i < 4; i++){
    int idx = i * 256 + t; int s = idx >> 4, n8 = (idx & 15) * 8;
    u16x8 v = *(const u16x8*)&E[((size_t)b * 64 + s) * NN + BR + n8];
#pragma unroll
    for (int j = 0; j < 8; j++) lA[(n8 + j) * 72 + s] = v[j];
  }
#pragma unroll
  for (int i = 0; i < 4; i++){
    int idx = i * 256 + t, row = idx >> 3, kp = idx & 7;
    *(u16x8*)&lB[row * 64 + swz8(row, kp)] = *(const u16x8*)&sl2Tb[((size_t)b * 256 + BC + row) * 64 + kp * 8];
  }
  __syncthreads();
  if (t < 128){
    float s = 0.f;
#pragma unroll
    for (int k2 = 0; k2 < 64; k2++) s += b2f(lA[t * 72 + k2]);
    z2S[t] = 1.0f / s;
  }
  __syncthreads();
  f32x4 acc[4][4];
#pragma unroll
  for (int m = 0; m < 4; m++)
#pragma unroll
    for (int n = 0; n < 4; n++) acc[m][n] = (f32x4){0.f, 0.f, 0.f, 0.f};
  mma_core<0, 1>(lA, 72, lB, 64, acc, wrow, wcol, lane);
  int rb4 = (lane >> 4) * 4, cb = lane & 15;
#pragma unroll
  for (int m = 0; m < 4; m++)
#pragma unroll
    for (int n = 0; n < 4; n++)
#pragma unroll
      for (int j = 0; j < 4; j++){
        int lrow = wrow + m * 16 + rb4 + j;
        size_t gi = ((size_t)b * NN + BR + lrow) * 256 + BC + wcol + n * 16 + cb;
        mixb[gi] = f2b(acc[m][n][j] * z2S[lrow]);
      }
}

// ------- pconv as 9-tap MFMA GEMM, halo staged ONCE (6 padded rows in LDS; taps read in-place) -------
__global__ __launch_bounds__(256) void k_pconv_mfma(const uint16_t* __restrict__ xn2p,
                                                    const uint16_t* __restrict__ wp2,
                                                    uint16_t* __restrict__ pcb){
  __shared__ uint16_t lS[3328 * 8];    // 53.2KB: 6x66 rows x 64ch (3168 units used, tail pad)
  __shared__ uint16_t lB[64 * 64];
  int t = threadIdx.x, lane = t & 63, w = t >> 6;
  int wrow = w * 64;
  int BR = blockIdx.x * 256;
  int b = BR >> 12, y0 = (BR & 4095) >> 6;   // 4 image rows y0..y0+3 -> padded rows y0..y0+5
  // ---- stage halo once: linear copy of 6 padded rows, source pre-swizzled by row li
  size_t G0 = ((size_t)(b * 66 + y0) * 66) * 64;
#pragma unroll
  for (int i = 0; i < 13; i++){
    int q = i * 256 + t;               // 16B unit index (tail >3168 loads pad; memory-safe: pcb follows)
    int li = q >> 3, kp = q & 7;
    g2l16(&xn2p[G0 + (size_t)li * 64 + ((kp ^ (li & 7)) << 3)], &lS[q * 8]);
  }
  const int rb = lane & 15, ub = lane >> 4;
  int li0[4];
#pragma unroll
  for (int m = 0; m < 4; m++){
    int r = wrow + m * 16 + rb;        // output px 0..255
    li0[m] = ((r >> 6) + 1) * 66 + (r & 63) + 1;
  }
  f32x4 acc[4][4];
#pragma unroll
  for (int m = 0; m < 4; m++)
#pragma unroll
    for (int n = 0; n < 4; n++) acc[m][n] = (f32x4){0.f, 0.f, 0.f, 0.f};
#pragma unroll
  for (int tap = 0; tap < 9; tap++){
    const int doff = (tap / 3 - 1) * 66 + (tap % 3 - 1);
#pragma unroll
    for (int i = 0; i < 2; i++){
      int q = (w * 2 + i) * 64 + lane;
      int row = q >> 3, kpe = swz8(row, q & 7);
      g2l16(&wp2[(size_t)row * 576 + tap * 64 + kpe], &lB[(w * 2 + i) * 512]);
    }
    __syncthreads();                   // drains lS (first tap) + lB(tap)
#pragma unroll
    for (int ks = 0; ks < 2; ks++){
      const int u = ks * 4 + ub;
      u16x8 af[4], bf[4];
#pragma unroll
      for (int m = 0; m < 4; m++){
        int li = li0[m] + doff;
        af[m] = *(const u16x8*)&lS[li * 64 + ((u ^ (li & 7)) << 3)];
      }
#pragma unroll
      for (int n = 0; n < 4; n++){
        int r = n * 16 + rb;
        bf[n] = *(const u16x8*)&lB[r * 64 + ((u ^ (r & 7)) << 3)];
      }
#pragma unroll
      for (int m = 0; m < 4; m++)
#pragma unroll
        for (int n = 0; n < 4; n++)
          mfma_bf16(acc[m][n], af[m], bf[n]);
    }
    __syncthreads();                   // protect lB before next tap's restage
  }
  int rb4 = (lane >> 4) * 4, cb = lane & 15;
#pragma unroll
  for (int m = 0; m < 4; m++)
#pragma unroll
    for (int j = 0; j < 4; j++){
      uint16_t* rp = &pcb[(size_t)(BR + wrow + m * 16 + rb4 + j) * 64 + cb];
#pragma unroll
      for (int n = 0; n < 4; n++)
        rp[n * 16] = f2b(acc[m][n][j]);
    }
}

// ---------------- lin1 MFMA + gelu -> Y1b/Y2b (1-D grid 4096, XCD-remapped) ----------------
// Epilogue: bias hoist + block-uniform dst + (m,j)-outer loop -> const-offset stores
__global__ __launch_bounds__(256) void k_lin1_mfma(const uint16_t* __restrict__ pcb,
                                                   const uint16_t* __restrict__ xn2b,
                                                   const uint16_t* __restrict__ w1b,
                                                   const float* __restrict__ b1,
                                                   uint16_t* __restrict__ Y1b, uint16_t* __restrict__ Y2b){
  __shared__ uint16_t lA[128 * 64];
  __shared__ uint16_t lB[128 * 64];
  int t = threadIdx.x, lane = t & 63, w = t >> 6;
  int wrow = (w >> 1) * 64, wcol = (w & 1) * 64;
  int bid = blockIdx.x;
  int xcd = bid & 7, i5 = bid >> 3;         // i5 in [0,512)
  int BR = (xcd * 64 + (i5 >> 3)) * 128;
  int BC = (i5 & 7) * 128;
  f32x4 acc[4][4];
#pragma unroll
  for (int m = 0; m < 4; m++)
#pragma unroll
    for (int n = 0; n < 4; n++) acc[m][n] = (f32x4){0.f, 0.f, 0.f, 0.f};
  for (int kc = 0; kc < 4; kc++){
#pragma unroll
    for (int i = 0; i < 4; i++){
      int q = (w * 4 + i) * 64 + lane;
      int row = q >> 3, kpe = swz8(row, q & 7);
      size_t gr = (size_t)(BR + row);
      const uint16_t* src = (kc == 0) ? &pcb[gr * 64 + kpe] : &xn2b[gr * 256 + kc * 64 + kpe];
      g2l16(src, &lA[(w * 4 + i) * 512]);
      g2l16(&w1b[(size_t)(BC + row) * 256 + kc * 64 + kpe], &lB[(w * 4 + i) * 512]);
    }
    __syncthreads();
    mma_core<1, 1>(lA, 64, lB, 64, acc, wrow, wcol, lane);
    __syncthreads();
  }
  int rb4 = (lane >> 4) * 4, cb = lane & 15;
  float bias[4];
#pragma unroll
  for (int n = 0; n < 4; n++) bias[n] = b1[BC + wcol + n * 16 + cb];
  // block-uniform routing: [BC, BC+128) entirely on one side of HID=512
  uint16_t* dst = (BC < HID) ? (Y1b + BC + wcol + cb) : (Y2b + (BC - HID) + wcol + cb);
#pragma unroll
  for (int m = 0; m < 4; m++)
#pragma unroll
    for (int j = 0; j < 4; j++){
      uint16_t* rp = dst + (size_t)(BR + wrow + m * 16 + rb4 + j) * HID;
#pragma unroll
      for (int n = 0; n < 4; n++)
        rp[n * 16] = f2b(gelu_fast(acc[m][n][j] + bias[n]));
    }
}

// ------- dwconv 3x3 + gelu, fused *Y2 — 2 px/thread, shared x-window, v_pk_fma_f32 -------
// grid (128 = 64rows × 2segs of 32px, 4 ch-chunks, BB). Halo tile 3×34×128 staged once.
__global__ __launch_bounds__(256) void k_dwconv(const uint16_t* __restrict__ Y1b,
                                                const float* __restrict__ dwwT,   // [tap][512]
                                                const float* __restrict__ dwb,
                                                const uint16_t* __restrict__ Y2b,
                                                uint16_t* __restrict__ YPb){
  __shared__ uint16_t lds[3 * 34 * 136];   // 27.7KB; px-stride 136 elems (272B)
  int b = blockIdx.z, chunk = blockIdx.y;
  int y = blockIdx.x >> 1, seg = blockIdx.x & 1;
  int x0 = seg * 32;
  int t = threadIdx.x;
  const uint16_t* base = Y1b + (size_t)b * NN * HID + chunk * 128;
  const u16x8 z8 = {0, 0, 0, 0, 0, 0, 0, 0};
#pragma unroll
  for (int i = 0; i < 7; i++){
    int idx = i * 256 + t;
    if (idx < 1632){                        // 3 rows × 34 px × 16 ch-groups
      int g8 = idx & 15, rest = idx >> 4;
      int c = rest % 34, r = rest / 34;
      int ry = y + r - 1, xx = x0 + c - 1;
      u16x8 v = z8;
      if (ry >= 0 && ry < HH && xx >= 0 && xx < WW)
        v = *(const u16x8*)&base[(size_t)(ry * WW + xx) * HID + g8 * 8];
      *(u16x8*)&lds[(r * 34 + c) * 136 + g8 * 8] = v;
    }
  }
  __syncthreads();
  int pg = t >> 4, g8 = t & 15;
  int cg = chunk * 128 + g8 * 8;
  int px = pg * 2;                          // 2 consecutive pixels per thread
  f32x2 acc[2][4];
  {
    float4 b0 = *(const float4*)&dwb[cg];
    float4 b1 = *(const float4*)&dwb[cg + 4];
    acc[0][0] = (f32x2){b0.x, b0.y}; acc[0][1] = (f32x2){b0.z, b0.w};
    acc[0][2] = (f32x2){b1.x, b1.y}; acc[0][3] = (f32x2){b1.z, b1.w};
#pragma unroll
    for (int j = 0; j < 4; j++) acc[1][j] = acc[0][j];
  }
#pragma unroll
  for (int r = 0; r < 3; r++){
    f32x2 u[4][4];                          // 4 shared x-columns (px-1 .. px+2)
#pragma unroll
    for (int cc = 0; cc < 4; cc++){
      u32x4 v = *(const u32x4*)&lds[(r * 34 + px + cc) * 136 + g8 * 8];
#pragma unroll
      for (int j = 0; j < 4; j++) u[cc][j] = bpair(v[j]);
    }
#pragma unroll
    for (int dx = 0; dx < 3; dx++){
      const f32x2* wt = (const f32x2*)&dwwT[(r * 3 + dx) * HID + cg];
      f32x2 w0 = wt[0], w1 = wt[1], w2 = wt[2], w3 = wt[3];
      pkfma(acc[0][0], u[dx][0], w0);     pkfma(acc[1][0], u[dx + 1][0], w0);
      pkfma(acc[0][1], u[dx][1], w1);     pkfma(acc[1][1], u[dx + 1][1], w1);
      pkfma(acc[0][2], u[dx][2], w2);     pkfma(acc[1][2], u[dx + 1][2], w2);
      pkfma(acc[0][3], u[dx][3], w3);     pkfma(acc[1][3], u[dx + 1][3], w3);
    }
  }
  int n = y * WW + x0 + px;
  const uint16_t* y2p = &Y2b[((size_t)b * NN + n) * HID + cg];
  uint16_t* yp = &YPb[((size_t)b * NN + n) * HID + cg];
#pragma unroll
  for (int p = 0; p < 2; p++){
    u32x4 y2v = *(const u32x4*)(y2p + (size_t)p * HID);
    u16x8 o;
#pragma unroll
    for (int j = 0; j < 4; j++){
      f32x2 yy = bpair(y2v[j]);
      o[2 * j]     = f2b(gelu_fast(acc[p][j].x) * yy.x);
      o[2 * j + 1] = f2b(gelu_fast(acc[p][j].y) * yy.y);
    }
    *(u16x8*)(yp + (size_t)p * HID) = o;
  }
}

// ---------------- lin2 MFMA: deltab = YP @ w2^T + b2 (1-D grid 1024, XCD-remapped) ----------------
__global__ __launch_bounds__(256) void k_lin2_mfma(const uint16_t* __restrict__ YPb,
                                                   const uint16_t* __restrict__ w2b,
                                                   const float* __restrict__ b2,
                                                   uint16_t* __restrict__ deltab){
  __shared__ uint16_t lA[128 * 64];
  __shared__ uint16_t lB[128 * 64];
  int t = threadIdx.x, lane = t & 63, w = t >> 6;
  int wrow = (w >> 1) * 64, wcol = (w & 1) * 64;
  int bid = blockIdx.x;
  int xcd = bid & 7, i5 = bid >> 3;         // i5 in [0,128)
  int BR = (xcd * 64 + (i5 >> 1)) * 128;
  int BC = (i5 & 1) * 128;
  f32x4 acc[4][4];
#pragma unroll
  for (int m = 0; m < 4; m++)
#pragma unroll
    for (int n = 0; n < 4; n++) acc[m][n] = (f32x4){0.f, 0.f, 0.f, 0.f};
  for (int kc = 0; kc < 8; kc++){
#pragma unroll
    for (int i = 0; i < 4; i++){
      int q = (w * 4 + i) * 64 + lane;
      int row = q >> 3, kpe = swz8(row, q & 7);
      g2l16(&YPb[(size_t)(BR + row) * HID + kc * 64 + kpe], &lA[(w * 4 + i) * 512]);
      g2l16(&w2b[(size_t)(BC + row) * HID + kc * 64 + kpe], &lB[(w * 4 + i) * 512]);
    }
    __syncthreads();
    mma_core<1, 1>(lA, 64, lB, 64, acc, wrow, wcol, lane);
    __syncthreads();
  }
  int rb4 = (lane >> 4) * 4, cb = lane & 15;
  float bias[4];
#pragma unroll
  for (int n = 0; n < 4; n++) bias[n] = b2[BC + wcol + n * 16 + cb];
  uint16_t* dst = deltab + BC + wcol + cb;
#pragma unroll
  for (int m = 0; m < 4; m++)
#pragma unroll
    for (int j = 0; j < 4; j++){
      uint16_t* rp = dst + (size_t)(BR + wrow + m * 16 + rb4 + j) * CC;
#pragma unroll
      for (int n = 0; n < 4; n++)
        rp[n * 16] = f2b(acc[m][n][j] + bias[n]);
    }
}

// ---------------- final: v = mixb+deltab; out0 = xhwcb + v (NCHW), out1 = -v ----------------
__global__ __launch_bounds__(256) void k_final2(const uint16_t* __restrict__ mixb,
                                                const uint16_t* __restrict__ deltab,
                                                const uint16_t* __restrict__ xhwcb,
                                                float* __restrict__ out){
  __shared__ float t0[64 * 68];
  __shared__ float t1[64 * 68];
  int b = blockIdx.z;
  int n0 = blockIdx.x * 64, c0 = blockIdx.y * 64;
  int t = threadIdx.x;
#pragma unroll
  for (int i = 0; i < 4; i++){
    int idx = i * 256 + t, row = idx >> 4, c4 = idx & 15;
    size_t gp = ((size_t)b * NN + n0 + row) * CC + c0 + c4 * 4;
    u16x4 m = *(const u16x4*)&mixb[gp];
    u16x4 d = *(const u16x4*)&deltab[gp];
    u16x4 xh = *(const u16x4*)&xhwcb[gp];
    f32x4 v0, v1;
#pragma unroll
    for (int j = 0; j < 4; j++){
      float v = b2f(m[j]) + b2f(d[j]);
      v0[j] = b2f(xh[j]) + v;
      v1[j] = -v;
    }
    *(f32x4*)&t0[row * 68 + c4 * 4] = v0;
    *(f32x4*)&t1[row * 68 + c4 * 4] = v1;
  }
  __syncthreads();
  int cl = t >> 2, seg = t & 3;
  float* o1 = out + (size_t)BB * CC * NN;
  size_t gbase = ((size_t)(b * CC + c0 + cl)) * NN + n0 + seg * 16;
#pragma unroll
  for (int k = 0; k < 4; k++){
    float4 a, c;
    a.x = t0[(seg * 16 + k * 4 + 0) * 68 + cl];
    a.y = t0[(seg * 16 + k * 4 + 1) * 68 + cl];
    a.z = t0[(seg * 16 + k * 4 + 2) * 68 + cl];
    a.w = t0[(seg * 16 + k * 4 + 3) * 68 + cl];
    c.x = t1[(seg * 16 + k * 4 + 0) * 68 + cl];
    c.y = t1[(seg * 16 + k * 4 + 1) * 68 + cl];
    c.z = t1[(seg * 16 + k * 4 + 2) * 68 + cl];
    c.w = t1[(seg * 16 + k * 4 + 3) * 68 + cl];
    *(float4*)&out[gbase + k * 4] = a;
    *(float4*)&o1[gbase + k * 4] = c;
  }
}

extern "C" void kernel_launch(void* const* d_in, const int* in_sizes, int n_in,
                              void* d_out, int out_size, void* d_ws, size_t ws_size,
                              hipStream_t stream){
  const float* x       = (const float*)d_in[0];
  const float* scale_p = (const float*)d_in[1];
  const float* n1w     = (const float*)d_in[2];
  const float* n1b     = (const float*)d_in[3];
  const float* wi      = (const float*)d_in[4];
  const float* bi      = (const float*)d_in[5];
  const float* wo      = (const float*)d_in[6];
  const float* bo      = (const float*)d_in[7];
  const float* n2w     = (const float*)d_in[8];
  const float* n2b     = (const float*)d_in[9];
  const float* pw      = (const float*)d_in[10];
  const float* w1      = (const float*)d_in[11];
  const float* b1      = (const float*)d_in[12];
  const float* dww     = (const float*)d_in[13];
  const float* dwb     = (const float*)d_in[14];
  const float* w2      = (const float*)d_in[15];
  const float* b2      = (const float*)d_in[16];

  // ---- workspace layout (float units) — total ≈ 451 MB, ws = 512 MiB ----
  float* base = (float*)d_ws;
  size_t off = 0;
  float* part = base + off; off += (size_t)BB * 8 * SS * CC;
  float* QKV  = base + off; off += (size_t)BB * SS * 3 * CC;
  float* RN   = base + off; off += (size_t)BB * NN;
  float* IZ1  = base + off; off += (size_t)BB * SS;
  float* dwwT = base + off; off += (size_t)9 * HID;
  uint16_t* slotsNb = (uint16_t*)(base + off); off += (size_t)BB * SS * CC / 2;
  uint16_t* slotsb  = (uint16_t*)(base + off); off += (size_t)BB * SS * CC / 2;
  uint16_t* aob     = (uint16_t*)(base + off); off += (size_t)BB * SS * CC / 2;
  uint16_t* sl2Tb   = (uint16_t*)(base + off); off += (size_t)BB * CC * SS / 2;
  uint16_t* xhwcb   = (uint16_t*)(base + off); off += (size_t)BB * NN * CC / 2;
  uint16_t* xnb     = (uint16_t*)(base + off); off += (size_t)BB * NN * CC / 2;
  uint16_t* xnTb    = (uint16_t*)(base + off); off += (size_t)BB * NN * CC / 2;   // xn transposed [b][c][n]
  uint16_t* mixb    = (uint16_t*)(base + off); off += (size_t)BB * NN * CC / 2;
  uint16_t* deltab  = (uint16_t*)(base + off); off += (size_t)BB * NN * CC / 2;
  uint16_t* E       = (uint16_t*)(base + off); off += (size_t)BB * SS * NN / 2;
  uint16_t* w1b     = (uint16_t*)(base + off); off += (size_t)(2 * HID) * CC / 2;
  uint16_t* w2b     = (uint16_t*)(base + off); off += (size_t)CC * HID / 2;
  uint16_t* wib     = (uint16_t*)(base + off); off += (size_t)(3 * CC) * CC / 2;
  uint16_t* wob     = (uint16_t*)(base + off); off += (size_t)CC * CC / 2;
  uint16_t* wp2     = (uint16_t*)(base + off); off += (size_t)64 * 576 / 2 + 16;
  uint16_t* Y1b     = (uint16_t*)(base + off); off += (size_t)BB * NN * HID / 2;
  uint16_t* Y2b     = (uint16_t*)(base + off); off += (size_t)BB * NN * HID / 2;
  uint16_t* YPb     = (uint16_t*)(base + off); off += (size_t)BB * NN * HID / 2;
  uint16_t* xn2b    = (uint16_t*)(base + off); off += (size_t)BB * NN * CC / 2;
  uint16_t* xn2p    = (uint16_t*)(base + off); off += (size_t)BB * 66 * 66 * 64 / 2;
  uint16_t* pcb     = (uint16_t*)(base + off); off += (size_t)BB * NN * 64 / 2;   // follows xn2p (pconv tail-read safety)
  if (ws_size < off * sizeof(float)) return;
  float* OUT = (float*)d_out;

  dim3 tb2(32, 8);
  // ---- slot-mixing phase ----
  k_t2b<<<dim3(NN / 32, CC / 64, BB), tb2, 0, stream>>>(x, xhwcb);
  k_pool<<<BB * SS, 256, 0, stream>>>(xhwcb, slotsNb);
  k_ln_w<<<BB * NN / 4, 256, 0, stream>>>(xhwcb, (const uint16_t*)nullptr, n1w, n1b, xnb, RN,
                                          (uint16_t*)nullptr);
  k_cvtw<<<803, 256, 0, stream>>>(wi, wo, w1, w2, pw, dww, wib, wob, w1b, w2b, wp2, dwwT);
  k_zb<<<(16 * 260 * 16 + 255) / 256, 256, 0, stream>>>(xn2p);
  k_logits_mfma<<<dim3(NN / 256, BB), 256, 0, stream>>>(slotsNb, xnb, RN, scale_p, E);
  k_txT<<<dim3(NN / 64, CC / 64, BB), 256, 0, stream>>>(xnb, xnTb);
  k_z1<<<BB * SS, 256, 0, stream>>>(E, IZ1);
  k_slots_mfma<<<dim3(8, BB), 256, 0, stream>>>(E, xnTb, part);
  k_fold<<<(BB * SS * CC / 4) / 256, 256, 0, stream>>>(part, IZ1, slotsb);
  k_gemm_qkv<<<dim3(8, 6), 256, 0, stream>>>(slotsb, wib, bi, QKV);
  k_attn<<<BB * NHEAD, 256, 0, stream>>>(QKV, aob);
  k_gemm_oproj<<<dim3(8, 2), 256, 0, stream>>>(aob, wob, bo, sl2Tb);
  k_mix<<<dim3(NN / 128, CC / 128, BB), 256, 0, stream>>>(E, sl2Tb, mixb);
  // ---- FRFN phase ----
  k_ln_w<<<BB * NN / 4, 256, 0, stream>>>(xhwcb, mixb, n2w, n2b, xn2b, (float*)nullptr, xn2p);
  k_pconv_mfma<<<BB * NN / 256, 256, 0, stream>>>(xn2p, wp2, pcb);
  k_lin1_mfma<<<4096, 256, 0, stream>>>(pcb, xn2b, w1b, b1, Y1b, Y2b);
  k_dwconv<<<dim3(128, 4, BB), 256, 0, stream>>>(Y1b, dwwT, dwb, Y2b, YPb);
  k_lin2_mfma<<<1024, 256, 0, stream>>>(YPb, w2b, b2, deltab);
  // ---- fused residual/transpose output ----
  k_final2<<<dim3(NN / 64, CC / 64, BB), 256, 0, stream>>>(mixb, deltab, xhwcb, OUT);
}